// Round 4
// baseline (5244.456 us; speedup 1.0000x reference)
//
#include <hip/hip_runtime.h>
#include <hip/hip_bf16.h>

typedef __hip_bfloat16 bf16;

__device__ __forceinline__ float b2f(bf16 v){ return __bfloat162float(v); }
__device__ __forceinline__ bf16  f2b(float v){ return __float2bfloat16(v); }

// Inputs may be bf16 OR f32 — runtime-detected flag (1 => f32).
// Output dtype follows input dtype (reference preserves dtype end-to-end).
__device__ __forceinline__ float ldin(const void* p, int i, bool f32in){
  return f32in ? ((const float*)p)[i] : b2f(((const bf16*)p)[i]);
}

// Problem: B=2, C=512, T=16, H=W=24, heads=8, ch=64
// spatial: 32 batches [512,576], processed in 4 chunks of 8 n
// temporal: 1152 batches [512,16], processed in 4 chunks of 288 m
// ws (42.5 MB): flag | A 2,359,296 bf16 | A2 2,359,296 | Bq 7,077,888 | Cx 9,437,184

// ---------------------------------------------------------------- detect input dtype
__global__ void k_detect(const void* x, int* flag){
  int tid = threadIdx.x;
  const bf16* p = (const bf16*)x;
  int cnt = 0;
  for (int i = tid; i < 512; i += 64){
    float v = b2f(p[i]);
    if (!(fabsf(v) <= 64.f)) cnt++;   // also true for NaN/Inf
  }
  #pragma unroll
  for (int off = 32; off; off >>= 1) cnt += __shfl_down(cnt, off, 64);
  if (tid == 0) flag[0] = (cnt > 16) ? 1 : 0;  // 1 => inputs are float32
}

// ---------------------------------------------------------------- K1: spatial groupnorm (chunk of 8 n)
__global__ __launch_bounds__(256) void k_gn_s(const void* __restrict__ x,
        const void* __restrict__ gw, const void* __restrict__ gb,
        bf16* __restrict__ xn, const int* __restrict__ flag, int n0){
  const bool f32in = flag[0] != 0;
  const int g = blockIdx.x;
  const int nl = blockIdx.y;
  const int n = n0 + nl;
  const int b = n >> 4, t = n & 15;
  const int tid = threadIdx.x;
  __shared__ float xs[9216];
  __shared__ float red[4][2];
  __shared__ float stats[2];
  float s = 0.f, q = 0.f;
  for (int i = tid; i < 9216; i += 256){
    int cg = i / 576, l = i - cg*576;
    int c = g*16 + cg;
    float v = ldin(x, ((b*512 + c)*16 + t)*576 + l, f32in);
    xs[i] = v; s += v; q += v*v;
  }
  #pragma unroll
  for (int off = 32; off; off >>= 1){ s += __shfl_down(s, off, 64); q += __shfl_down(q, off, 64); }
  int wid = tid >> 6;
  if ((tid & 63) == 0){ red[wid][0] = s; red[wid][1] = q; }
  __syncthreads();
  if (tid == 0){
    float S = red[0][0]+red[1][0]+red[2][0]+red[3][0];
    float Q = red[0][1]+red[1][1]+red[2][1]+red[3][1];
    float mean = S * (1.f/9216.f);
    float var  = Q * (1.f/9216.f) - mean*mean;
    stats[0] = mean; stats[1] = rsqrtf(fmaxf(var, 0.f) + 1e-5f);
  }
  __syncthreads();
  float mean = stats[0], rstd = stats[1];
  for (int i = tid; i < 9216; i += 256){
    int cg = i / 576, l = i - cg*576;
    int c = g*16 + cg;
    xn[(nl*512 + c)*576 + l] = f2b((xs[i] - mean)*rstd*ldin(gw, c, f32in) + ldin(gb, c, f32in));
  }
}

// ---------------------------------------------------------------- K2: spatial qkv GEMM (chunk)
__global__ __launch_bounds__(256) void k_qkv_s(const bf16* __restrict__ X,
        const void* __restrict__ W, const void* __restrict__ Bv,
        bf16* __restrict__ Y, const int* __restrict__ flag){
  const bool f32in = flag[0] != 0;
  const int l0 = blockIdx.x * 64;
  const int o0 = blockIdx.y * 64;
  const int nl = blockIdx.z;
  const int tid = threadIdx.x;
  const int tx = tid & 15, ty = tid >> 4;
  __shared__ float As[64][33];
  __shared__ float Bs[32][64];
  float acc[4][4] = {};
  for (int kc = 0; kc < 512; kc += 32){
    #pragma unroll
    for (int r = 0; r < 8; ++r){
      int e = tid + 256*r;
      As[e >> 5][e & 31] = ldin(W, (o0 + (e >> 5))*512 + kc + (e & 31), f32in);
    }
    #pragma unroll
    for (int r = 0; r < 8; ++r){
      int e = tid + 256*r;
      Bs[e >> 6][e & 63] = b2f(X[(nl*512 + kc + (e >> 6))*576 + l0 + (e & 63)]);
    }
    __syncthreads();
    #pragma unroll
    for (int kk = 0; kk < 32; ++kk){
      float av[4], bv[4];
      #pragma unroll
      for (int i = 0; i < 4; ++i) av[i] = As[ty + 16*i][kk];
      #pragma unroll
      for (int j = 0; j < 4; ++j) bv[j] = Bs[kk][tx + 16*j];
      #pragma unroll
      for (int i = 0; i < 4; ++i)
        #pragma unroll
        for (int j = 0; j < 4; ++j) acc[i][j] += av[i]*bv[j];
    }
    __syncthreads();
  }
  #pragma unroll
  for (int i = 0; i < 4; ++i){
    int o = o0 + ty + 16*i;
    float bia = ldin(Bv, o, f32in);
    #pragma unroll
    for (int j = 0; j < 4; ++j)
      Y[(nl*1536 + o)*576 + l0 + tx + 16*j] = f2b(acc[i][j] + bia);
  }
}

// ---------------------------------------------------------------- K3: spatial attention (chunk)
__global__ __launch_bounds__(576) void k_attn_s(const bf16* __restrict__ qkv,
        bf16* __restrict__ att){
  const int tt0 = blockIdx.x;       // 0..71
  const int nh  = blockIdx.y;       // 0..63
  const int nl = nh >> 3, head = nh & 7;
  const int tid = threadIdx.x;      // 0..575
  __shared__ float qs[64][8];
  __shared__ float ps[8][576];
  __shared__ float red2[64][9][8];
  const int qb = (nl*1536 + head*64)*576;
  const int kb = (nl*1536 + 512 + head*64)*576;
  const int vb = (nl*1536 + 1024 + head*64)*576;
  if (tid < 512){
    int c = tid >> 3, tt = tid & 7;
    qs[c][tt] = b2f(qkv[qb + c*576 + tt0*8 + tt]);
  }
  __syncthreads();
  {
    float w[8] = {};
    const int s = tid;
    for (int c = 0; c < 64; ++c){
      float kc = b2f(qkv[kb + c*576 + s]);
      #pragma unroll
      for (int tt = 0; tt < 8; ++tt) w[tt] += qs[c][tt]*kc;
    }
    #pragma unroll
    for (int tt = 0; tt < 8; ++tt) ps[tt][s] = w[tt]*0.125f;  // scale^2 = 1/sqrt(64)
  }
  __syncthreads();
  {
    int wv = tid >> 6, lane = tid & 63;
    if (wv < 8){
      float m = -1e30f;
      #pragma unroll
      for (int k2 = 0; k2 < 9; ++k2) m = fmaxf(m, ps[wv][lane + 64*k2]);
      #pragma unroll
      for (int off = 32; off; off >>= 1) m = fmaxf(m, __shfl_xor(m, off, 64));
      float tot = 0.f;
      #pragma unroll
      for (int k2 = 0; k2 < 9; ++k2){
        int idx = lane + 64*k2;
        float e = __expf(ps[wv][idx] - m);
        ps[wv][idx] = e; tot += e;
      }
      #pragma unroll
      for (int off = 32; off; off >>= 1) tot += __shfl_xor(tot, off, 64);
      float r = 1.f / tot;
      #pragma unroll
      for (int k2 = 0; k2 < 9; ++k2) ps[wv][lane + 64*k2] *= r;
    }
  }
  __syncthreads();
  {
    int c = tid / 9, j = tid - c*9;
    float part[8] = {};
    for (int it = 0; it < 64; ++it){
      int s = j*64 + it;
      float v = b2f(qkv[vb + c*576 + s]);
      #pragma unroll
      for (int tt = 0; tt < 8; ++tt) part[tt] += ps[tt][s]*v;
    }
    #pragma unroll
    for (int tt = 0; tt < 8; ++tt) red2[c][j][tt] = part[tt];
  }
  __syncthreads();
  if (tid < 512){
    int c = tid >> 3, tt = tid & 7;
    float a = 0.f;
    #pragma unroll
    for (int j = 0; j < 9; ++j) a += red2[c][j][tt];
    att[(nl*512 + head*64 + c)*576 + tt0*8 + tt] = f2b(a);
  }
}

// ---------------------------------------------------------------- K4: spatial proj + residual (chunk)
__global__ __launch_bounds__(256) void k_proj_s(const bf16* __restrict__ X,
        const void* __restrict__ W, const void* __restrict__ Bv,
        const void* __restrict__ xin, bf16* __restrict__ x2,
        const int* __restrict__ flag, int n0){
  const bool f32in = flag[0] != 0;
  const int l0 = blockIdx.x * 64;
  const int o0 = blockIdx.y * 64;
  const int nl = blockIdx.z;
  const int n = n0 + nl;
  const int b = n >> 4, t = n & 15;
  const int tid = threadIdx.x;
  const int tx = tid & 15, ty = tid >> 4;
  __shared__ float As[64][33];
  __shared__ float Bs[32][64];
  float acc[4][4] = {};
  for (int kc = 0; kc < 512; kc += 32){
    #pragma unroll
    for (int r = 0; r < 8; ++r){
      int e = tid + 256*r;
      As[e >> 5][e & 31] = ldin(W, (o0 + (e >> 5))*512 + kc + (e & 31), f32in);
    }
    #pragma unroll
    for (int r = 0; r < 8; ++r){
      int e = tid + 256*r;
      Bs[e >> 6][e & 63] = b2f(X[(nl*512 + kc + (e >> 6))*576 + l0 + (e & 63)]);
    }
    __syncthreads();
    #pragma unroll
    for (int kk = 0; kk < 32; ++kk){
      float av[4], bv[4];
      #pragma unroll
      for (int i = 0; i < 4; ++i) av[i] = As[ty + 16*i][kk];
      #pragma unroll
      for (int j = 0; j < 4; ++j) bv[j] = Bs[kk][tx + 16*j];
      #pragma unroll
      for (int i = 0; i < 4; ++i)
        #pragma unroll
        for (int j = 0; j < 4; ++j) acc[i][j] += av[i]*bv[j];
    }
    __syncthreads();
  }
  #pragma unroll
  for (int i = 0; i < 4; ++i){
    int o = o0 + ty + 16*i;
    float bia = ldin(Bv, o, f32in);
    #pragma unroll
    for (int j = 0; j < 4; ++j){
      int l = l0 + tx + 16*j;
      int addr = ((b*512 + o)*16 + t)*576 + l;
      x2[addr] = f2b(ldin(xin, addr, f32in) + acc[i][j] + bia);
    }
  }
}

// ---------------------------------------------------------------- K5: temporal groupnorm (chunk of 288 m)
__global__ __launch_bounds__(256) void k_gn_t(const bf16* __restrict__ x2,
        const void* __restrict__ gw, const void* __restrict__ gb,
        bf16* __restrict__ xn, const int* __restrict__ flag, int m0){
  const bool f32in = flag[0] != 0;
  const int ml = blockIdx.x;
  const int m = m0 + ml;
  const int b = m / 576, l = m - b*576;
  const int tid = threadIdx.x;
  __shared__ float xs[8192];
  __shared__ float mg[32], rg[32];
  for (int i = tid; i < 8192; i += 256){
    int c = i >> 4, t = i & 15;
    xs[i] = b2f(x2[((b*512 + c)*16 + t)*576 + l]);
  }
  __syncthreads();
  {
    int g = tid >> 3, ii = tid & 7;
    float s = 0.f, q = 0.f;
    for (int e = ii*32; e < ii*32 + 32; ++e){
      float v = xs[g*256 + e]; s += v; q += v*v;
    }
    #pragma unroll
    for (int off = 1; off < 8; off <<= 1){ s += __shfl_xor(s, off, 64); q += __shfl_xor(q, off, 64); }
    if (ii == 0){
      float mean = s*(1.f/256.f);
      float var  = q*(1.f/256.f) - mean*mean;
      mg[g] = mean; rg[g] = rsqrtf(fmaxf(var, 0.f) + 1e-5f);
    }
  }
  __syncthreads();
  for (int i = tid; i < 8192; i += 256){
    int c = i >> 4, g = c >> 4;
    xn[ml*8192 + i] = f2b((xs[i] - mg[g])*rg[g]*ldin(gw, c, f32in) + ldin(gb, c, f32in));
  }
}

// ---------------------------------------------------------------- K6: temporal qkv GEMM (chunk)
__global__ __launch_bounds__(256) void k_qkv_t(const bf16* __restrict__ X,
        const void* __restrict__ W, const void* __restrict__ Bv,
        bf16* __restrict__ Y, const int* __restrict__ flag){
  const bool f32in = flag[0] != 0;
  const int o0 = blockIdx.x * 96;
  const int ml = blockIdx.y;
  const int tid = threadIdx.x;
  const int t = tid & 15, oi = tid >> 4;
  __shared__ float Xs[8192];
  __shared__ float Ws[96][33];
  for (int i = tid; i < 8192; i += 256) Xs[i] = b2f(X[ml*8192 + i]);
  float acc[6] = {};
  for (int kc = 0; kc < 512; kc += 32){
    __syncthreads();
    #pragma unroll
    for (int r = 0; r < 12; ++r){
      int e = tid + 256*r;
      Ws[e >> 5][e & 31] = ldin(W, (o0 + (e >> 5))*512 + kc + (e & 31), f32in);
    }
    __syncthreads();
    #pragma unroll
    for (int c = 0; c < 32; ++c){
      float xv = Xs[(kc + c)*16 + t];
      #pragma unroll
      for (int j = 0; j < 6; ++j) acc[j] += Ws[oi + 16*j][c]*xv;
    }
  }
  #pragma unroll
  for (int j = 0; j < 6; ++j){
    int o = o0 + oi + 16*j;
    Y[(ml*1536 + o)*16 + t] = f2b(acc[j] + ldin(Bv, o, f32in));
  }
}

// ---------------------------------------------------------------- K7: temporal attention (causal + RPE, chunk)
__global__ __launch_bounds__(256) void k_attn_t(const bf16* __restrict__ qkv,
        const void* __restrict__ tbk, const void* __restrict__ tbv,
        bf16* __restrict__ att, const int* __restrict__ flag){
  const bool f32in = flag[0] != 0;
  const int head = blockIdx.x;
  const int ml = blockIdx.y;
  const int tid = threadIdx.x;
  __shared__ float qs[1024], ks[1024], vs[1024];
  __shared__ float tk[33*65], tv[33*65];
  __shared__ float ps[16*17];
  const int base = (ml*1536 + head*64)*16;
  for (int i = tid; i < 1024; i += 256){
    qs[i] = b2f(qkv[base + i]);
    ks[i] = b2f(qkv[base + 512*16 + i]);
    vs[i] = b2f(qkv[base + 1024*16 + i]);
  }
  for (int i = tid; i < 33*64; i += 256){
    int row = i >> 6, col = i & 63;
    tk[row*65 + col] = ldin(tbk, i, f32in);
    tv[row*65 + col] = ldin(tbv, i, f32in);
  }
  __syncthreads();
  {
    const int t = tid >> 4, s = tid & 15;
    float qk = 0.f, rpe = 0.f;
    #pragma unroll
    for (int c = 0; c < 64; ++c){
      qk  += qs[c*16 + t]*ks[c*16 + s];
      // faithful transposed-add: w[t,s] += scale * sum_c q[c,s]*rpk[(t-s)+16, c]
      rpe += qs[c*16 + s]*tk[(t - s + 16)*65 + c];
    }
    float logit = 0.125f*qk + 0.35355339059327373f*rpe;
    if (s > t) logit = -1e8f;  // causal, exactly NEG_INF like reference
    float mx = logit;
    #pragma unroll
    for (int off = 8; off; off >>= 1) mx = fmaxf(mx, __shfl_xor(mx, off, 16));
    float e = __expf(logit - mx);
    float tot = e;
    #pragma unroll
    for (int off = 8; off; off >>= 1) tot += __shfl_xor(tot, off, 16);
    ps[t*17 + s] = e / tot;
  }
  __syncthreads();
  {
    const int c4 = tid >> 4, t = tid & 15;
    #pragma unroll
    for (int u = 0; u < 4; ++u){
      int c = c4 + 16*u;
      float a = 0.f;
      #pragma unroll
      for (int s = 0; s < 16; ++s)
        a += ps[t*17 + s]*(vs[c*16 + s] + tv[(s - t + 16)*65 + c]);
      att[(ml*512 + head*64 + c)*16 + t] = f2b(a);
    }
  }
}

// ---------------------------------------------------------------- K8: temporal proj + residual -> out (dtype per flag)
__global__ __launch_bounds__(256) void k_proj_t(const bf16* __restrict__ X,
        const void* __restrict__ W, const void* __restrict__ Bv,
        const bf16* __restrict__ x2, void* __restrict__ out,
        const int* __restrict__ flag, int m0){
  const bool f32in = flag[0] != 0;
  const int o0 = blockIdx.x * 64;
  const int ml = blockIdx.y;
  const int m = m0 + ml;
  const int b = m / 576, l = m - b*576;
  const int tid = threadIdx.x;
  const int t = tid & 15, oi = tid >> 4;
  __shared__ float Xs[8192];
  __shared__ float Ws[64][33];
  for (int i = tid; i < 8192; i += 256) Xs[i] = b2f(X[ml*8192 + i]);
  float acc[4] = {};
  for (int kc = 0; kc < 512; kc += 32){
    __syncthreads();
    #pragma unroll
    for (int r = 0; r < 8; ++r){
      int e = tid + 256*r;
      Ws[e >> 5][e & 31] = ldin(W, (o0 + (e >> 5))*512 + kc + (e & 31), f32in);
    }
    __syncthreads();
    #pragma unroll
    for (int c = 0; c < 32; ++c){
      float xv = Xs[(kc + c)*16 + t];
      #pragma unroll
      for (int j = 0; j < 4; ++j) acc[j] += Ws[oi + 16*j][c]*xv;
    }
  }
  #pragma unroll
  for (int j = 0; j < 4; ++j){
    int o = o0 + oi + 16*j;
    int addr = ((b*512 + o)*16 + t)*576 + l;
    float val = b2f(x2[addr]) + acc[j] + ldin(Bv, o, f32in);
    // output dtype mirrors input dtype: f32 inputs -> f32 output, bf16 -> bf16
    if (f32in) ((float*)out)[addr] = val;
    else       ((bf16*)out)[addr] = f2b(val);
  }
}

// ----------------------------------------------------------------
extern "C" void kernel_launch(void* const* d_in, const int* in_sizes, int n_in,
                              void* d_out, int out_size, void* d_ws, size_t ws_size,
                              hipStream_t stream){
  const void* x   = d_in[0];
  const void* nsw = d_in[1];
  const void* nsb = d_in[2];
  const void* qsw = d_in[3];
  const void* qsb = d_in[4];
  const void* psw = d_in[5];
  const void* psb = d_in[6];
  const void* ntw = d_in[7];
  const void* ntb = d_in[8];
  const void* qtw = d_in[9];
  const void* qtb = d_in[10];
  const void* ptw = d_in[11];
  const void* ptb = d_in[12];
  const void* rpk = d_in[13];
  const void* rpv = d_in[14];

  // ws: 42.5 MB total
  int*  flag = (int*)d_ws;
  bf16* A  = (bf16*)((char*)d_ws + 256);   // 2,359,296: xn_s chunk / xn_t chunk
  bf16* A2 = A  + 2359296;                  // 2,359,296: att_s chunk / att_t chunk
  bf16* Bq = A2 + 2359296;                  // 7,077,888: qkv chunk
  bf16* Cx = Bq + 7077888;                  // 9,437,184: full residual stream

  k_detect<<<1, 64, 0, stream>>>(x, flag);

  // spatial phase: 4 chunks of 8 n
  for (int n0 = 0; n0 < 32; n0 += 8){
    k_gn_s  <<<dim3(32, 8),     256, 0, stream>>>(x, nsw, nsb, A, flag, n0);
    k_qkv_s <<<dim3(9, 24, 8),  256, 0, stream>>>(A, qsw, qsb, Bq, flag);
    k_attn_s<<<dim3(72, 64),    576, 0, stream>>>(Bq, A2);
    k_proj_s<<<dim3(9, 8, 8),   256, 0, stream>>>(A2, psw, psb, x, Cx, flag, n0);
  }
  // temporal phase: 4 chunks of 288 m
  for (int m0 = 0; m0 < 1152; m0 += 288){
    k_gn_t  <<<dim3(288),       256, 0, stream>>>(Cx, ntw, ntb, A, flag, m0);
    k_qkv_t <<<dim3(16, 288),   256, 0, stream>>>(A, qtw, qtb, Bq, flag);
    k_attn_t<<<dim3(8, 288),    256, 0, stream>>>(Bq, rpk, rpv, A2, flag);
    k_proj_t<<<dim3(8, 288),    256, 0, stream>>>(A2, ptw, ptb, Cx, d_out, flag, m0);
  }
}

// Round 5
// 1983.029 us; speedup vs baseline: 2.6447x; 2.6447x over previous
//
#include <hip/hip_runtime.h>
#include <hip/hip_bf16.h>

typedef __hip_bfloat16 bf16;
typedef __attribute__((ext_vector_type(8))) short v8s;
typedef __attribute__((ext_vector_type(4))) float v4f;

__device__ __forceinline__ float b2f(bf16 v){ return __bfloat162float(v); }
__device__ __forceinline__ bf16  f2b(float v){ return __float2bfloat16(v); }

// Inputs may be bf16 OR f32 — runtime-detected flag (1 => f32). Output dtype follows.
__device__ __forceinline__ float ldin(const void* p, int i, bool f32in){
  return f32in ? ((const float*)p)[i] : b2f(((const bf16*)p)[i]);
}

// stage 4 consecutive source elems (f32-or-bf16) into LDS as bf16 (one b64 write)
__device__ __forceinline__ void stage4(const void* src, size_t off, bool f32in, bf16* dst){
  union { bf16 h[4]; ushort4 u; } tmp;
  if (f32in){
    float4 f = *(const float4*)((const float*)src + off);
    tmp.h[0] = f2b(f.x); tmp.h[1] = f2b(f.y); tmp.h[2] = f2b(f.z); tmp.h[3] = f2b(f.w);
  } else {
    tmp.u = *(const ushort4*)((const ushort*)src + off);
  }
  *(ushort4*)dst = tmp.u;
}
__device__ __forceinline__ void stage4b(const bf16* src, bf16* dst){
  *(ushort4*)dst = *(const ushort4*)src;
}

// Problem: B=2, C=512, T=16, H=W=24, heads=8, ch=64
// spatial: 32 batches [512,576] in 4 chunks of 8 n; temporal: 1152 batches [512,16] in 4 chunks of 288 m
// ws (42.5 MB): flag | A 2,359,296 bf16 (xnT_s / xnT_t) | A2 2,359,296 (attT_s / attT_t)
//               | Bq 7,077,888 (qkv_s [o][l] / qkv_t [m][o][t]) | Cx 9,437,184 (x2 residual)

// ---------------------------------------------------------------- detect input dtype
__global__ void k_detect(const void* x, int* flag){
  int tid = threadIdx.x;
  const bf16* p = (const bf16*)x;
  int cnt = 0;
  for (int i = tid; i < 512; i += 64){
    float v = b2f(p[i]);
    if (!(fabsf(v) <= 64.f)) cnt++;
  }
  #pragma unroll
  for (int off = 32; off; off >>= 1) cnt += __shfl_down(cnt, off, 64);
  if (tid == 0) flag[0] = (cnt > 16) ? 1 : 0;
}

// ---------------------------------------------------------------- K1: spatial groupnorm -> xnT [l][c]
__global__ __launch_bounds__(256) void k_gn_s(const void* __restrict__ x,
        const void* __restrict__ gw, const void* __restrict__ gb,
        bf16* __restrict__ xnT, const int* __restrict__ flag, int n0){
  const bool f32in = flag[0] != 0;
  const int g = blockIdx.x;
  const int nl = blockIdx.y;
  const int n = n0 + nl;
  const int b = n >> 4, t = n & 15;
  const int tid = threadIdx.x;
  __shared__ float xs[576*17];     // [l][cg] padded
  __shared__ float red[4][2];
  __shared__ float stats[2];
  float s = 0.f, q = 0.f;
  for (int i = tid; i < 9216; i += 256){
    int cg = i / 576, l = i - cg*576;
    int c = g*16 + cg;
    float v = ldin(x, ((b*512 + c)*16 + t)*576 + l, f32in);
    xs[l*17 + cg] = v; s += v; q += v*v;
  }
  #pragma unroll
  for (int off = 32; off; off >>= 1){ s += __shfl_down(s, off, 64); q += __shfl_down(q, off, 64); }
  int wid = tid >> 6;
  if ((tid & 63) == 0){ red[wid][0] = s; red[wid][1] = q; }
  __syncthreads();
  if (tid == 0){
    float S = red[0][0]+red[1][0]+red[2][0]+red[3][0];
    float Q = red[0][1]+red[1][1]+red[2][1]+red[3][1];
    float mean = S * (1.f/9216.f);
    float var  = Q * (1.f/9216.f) - mean*mean;
    stats[0] = mean; stats[1] = rsqrtf(fmaxf(var, 0.f) + 1e-5f);
  }
  __syncthreads();
  float mean = stats[0], rstd = stats[1];
  for (int i = tid; i < 9216; i += 256){
    int l = i >> 4, cg = i & 15;
    int c = g*16 + cg;
    xnT[(size_t)(nl*576 + l)*512 + c] =
        f2b((xs[l*17 + cg] - mean)*rstd*ldin(gw, c, f32in) + ldin(gb, c, f32in));
  }
}

// ---------------------------------------------------------------- K2: spatial qkv GEMM (MFMA)
// Y[o][l] = sum_c W[o][c] * XT[l][c] + bias[o]; block 128o x 64l, BK=64
__global__ __launch_bounds__(256) void k_qkv_s_mfma(const bf16* __restrict__ XT,
        const void* __restrict__ W, const void* __restrict__ Bv,
        bf16* __restrict__ Y, const int* __restrict__ flag){
  const bool f32in = flag[0] != 0;
  const int o0 = blockIdx.x * 128;
  const int l0 = blockIdx.y * 64;
  const int nl = blockIdx.z;
  const int tid = threadIdx.x, lane = tid & 63;
  const int wm = (tid >> 6) & 1, wn = tid >> 7;
  const int r15 = lane & 15, quad = lane >> 4;
  __shared__ bf16 As[128*72];
  __shared__ bf16 Bs[64*72];
  v4f acc[4][2];
  #pragma unroll
  for (int i = 0; i < 4; ++i)
    #pragma unroll
    for (int j = 0; j < 2; ++j) acc[i][j] = (v4f){0.f,0.f,0.f,0.f};
  for (int kc = 0; kc < 512; kc += 64){
    __syncthreads();
    #pragma unroll
    for (int r = 0; r < 8; ++r){
      int e4 = (tid + 256*r)*4;
      int row = e4 >> 6, k = e4 & 63;
      stage4(W, (size_t)(o0+row)*512 + kc + k, f32in, &As[row*72 + k]);
    }
    #pragma unroll
    for (int r = 0; r < 4; ++r){
      int e4 = (tid + 256*r)*4;
      int row = e4 >> 6, k = e4 & 63;
      stage4b(&XT[(size_t)(nl*576 + l0 + row)*512 + kc + k], &Bs[row*72 + k]);
    }
    __syncthreads();
    #pragma unroll
    for (int ks = 0; ks < 2; ++ks){
      v8s a[4], b[2];
      #pragma unroll
      for (int mi = 0; mi < 4; ++mi)
        a[mi] = *(const v8s*)&As[(wm*64 + mi*16 + r15)*72 + ks*32 + quad*8];
      #pragma unroll
      for (int ni = 0; ni < 2; ++ni)
        b[ni] = *(const v8s*)&Bs[(wn*32 + ni*16 + r15)*72 + ks*32 + quad*8];
      #pragma unroll
      for (int mi = 0; mi < 4; ++mi)
        #pragma unroll
        for (int ni = 0; ni < 2; ++ni)
          acc[mi][ni] = __builtin_amdgcn_mfma_f32_16x16x32_bf16(a[mi], b[ni], acc[mi][ni], 0, 0, 0);
    }
  }
  #pragma unroll
  for (int mi = 0; mi < 4; ++mi)
    #pragma unroll
    for (int rg = 0; rg < 4; ++rg){
      int o = o0 + wm*64 + mi*16 + quad*4 + rg;
      float bia = ldin(Bv, o, f32in);
      #pragma unroll
      for (int ni = 0; ni < 2; ++ni){
        int l = l0 + wn*32 + ni*16 + r15;
        Y[(size_t)(nl*1536 + o)*576 + l] = f2b(acc[mi][ni][rg] + bia);
      }
    }
}

// ---------------------------------------------------------------- K3: spatial attention -> attT [l][c]
__global__ __launch_bounds__(576) void k_attn_s(const bf16* __restrict__ qkv,
        bf16* __restrict__ attT){
  const int tt0 = blockIdx.x;       // 0..71
  const int nh  = blockIdx.y;       // 0..63
  const int nl = nh >> 3, head = nh & 7;
  const int tid = threadIdx.x;      // 0..575
  __shared__ float qs[64][8];
  __shared__ float ps[8][576];
  __shared__ float red2[64][9][9];  // padded
  const int qb = (nl*1536 + head*64)*576;
  const int kb = (nl*1536 + 512 + head*64)*576;
  const int vb = (nl*1536 + 1024 + head*64)*576;
  if (tid < 512){
    int c = tid >> 3, tt = tid & 7;
    qs[c][tt] = b2f(qkv[qb + c*576 + tt0*8 + tt]);
  }
  __syncthreads();
  {
    float w[8] = {};
    const int s = tid;
    for (int c = 0; c < 64; ++c){
      float kc = b2f(qkv[kb + c*576 + s]);
      #pragma unroll
      for (int tt = 0; tt < 8; ++tt) w[tt] += qs[c][tt]*kc;
    }
    #pragma unroll
    for (int tt = 0; tt < 8; ++tt) ps[tt][s] = w[tt]*0.125f;  // scale^2 = 1/sqrt(64)
  }
  __syncthreads();
  {
    int wv = tid >> 6, lane = tid & 63;
    if (wv < 8){
      float m = -1e30f;
      #pragma unroll
      for (int k2 = 0; k2 < 9; ++k2) m = fmaxf(m, ps[wv][lane + 64*k2]);
      #pragma unroll
      for (int off = 32; off; off >>= 1) m = fmaxf(m, __shfl_xor(m, off, 64));
      float tot = 0.f;
      #pragma unroll
      for (int k2 = 0; k2 < 9; ++k2){
        int idx = lane + 64*k2;
        float e = __expf(ps[wv][idx] - m);
        ps[wv][idx] = e; tot += e;
      }
      #pragma unroll
      for (int off = 32; off; off >>= 1) tot += __shfl_xor(tot, off, 64);
      float r = 1.f / tot;
      #pragma unroll
      for (int k2 = 0; k2 < 9; ++k2) ps[wv][lane + 64*k2] *= r;
    }
  }
  __syncthreads();
  {
    int c = tid / 9, j = tid - c*9;
    float part[8] = {};
    for (int it = 0; it < 64; ++it){
      int s = it*9 + j;              // bank-conflict-free partitioning
      float v = b2f(qkv[vb + c*576 + s]);
      #pragma unroll
      for (int tt = 0; tt < 8; ++tt) part[tt] += ps[tt][s]*v;
    }
    #pragma unroll
    for (int tt = 0; tt < 8; ++tt) red2[c][j][tt] = part[tt];
  }
  __syncthreads();
  if (tid < 512){
    int c = tid >> 3, tt = tid & 7;
    float a = 0.f;
    #pragma unroll
    for (int j = 0; j < 9; ++j) a += red2[c][j][tt];
    attT[(size_t)(nl*576 + tt0*8 + tt)*512 + head*64 + c] = f2b(a);
  }
}

// ---------------------------------------------------------------- K4: spatial proj + residual (MFMA)
__global__ __launch_bounds__(256) void k_proj_s_mfma(const bf16* __restrict__ AT,
        const void* __restrict__ W, const void* __restrict__ Bv,
        const void* __restrict__ xin, bf16* __restrict__ x2,
        const int* __restrict__ flag, int n0){
  const bool f32in = flag[0] != 0;
  const int o0 = blockIdx.x * 128;
  const int l0 = blockIdx.y * 64;
  const int nl = blockIdx.z;
  const int n = n0 + nl;
  const int b = n >> 4, t = n & 15;
  const int tid = threadIdx.x, lane = tid & 63;
  const int wm = (tid >> 6) & 1, wn = tid >> 7;
  const int r15 = lane & 15, quad = lane >> 4;
  __shared__ bf16 As[128*72];
  __shared__ bf16 Bs[64*72];
  v4f acc[4][2];
  #pragma unroll
  for (int i = 0; i < 4; ++i)
    #pragma unroll
    for (int j = 0; j < 2; ++j) acc[i][j] = (v4f){0.f,0.f,0.f,0.f};
  for (int kc = 0; kc < 512; kc += 64){
    __syncthreads();
    #pragma unroll
    for (int r = 0; r < 8; ++r){
      int e4 = (tid + 256*r)*4;
      int row = e4 >> 6, k = e4 & 63;
      stage4(W, (size_t)(o0+row)*512 + kc + k, f32in, &As[row*72 + k]);
    }
    #pragma unroll
    for (int r = 0; r < 4; ++r){
      int e4 = (tid + 256*r)*4;
      int row = e4 >> 6, k = e4 & 63;
      stage4b(&AT[(size_t)(nl*576 + l0 + row)*512 + kc + k], &Bs[row*72 + k]);
    }
    __syncthreads();
    #pragma unroll
    for (int ks = 0; ks < 2; ++ks){
      v8s a[4], b[2];
      #pragma unroll
      for (int mi = 0; mi < 4; ++mi)
        a[mi] = *(const v8s*)&As[(wm*64 + mi*16 + r15)*72 + ks*32 + quad*8];
      #pragma unroll
      for (int ni = 0; ni < 2; ++ni)
        b[ni] = *(const v8s*)&Bs[(wn*32 + ni*16 + r15)*72 + ks*32 + quad*8];
      #pragma unroll
      for (int mi = 0; mi < 4; ++mi)
        #pragma unroll
        for (int ni = 0; ni < 2; ++ni)
          acc[mi][ni] = __builtin_amdgcn_mfma_f32_16x16x32_bf16(a[mi], b[ni], acc[mi][ni], 0, 0, 0);
    }
  }
  #pragma unroll
  for (int mi = 0; mi < 4; ++mi)
    #pragma unroll
    for (int rg = 0; rg < 4; ++rg){
      int o = o0 + wm*64 + mi*16 + quad*4 + rg;
      float bia = ldin(Bv, o, f32in);
      #pragma unroll
      for (int ni = 0; ni < 2; ++ni){
        int l = l0 + wn*32 + ni*16 + r15;
        size_t addr = ((size_t)(b*512 + o)*16 + t)*576 + l;
        x2[addr] = f2b(acc[mi][ni][rg] + bia + ldin(xin, addr, f32in));
      }
    }
}

// ---------------------------------------------------------------- K5: temporal groupnorm -> xnT [m][t][c]
__global__ __launch_bounds__(256) void k_gn_t(const bf16* __restrict__ x2,
        const void* __restrict__ gw, const void* __restrict__ gb,
        bf16* __restrict__ xnT, const int* __restrict__ flag, int m0){
  const bool f32in = flag[0] != 0;
  const int ml = blockIdx.x;
  const int m = m0 + ml;
  const int b = m / 576, l = m - b*576;
  const int tid = threadIdx.x;
  __shared__ float xs[8192];        // [t][c]
  __shared__ float mg[32], rg[32];
  for (int i = tid; i < 8192; i += 256){
    int t = i >> 9, c = i & 511;
    xs[i] = b2f(x2[((b*512 + c)*16 + t)*576 + l]);
  }
  __syncthreads();
  {
    int g = tid >> 3, ii = tid & 7;
    float s = 0.f, q = 0.f;
    for (int idx = ii; idx < 256; idx += 8){
      int t = idx >> 4, cg = idx & 15;
      float v = xs[t*512 + g*16 + cg]; s += v; q += v*v;
    }
    #pragma unroll
    for (int off = 1; off < 8; off <<= 1){ s += __shfl_xor(s, off, 64); q += __shfl_xor(q, off, 64); }
    if (ii == 0){
      float mean = s*(1.f/256.f);
      float var  = q*(1.f/256.f) - mean*mean;
      mg[g] = mean; rg[g] = rsqrtf(fmaxf(var, 0.f) + 1e-5f);
    }
  }
  __syncthreads();
  for (int i = tid; i < 8192; i += 256){
    int c = i & 511, g = c >> 4;
    xnT[(size_t)ml*8192 + i] = f2b((xs[i] - mg[g])*rg[g]*ldin(gw, c, f32in) + ldin(gb, c, f32in));
  }
}

// ---------------------------------------------------------------- K6: temporal qkv GEMM (MFMA, batched 4 m per block)
__global__ __launch_bounds__(256) void k_qkv_t_mfma(const bf16* __restrict__ XT,
        const void* __restrict__ W, const void* __restrict__ Bv,
        bf16* __restrict__ Y, const int* __restrict__ flag){
  const bool f32in = flag[0] != 0;
  const int o0 = blockIdx.x * 128;
  const int mg0 = blockIdx.y * 4;   // chunk-local m offset
  const int tid = threadIdx.x, lane = tid & 63;
  const int wm = (tid >> 6) & 1, wn = tid >> 7;
  const int r15 = lane & 15, quad = lane >> 4;
  __shared__ bf16 As[128*72];
  __shared__ bf16 Bs[64*72];
  v4f acc[4][2];
  #pragma unroll
  for (int i = 0; i < 4; ++i)
    #pragma unroll
    for (int j = 0; j < 2; ++j) acc[i][j] = (v4f){0.f,0.f,0.f,0.f};
  for (int kc = 0; kc < 512; kc += 64){
    __syncthreads();
    #pragma unroll
    for (int r = 0; r < 8; ++r){
      int e4 = (tid + 256*r)*4;
      int row = e4 >> 6, k = e4 & 63;
      stage4(W, (size_t)(o0+row)*512 + kc + k, f32in, &As[row*72 + k]);
    }
    #pragma unroll
    for (int r = 0; r < 4; ++r){
      int e4 = (tid + 256*r)*4;
      int row = e4 >> 6, k = e4 & 63;   // row = mi*16 + t
      stage4b(&XT[(size_t)(mg0 + (row >> 4))*8192 + (row & 15)*512 + kc + k], &Bs[row*72 + k]);
    }
    __syncthreads();
    #pragma unroll
    for (int ks = 0; ks < 2; ++ks){
      v8s a[4], b[2];
      #pragma unroll
      for (int mi = 0; mi < 4; ++mi)
        a[mi] = *(const v8s*)&As[(wm*64 + mi*16 + r15)*72 + ks*32 + quad*8];
      #pragma unroll
      for (int ni = 0; ni < 2; ++ni)
        b[ni] = *(const v8s*)&Bs[(wn*32 + ni*16 + r15)*72 + ks*32 + quad*8];
      #pragma unroll
      for (int mi = 0; mi < 4; ++mi)
        #pragma unroll
        for (int ni = 0; ni < 2; ++ni)
          acc[mi][ni] = __builtin_amdgcn_mfma_f32_16x16x32_bf16(a[mi], b[ni], acc[mi][ni], 0, 0, 0);
    }
  }
  #pragma unroll
  for (int mi = 0; mi < 4; ++mi)
    #pragma unroll
    for (int rg = 0; rg < 4; ++rg){
      int o = o0 + wm*64 + mi*16 + quad*4 + rg;
      float bia = ldin(Bv, o, f32in);
      #pragma unroll
      for (int ni = 0; ni < 2; ++ni){
        int nidx = wn*32 + ni*16 + r15;
        int mb = nidx >> 4, t = nidx & 15;
        Y[((size_t)(mg0 + mb)*1536 + o)*16 + t] = f2b(acc[mi][ni][rg] + bia);
      }
    }
}

// ---------------------------------------------------------------- K7: temporal attention -> attT [m][t][c]
__global__ __launch_bounds__(256) void k_attn_t(const bf16* __restrict__ qkv,
        const void* __restrict__ tbk, const void* __restrict__ tbv,
        bf16* __restrict__ attT, const int* __restrict__ flag){
  const bool f32in = flag[0] != 0;
  const int head = blockIdx.x;
  const int ml = blockIdx.y;
  const int tid = threadIdx.x;
  __shared__ float qs[1024], ks[1024], vs[1024];
  __shared__ float tk[33*65], tv[33*65];
  __shared__ float ps[16*17];
  const int base = (ml*1536 + head*64)*16;
  for (int i = tid; i < 1024; i += 256){
    qs[i] = b2f(qkv[base + i]);
    ks[i] = b2f(qkv[base + 512*16 + i]);
    vs[i] = b2f(qkv[base + 1024*16 + i]);
  }
  for (int i = tid; i < 33*64; i += 256){
    int row = i >> 6, col = i & 63;
    tk[row*65 + col] = ldin(tbk, i, f32in);
    tv[row*65 + col] = ldin(tbv, i, f32in);
  }
  __syncthreads();
  {
    const int t = tid >> 4, s = tid & 15;
    float qk = 0.f, rpe = 0.f;
    #pragma unroll
    for (int c = 0; c < 64; ++c){
      qk  += qs[c*16 + t]*ks[c*16 + s];
      rpe += qs[c*16 + s]*tk[(t - s + 16)*65 + c];
    }
    float logit = 0.125f*qk + 0.35355339059327373f*rpe;
    if (s > t) logit = -1e8f;
    float mx = logit;
    #pragma unroll
    for (int off = 8; off; off >>= 1) mx = fmaxf(mx, __shfl_xor(mx, off, 16));
    float e = __expf(logit - mx);
    float tot = e;
    #pragma unroll
    for (int off = 8; off; off >>= 1) tot += __shfl_xor(tot, off, 16);
    ps[t*17 + s] = e / tot;
  }
  __syncthreads();
  {
    const int c4 = tid >> 4, t = tid & 15;
    #pragma unroll
    for (int u = 0; u < 4; ++u){
      int c = c4 + 16*u;
      float a = 0.f;
      #pragma unroll
      for (int s = 0; s < 16; ++s)
        a += ps[t*17 + s]*(vs[c*16 + s] + tv[(s - t + 16)*65 + c]);
      attT[(size_t)ml*8192 + t*512 + head*64 + c] = f2b(a);
    }
  }
}

// ---------------------------------------------------------------- K8: temporal proj + residual -> out (MFMA)
__global__ __launch_bounds__(256) void k_proj_t_mfma(const bf16* __restrict__ AT,
        const void* __restrict__ W, const void* __restrict__ Bv,
        const bf16* __restrict__ x2, void* __restrict__ out,
        const int* __restrict__ flag, int m0){
  const bool f32in = flag[0] != 0;
  const int o0 = blockIdx.x * 128;
  const int mg0 = blockIdx.y * 4;
  const int tid = threadIdx.x, lane = tid & 63;
  const int wm = (tid >> 6) & 1, wn = tid >> 7;
  const int r15 = lane & 15, quad = lane >> 4;
  __shared__ bf16 As[128*72];
  __shared__ bf16 Bs[64*72];
  v4f acc[4][2];
  #pragma unroll
  for (int i = 0; i < 4; ++i)
    #pragma unroll
    for (int j = 0; j < 2; ++j) acc[i][j] = (v4f){0.f,0.f,0.f,0.f};
  for (int kc = 0; kc < 512; kc += 64){
    __syncthreads();
    #pragma unroll
    for (int r = 0; r < 8; ++r){
      int e4 = (tid + 256*r)*4;
      int row = e4 >> 6, k = e4 & 63;
      stage4(W, (size_t)(o0+row)*512 + kc + k, f32in, &As[row*72 + k]);
    }
    #pragma unroll
    for (int r = 0; r < 4; ++r){
      int e4 = (tid + 256*r)*4;
      int row = e4 >> 6, k = e4 & 63;
      stage4b(&AT[(size_t)(mg0 + (row >> 4))*8192 + (row & 15)*512 + kc + k], &Bs[row*72 + k]);
    }
    __syncthreads();
    #pragma unroll
    for (int ks = 0; ks < 2; ++ks){
      v8s a[4], b[2];
      #pragma unroll
      for (int mi = 0; mi < 4; ++mi)
        a[mi] = *(const v8s*)&As[(wm*64 + mi*16 + r15)*72 + ks*32 + quad*8];
      #pragma unroll
      for (int ni = 0; ni < 2; ++ni)
        b[ni] = *(const v8s*)&Bs[(wn*32 + ni*16 + r15)*72 + ks*32 + quad*8];
      #pragma unroll
      for (int mi = 0; mi < 4; ++mi)
        #pragma unroll
        for (int ni = 0; ni < 2; ++ni)
          acc[mi][ni] = __builtin_amdgcn_mfma_f32_16x16x32_bf16(a[mi], b[ni], acc[mi][ni], 0, 0, 0);
    }
  }
  #pragma unroll
  for (int mi = 0; mi < 4; ++mi)
    #pragma unroll
    for (int rg = 0; rg < 4; ++rg){
      int o = o0 + wm*64 + mi*16 + quad*4 + rg;
      float bia = ldin(Bv, o, f32in);
      #pragma unroll
      for (int ni = 0; ni < 2; ++ni){
        int nidx = wn*32 + ni*16 + r15;
        int mb = nidx >> 4, t = nidx & 15;
        int m = m0 + mg0 + mb;
        int b = m / 576, l = m - b*576;
        size_t addr = ((size_t)(b*512 + o)*16 + t)*576 + l;
        float val = acc[mi][ni][rg] + bia + b2f(x2[addr]);
        if (f32in) ((float*)out)[addr] = val;
        else       ((bf16*)out)[addr] = f2b(val);
      }
    }
}

// ----------------------------------------------------------------
extern "C" void kernel_launch(void* const* d_in, const int* in_sizes, int n_in,
                              void* d_out, int out_size, void* d_ws, size_t ws_size,
                              hipStream_t stream){
  const void* x   = d_in[0];
  const void* nsw = d_in[1];
  const void* nsb = d_in[2];
  const void* qsw = d_in[3];
  const void* qsb = d_in[4];
  const void* psw = d_in[5];
  const void* psb = d_in[6];
  const void* ntw = d_in[7];
  const void* ntb = d_in[8];
  const void* qtw = d_in[9];
  const void* qtb = d_in[10];
  const void* ptw = d_in[11];
  const void* ptb = d_in[12];
  const void* rpk = d_in[13];
  const void* rpv = d_in[14];

  int*  flag = (int*)d_ws;
  bf16* A  = (bf16*)((char*)d_ws + 256);   // 2,359,296: xnT_s / xnT_t chunk
  bf16* A2 = A  + 2359296;                  // 2,359,296: attT_s / attT_t chunk
  bf16* Bq = A2 + 2359296;                  // 7,077,888: qkv chunk
  bf16* Cx = Bq + 7077888;                  // 9,437,184: x2 residual stream

  k_detect<<<1, 64, 0, stream>>>(x, flag);

  // spatial phase: 4 chunks of 8 n
  for (int n0 = 0; n0 < 32; n0 += 8){
    k_gn_s      <<<dim3(32, 8),    256, 0, stream>>>(x, nsw, nsb, A, flag, n0);
    k_qkv_s_mfma<<<dim3(12, 9, 8), 256, 0, stream>>>(A, qsw, qsb, Bq, flag);
    k_attn_s    <<<dim3(72, 64),   576, 0, stream>>>(Bq, A2);
    k_proj_s_mfma<<<dim3(4, 9, 8), 256, 0, stream>>>(A2, psw, psb, x, Cx, flag, n0);
  }
  // temporal phase: 4 chunks of 288 m
  for (int m0 = 0; m0 < 1152; m0 += 288){
    k_gn_t      <<<dim3(288),      256, 0, stream>>>(Cx, ntw, ntb, A, flag, m0);
    k_qkv_t_mfma<<<dim3(12, 72),   256, 0, stream>>>(A, qtw, qtb, Bq, flag);
    k_attn_t    <<<dim3(8, 288),   256, 0, stream>>>(Bq, rpk, rpv, A2, flag);
    k_proj_t_mfma<<<dim3(4, 72),   256, 0, stream>>>(A2, ptw, ptb, Cx, d_out, flag, m0);
  }
}

// Round 6
// 1771.104 us; speedup vs baseline: 2.9611x; 1.1197x over previous
//
#include <hip/hip_runtime.h>
#include <hip/hip_bf16.h>

typedef __hip_bfloat16 bf16;
typedef __attribute__((ext_vector_type(8))) short v8s;
typedef __attribute__((ext_vector_type(4))) float v4f;

__device__ __forceinline__ float b2f(bf16 v){ return __bfloat162float(v); }
__device__ __forceinline__ bf16  f2b(float v){ return __float2bfloat16(v); }

// Inputs may be bf16 OR f32 — runtime-detected flag (1 => f32). Output dtype follows.
__device__ __forceinline__ float ldin(const void* p, int i, bool f32in){
  return f32in ? ((const float*)p)[i] : b2f(((const bf16*)p)[i]);
}

// stage 4 consecutive source elems (f32-or-bf16) into LDS as bf16
__device__ __forceinline__ void stage4(const void* src, size_t off, bool f32in, bf16* dst){
  union { bf16 h[4]; ushort4 u; } tmp;
  if (f32in){
    float4 f = *(const float4*)((const float*)src + off);
    tmp.h[0] = f2b(f.x); tmp.h[1] = f2b(f.y); tmp.h[2] = f2b(f.z); tmp.h[3] = f2b(f.w);
  } else {
    tmp.u = *(const ushort4*)((const ushort*)src + off);
  }
  *(ushort4*)dst = tmp.u;
}
__device__ __forceinline__ void stage4b(const bf16* src, bf16* dst){
  *(ushort4*)dst = *(const ushort4*)src;
}

// Problem: B=2, C=512, T=16, H=W=24, heads=8, ch=64
// spatial: 32 batches [512,576] in 4 chunks of 8 n; temporal: 1152 batches [512,16] in 4 chunks of 288 m
// ws (42.5 MB): flag | A 2,359,296 bf16 (xnT_s / xnT_t) | A2 2,359,296 (attT_s / attT_t)
//   | Bq 7,077,888 (spatial: QT[nl][576][512] + KT[nl][576][512] + V[nl][512][576]; temporal: [m][o][t])
//   | Cx 9,437,184 (x2 residual)

// ---------------------------------------------------------------- detect input dtype
__global__ void k_detect(const void* x, int* flag){
  int tid = threadIdx.x;
  const bf16* p = (const bf16*)x;
  int cnt = 0;
  for (int i = tid; i < 512; i += 64){
    float v = b2f(p[i]);
    if (!(fabsf(v) <= 64.f)) cnt++;
  }
  #pragma unroll
  for (int off = 32; off; off >>= 1) cnt += __shfl_down(cnt, off, 64);
  if (tid == 0) flag[0] = (cnt > 16) ? 1 : 0;
}

// ---------------------------------------------------------------- K1: spatial groupnorm -> xnT [l][c]
__global__ __launch_bounds__(256) void k_gn_s(const void* __restrict__ x,
        const void* __restrict__ gw, const void* __restrict__ gb,
        bf16* __restrict__ xnT, const int* __restrict__ flag, int n0){
  const bool f32in = flag[0] != 0;
  const int g = blockIdx.x;
  const int nl = blockIdx.y;
  const int n = n0 + nl;
  const int b = n >> 4, t = n & 15;
  const int tid = threadIdx.x;
  __shared__ float xs[576*17];     // [l][cg] padded
  __shared__ float red[4][2];
  __shared__ float stats[2];
  float s = 0.f, q = 0.f;
  for (int i = tid; i < 9216; i += 256){
    int cg = i / 576, l = i - cg*576;
    int c = g*16 + cg;
    float v = ldin(x, ((b*512 + c)*16 + t)*576 + l, f32in);
    xs[l*17 + cg] = v; s += v; q += v*v;
  }
  #pragma unroll
  for (int off = 32; off; off >>= 1){ s += __shfl_down(s, off, 64); q += __shfl_down(q, off, 64); }
  int wid = tid >> 6;
  if ((tid & 63) == 0){ red[wid][0] = s; red[wid][1] = q; }
  __syncthreads();
  if (tid == 0){
    float S = red[0][0]+red[1][0]+red[2][0]+red[3][0];
    float Q = red[0][1]+red[1][1]+red[2][1]+red[3][1];
    float mean = S * (1.f/9216.f);
    float var  = Q * (1.f/9216.f) - mean*mean;
    stats[0] = mean; stats[1] = rsqrtf(fmaxf(var, 0.f) + 1e-5f);
  }
  __syncthreads();
  float mean = stats[0], rstd = stats[1];
  for (int i = tid; i < 9216; i += 256){
    int l = i >> 4, cg = i & 15;
    int c = g*16 + cg;
    xnT[(size_t)(nl*576 + l)*512 + c] =
        f2b((xs[l*17 + cg] - mean)*rstd*ldin(gw, c, f32in) + ldin(gb, c, f32in));
  }
}

// ---------------------------------------------------------------- K2: spatial qkv GEMM (MFMA)
// D[l][o] = sum_c XT[l][c] * W[o][c] + bias[o]; block 64l x 128o, BK=64.
// Stores: Q -> QT[l][c], K -> KT[l][c] (c-contiguous), V -> V[c][l].
__global__ __launch_bounds__(256) void k_qkv_s_mfma(const bf16* __restrict__ XT,
        const void* __restrict__ W, const void* __restrict__ Bv,
        bf16* __restrict__ Y, const int* __restrict__ flag){
  const bool f32in = flag[0] != 0;
  const int l0 = blockIdx.x * 64;
  const int o0 = blockIdx.y * 128;
  const int nl = blockIdx.z;
  const int tid = threadIdx.x, lane = tid & 63;
  const int wm = (tid >> 6) & 1, wn = tid >> 7;
  const int r15 = lane & 15, quad = lane >> 4;
  __shared__ bf16 As[64*72];    // XT rows (l)
  __shared__ bf16 Bs[128*72];   // W rows (o)
  v4f acc[2][4];
  #pragma unroll
  for (int i = 0; i < 2; ++i)
    #pragma unroll
    for (int j = 0; j < 4; ++j) acc[i][j] = (v4f){0.f,0.f,0.f,0.f};
  for (int kc = 0; kc < 512; kc += 64){
    __syncthreads();
    #pragma unroll
    for (int r = 0; r < 4; ++r){
      int e4 = (tid + 256*r)*4;
      int row = e4 >> 6, k = e4 & 63;
      stage4b(&XT[(size_t)(nl*576 + l0 + row)*512 + kc + k], &As[row*72 + k]);
    }
    #pragma unroll
    for (int r = 0; r < 8; ++r){
      int e4 = (tid + 256*r)*4;
      int row = e4 >> 6, k = e4 & 63;
      stage4(W, (size_t)(o0+row)*512 + kc + k, f32in, &Bs[row*72 + k]);
    }
    __syncthreads();
    #pragma unroll
    for (int ks = 0; ks < 2; ++ks){
      v8s a[2], b[4];
      #pragma unroll
      for (int mi = 0; mi < 2; ++mi)
        a[mi] = *(const v8s*)&As[(wm*32 + mi*16 + r15)*72 + ks*32 + quad*8];
      #pragma unroll
      for (int ni = 0; ni < 4; ++ni)
        b[ni] = *(const v8s*)&Bs[(wn*64 + ni*16 + r15)*72 + ks*32 + quad*8];
      #pragma unroll
      for (int mi = 0; mi < 2; ++mi)
        #pragma unroll
        for (int ni = 0; ni < 4; ++ni)
          acc[mi][ni] = __builtin_amdgcn_mfma_f32_16x16x32_bf16(a[mi], b[ni], acc[mi][ni], 0, 0, 0);
    }
  }
  const int seg = o0 >> 9;  // 0=Q,1=K,2=V (BN=128 divides 512 -> uniform per block)
  size_t segbase = (seg==0) ? (size_t)nl*294912
                 : (seg==1) ? 2359296u + (size_t)nl*294912
                            : 4718592u + (size_t)nl*294912;
  const int ob = o0 & 511;
  #pragma unroll
  for (int mi = 0; mi < 2; ++mi)
    #pragma unroll
    for (int ni = 0; ni < 4; ++ni){
      int oseg = ob + wn*64 + ni*16 + r15;
      float bia = ldin(Bv, o0 + wn*64 + ni*16 + r15, f32in);
      #pragma unroll
      for (int rg = 0; rg < 4; ++rg){
        int l = l0 + wm*32 + mi*16 + quad*4 + rg;
        float val = acc[mi][ni][rg] + bia;
        size_t dst = (seg==2) ? segbase + (size_t)oseg*576 + l
                              : segbase + (size_t)l*512 + oseg;
        Y[dst] = f2b(val);
      }
    }
}

// ---------------------------------------------------------------- K3: spatial attention (MFMA) -> attT [l][c]
// block: (t-tile of 64, nl*8+head). 4 waves; wave w owns q-rows w*16..w*16+15.
__global__ __launch_bounds__(256, 2) void k_attn_s_mfma(const bf16* __restrict__ qkv,
        bf16* __restrict__ attT){
  const int t0 = blockIdx.x;        // 0..8
  const int nh = blockIdx.y;        // 0..63
  const int nl = nh >> 3, head = nh & 7;
  const int tid = threadIdx.x, lane = tid & 63, w = tid >> 6;
  const int r15 = lane & 15, quad = lane >> 4;
  __shared__ bf16 P[64*600];        // stride 600: 16B-aligned rows, ~2-way banks
  const bf16* QT = qkv + (size_t)nl*294912;
  const bf16* KT = qkv + 2359296u + (size_t)nl*294912;
  const bf16* Vp = qkv + 4718592u + (size_t)nl*294912;
  const int c0 = head*64;
  // Q A-fragments (2 ksteps of 32), resident for the whole S phase
  v8s aq0, aq1;
  {
    const bf16* qrow = QT + (size_t)(t0*64 + w*16 + r15)*512 + c0;
    aq0 = *(const v8s*)(qrow + quad*8);
    aq1 = *(const v8s*)(qrow + 32 + quad*8);
  }
  // ---- phase 1: S = (q*scale)·(k*scale)^T, full 576 s in registers
  v4f acc[36];
  #pragma unroll
  for (int st = 0; st < 36; ++st) acc[st] = (v4f){0.f,0.f,0.f,0.f};
  #pragma unroll 4
  for (int st = 0; st < 36; ++st){
    const bf16* krow = KT + (size_t)(st*16 + r15)*512 + c0;
    v8s b0 = *(const v8s*)(krow + quad*8);
    v8s b1 = *(const v8s*)(krow + 32 + quad*8);
    acc[st] = __builtin_amdgcn_mfma_f32_16x16x32_bf16(aq0, b0, acc[st], 0, 0, 0);
    acc[st] = __builtin_amdgcn_mfma_f32_16x16x32_bf16(aq1, b1, acc[st], 0, 0, 0);
  }
  // ---- softmax over s (rows owned by (quad,rg); cols spread over r15 x 36 tiles)
  float mx[4] = {-1e30f,-1e30f,-1e30f,-1e30f};
  #pragma unroll
  for (int st = 0; st < 36; ++st)
    #pragma unroll
    for (int rg = 0; rg < 4; ++rg){
      float v = acc[st][rg]*0.125f;  // scale^2 = 1/sqrt(64)
      acc[st][rg] = v;
      mx[rg] = fmaxf(mx[rg], v);
    }
  #pragma unroll
  for (int off = 1; off < 16; off <<= 1)
    #pragma unroll
    for (int rg = 0; rg < 4; ++rg) mx[rg] = fmaxf(mx[rg], __shfl_xor(mx[rg], off, 64));
  float sm[4] = {0.f,0.f,0.f,0.f};
  #pragma unroll
  for (int st = 0; st < 36; ++st)
    #pragma unroll
    for (int rg = 0; rg < 4; ++rg){
      float e = __expf(acc[st][rg] - mx[rg]);
      acc[st][rg] = e; sm[rg] += e;
    }
  #pragma unroll
  for (int off = 1; off < 16; off <<= 1)
    #pragma unroll
    for (int rg = 0; rg < 4; ++rg) sm[rg] += __shfl_xor(sm[rg], off, 64);
  float inv[4];
  #pragma unroll
  for (int rg = 0; rg < 4; ++rg) inv[rg] = 1.f / sm[rg];
  // ---- write P rows (this wave's 16 rows only; consumed by same wave below)
  #pragma unroll
  for (int st = 0; st < 36; ++st)
    #pragma unroll
    for (int rg = 0; rg < 4; ++rg)
      P[(w*16 + quad*4 + rg)*600 + st*16 + r15] = f2b(acc[st][rg]*inv[rg]);
  // ---- phase 2: O = P · V^T  (contraction over s, B-frags direct from global V[c][s])
  v4f oc[4];
  #pragma unroll
  for (int ni = 0; ni < 4; ++ni) oc[ni] = (v4f){0.f,0.f,0.f,0.f};
  #pragma unroll 3
  for (int ks = 0; ks < 18; ++ks){
    v8s a = *(const v8s*)&P[(w*16 + r15)*600 + ks*32 + quad*8];
    #pragma unroll
    for (int ni = 0; ni < 4; ++ni){
      v8s b = *(const v8s*)(Vp + (size_t)(c0 + ni*16 + r15)*576 + ks*32 + quad*8);
      oc[ni] = __builtin_amdgcn_mfma_f32_16x16x32_bf16(a, b, oc[ni], 0, 0, 0);
    }
  }
  #pragma unroll
  for (int ni = 0; ni < 4; ++ni)
    #pragma unroll
    for (int rg = 0; rg < 4; ++rg){
      int t = t0*64 + w*16 + quad*4 + rg;
      attT[(size_t)(nl*576 + t)*512 + c0 + ni*16 + r15] = f2b(oc[ni][rg]);
    }
}

// ---------------------------------------------------------------- K4: spatial proj + residual (MFMA)
__global__ __launch_bounds__(256) void k_proj_s_mfma(const bf16* __restrict__ AT,
        const void* __restrict__ W, const void* __restrict__ Bv,
        const void* __restrict__ xin, bf16* __restrict__ x2,
        const int* __restrict__ flag, int n0){
  const bool f32in = flag[0] != 0;
  const int o0 = blockIdx.x * 128;
  const int l0 = blockIdx.y * 64;
  const int nl = blockIdx.z;
  const int n = n0 + nl;
  const int b = n >> 4, t = n & 15;
  const int tid = threadIdx.x, lane = tid & 63;
  const int wm = (tid >> 6) & 1, wn = tid >> 7;
  const int r15 = lane & 15, quad = lane >> 4;
  __shared__ bf16 As[128*72];
  __shared__ bf16 Bs[64*72];
  v4f acc[4][2];
  #pragma unroll
  for (int i = 0; i < 4; ++i)
    #pragma unroll
    for (int j = 0; j < 2; ++j) acc[i][j] = (v4f){0.f,0.f,0.f,0.f};
  for (int kc = 0; kc < 512; kc += 64){
    __syncthreads();
    #pragma unroll
    for (int r = 0; r < 8; ++r){
      int e4 = (tid + 256*r)*4;
      int row = e4 >> 6, k = e4 & 63;
      stage4(W, (size_t)(o0+row)*512 + kc + k, f32in, &As[row*72 + k]);
    }
    #pragma unroll
    for (int r = 0; r < 4; ++r){
      int e4 = (tid + 256*r)*4;
      int row = e4 >> 6, k = e4 & 63;
      stage4b(&AT[(size_t)(nl*576 + l0 + row)*512 + kc + k], &Bs[row*72 + k]);
    }
    __syncthreads();
    #pragma unroll
    for (int ks = 0; ks < 2; ++ks){
      v8s a[4], b[2];
      #pragma unroll
      for (int mi = 0; mi < 4; ++mi)
        a[mi] = *(const v8s*)&As[(wm*64 + mi*16 + r15)*72 + ks*32 + quad*8];
      #pragma unroll
      for (int ni = 0; ni < 2; ++ni)
        b[ni] = *(const v8s*)&Bs[(wn*32 + ni*16 + r15)*72 + ks*32 + quad*8];
      #pragma unroll
      for (int mi = 0; mi < 4; ++mi)
        #pragma unroll
        for (int ni = 0; ni < 2; ++ni)
          acc[mi][ni] = __builtin_amdgcn_mfma_f32_16x16x32_bf16(a[mi], b[ni], acc[mi][ni], 0, 0, 0);
    }
  }
  #pragma unroll
  for (int mi = 0; mi < 4; ++mi)
    #pragma unroll
    for (int rg = 0; rg < 4; ++rg){
      int o = o0 + wm*64 + mi*16 + quad*4 + rg;
      float bia = ldin(Bv, o, f32in);
      #pragma unroll
      for (int ni = 0; ni < 2; ++ni){
        int l = l0 + wn*32 + ni*16 + r15;
        size_t addr = ((size_t)(b*512 + o)*16 + t)*576 + l;
        x2[addr] = f2b(acc[mi][ni][rg] + bia + ldin(xin, addr, f32in));
      }
    }
}

// ---------------------------------------------------------------- K5: temporal groupnorm -> xnT [m][t][c]
__global__ __launch_bounds__(256) void k_gn_t(const bf16* __restrict__ x2,
        const void* __restrict__ gw, const void* __restrict__ gb,
        bf16* __restrict__ xnT, const int* __restrict__ flag, int m0){
  const bool f32in = flag[0] != 0;
  const int ml = blockIdx.x;
  const int m = m0 + ml;
  const int b = m / 576, l = m - b*576;
  const int tid = threadIdx.x;
  __shared__ float xs[8192];        // [t][c]
  __shared__ float mg[32], rg[32];
  for (int i = tid; i < 8192; i += 256){
    int t = i >> 9, c = i & 511;
    xs[i] = b2f(x2[((b*512 + c)*16 + t)*576 + l]);
  }
  __syncthreads();
  {
    int g = tid >> 3, ii = tid & 7;
    float s = 0.f, q = 0.f;
    for (int idx = ii; idx < 256; idx += 8){
      int t = idx >> 4, cg = idx & 15;
      float v = xs[t*512 + g*16 + cg]; s += v; q += v*v;
    }
    #pragma unroll
    for (int off = 1; off < 8; off <<= 1){ s += __shfl_xor(s, off, 64); q += __shfl_xor(q, off, 64); }
    if (ii == 0){
      float mean = s*(1.f/256.f);
      float var  = q*(1.f/256.f) - mean*mean;
      mg[g] = mean; rg[g] = rsqrtf(fmaxf(var, 0.f) + 1e-5f);
    }
  }
  __syncthreads();
  for (int i = tid; i < 8192; i += 256){
    int c = i & 511, g = c >> 4;
    xnT[(size_t)ml*8192 + i] = f2b((xs[i] - mg[g])*rg[g]*ldin(gw, c, f32in) + ldin(gb, c, f32in));
  }
}

// ---------------------------------------------------------------- K6: temporal qkv GEMM (MFMA, 4 m per block)
__global__ __launch_bounds__(256) void k_qkv_t_mfma(const bf16* __restrict__ XT,
        const void* __restrict__ W, const void* __restrict__ Bv,
        bf16* __restrict__ Y, const int* __restrict__ flag){
  const bool f32in = flag[0] != 0;
  const int o0 = blockIdx.x * 128;
  const int mg0 = blockIdx.y * 4;
  const int tid = threadIdx.x, lane = tid & 63;
  const int wm = (tid >> 6) & 1, wn = tid >> 7;
  const int r15 = lane & 15, quad = lane >> 4;
  __shared__ bf16 As[128*72];
  __shared__ bf16 Bs[64*72];
  v4f acc[4][2];
  #pragma unroll
  for (int i = 0; i < 4; ++i)
    #pragma unroll
    for (int j = 0; j < 2; ++j) acc[i][j] = (v4f){0.f,0.f,0.f,0.f};
  for (int kc = 0; kc < 512; kc += 64){
    __syncthreads();
    #pragma unroll
    for (int r = 0; r < 8; ++r){
      int e4 = (tid + 256*r)*4;
      int row = e4 >> 6, k = e4 & 63;
      stage4(W, (size_t)(o0+row)*512 + kc + k, f32in, &As[row*72 + k]);
    }
    #pragma unroll
    for (int r = 0; r < 4; ++r){
      int e4 = (tid + 256*r)*4;
      int row = e4 >> 6, k = e4 & 63;
      stage4b(&XT[(size_t)(mg0 + (row >> 4))*8192 + (row & 15)*512 + kc + k], &Bs[row*72 + k]);
    }
    __syncthreads();
    #pragma unroll
    for (int ks = 0; ks < 2; ++ks){
      v8s a[4], b[2];
      #pragma unroll
      for (int mi = 0; mi < 4; ++mi)
        a[mi] = *(const v8s*)&As[(wm*64 + mi*16 + r15)*72 + ks*32 + quad*8];
      #pragma unroll
      for (int ni = 0; ni < 2; ++ni)
        b[ni] = *(const v8s*)&Bs[(wn*32 + ni*16 + r15)*72 + ks*32 + quad*8];
      #pragma unroll
      for (int mi = 0; mi < 4; ++mi)
        #pragma unroll
        for (int ni = 0; ni < 2; ++ni)
          acc[mi][ni] = __builtin_amdgcn_mfma_f32_16x16x32_bf16(a[mi], b[ni], acc[mi][ni], 0, 0, 0);
    }
  }
  #pragma unroll
  for (int mi = 0; mi < 4; ++mi)
    #pragma unroll
    for (int rg = 0; rg < 4; ++rg){
      int o = o0 + wm*64 + mi*16 + quad*4 + rg;
      float bia = ldin(Bv, o, f32in);
      #pragma unroll
      for (int ni = 0; ni < 2; ++ni){
        int nidx = wn*32 + ni*16 + r15;
        int mb = nidx >> 4, t = nidx & 15;
        Y[((size_t)(mg0 + mb)*1536 + o)*16 + t] = f2b(acc[mi][ni][rg] + bia);
      }
    }
}

// ---------------------------------------------------------------- K7: temporal attention -> attT [m][t][c]
__global__ __launch_bounds__(256) void k_attn_t(const bf16* __restrict__ qkv,
        const void* __restrict__ tbk, const void* __restrict__ tbv,
        bf16* __restrict__ attT, const int* __restrict__ flag){
  const bool f32in = flag[0] != 0;
  const int head = blockIdx.x;
  const int ml = blockIdx.y;
  const int tid = threadIdx.x;
  __shared__ float qs[1024], ks[1024], vs[1024];
  __shared__ float tk[33*65], tv[33*65];
  __shared__ float ps[16*17];
  const int base = (ml*1536 + head*64)*16;
  for (int i = tid; i < 1024; i += 256){
    qs[i] = b2f(qkv[base + i]);
    ks[i] = b2f(qkv[base + 512*16 + i]);
    vs[i] = b2f(qkv[base + 1024*16 + i]);
  }
  for (int i = tid; i < 33*64; i += 256){
    int row = i >> 6, col = i & 63;
    tk[row*65 + col] = ldin(tbk, i, f32in);
    tv[row*65 + col] = ldin(tbv, i, f32in);
  }
  __syncthreads();
  {
    const int t = tid >> 4, s = tid & 15;
    float qk = 0.f, rpe = 0.f;
    #pragma unroll
    for (int c = 0; c < 64; ++c){
      qk  += qs[c*16 + t]*ks[c*16 + s];
      rpe += qs[c*16 + s]*tk[(t - s + 16)*65 + c];
    }
    float logit = 0.125f*qk + 0.35355339059327373f*rpe;
    if (s > t) logit = -1e8f;
    float mx = logit;
    #pragma unroll
    for (int off = 8; off; off >>= 1) mx = fmaxf(mx, __shfl_xor(mx, off, 16));
    float e = __expf(logit - mx);
    float tot = e;
    #pragma unroll
    for (int off = 8; off; off >>= 1) tot += __shfl_xor(tot, off, 16);
    ps[t*17 + s] = e / tot;
  }
  __syncthreads();
  {
    const int c4 = tid >> 4, t = tid & 15;
    #pragma unroll
    for (int u = 0; u < 4; ++u){
      int c = c4 + 16*u;
      float a = 0.f;
      #pragma unroll
      for (int s = 0; s < 16; ++s)
        a += ps[t*17 + s]*(vs[c*16 + s] + tv[(s - t + 16)*65 + c]);
      attT[(size_t)ml*8192 + t*512 + head*64 + c] = f2b(a);
    }
  }
}

// ---------------------------------------------------------------- K8: temporal proj + residual -> out (MFMA)
__global__ __launch_bounds__(256) void k_proj_t_mfma(const bf16* __restrict__ AT,
        const void* __restrict__ W, const void* __restrict__ Bv,
        const bf16* __restrict__ x2, void* __restrict__ out,
        const int* __restrict__ flag, int m0){
  const bool f32in = flag[0] != 0;
  const int o0 = blockIdx.x * 128;
  const int mg0 = blockIdx.y * 4;
  const int tid = threadIdx.x, lane = tid & 63;
  const int wm = (tid >> 6) & 1, wn = tid >> 7;
  const int r15 = lane & 15, quad = lane >> 4;
  __shared__ bf16 As[128*72];
  __shared__ bf16 Bs[64*72];
  v4f acc[4][2];
  #pragma unroll
  for (int i = 0; i < 4; ++i)
    #pragma unroll
    for (int j = 0; j < 2; ++j) acc[i][j] = (v4f){0.f,0.f,0.f,0.f};
  for (int kc = 0; kc < 512; kc += 64){
    __syncthreads();
    #pragma unroll
    for (int r = 0; r < 8; ++r){
      int e4 = (tid + 256*r)*4;
      int row = e4 >> 6, k = e4 & 63;
      stage4(W, (size_t)(o0+row)*512 + kc + k, f32in, &As[row*72 + k]);
    }
    #pragma unroll
    for (int r = 0; r < 4; ++r){
      int e4 = (tid + 256*r)*4;
      int row = e4 >> 6, k = e4 & 63;
      stage4b(&AT[(size_t)(mg0 + (row >> 4))*8192 + (row & 15)*512 + kc + k], &Bs[row*72 + k]);
    }
    __syncthreads();
    #pragma unroll
    for (int ks = 0; ks < 2; ++ks){
      v8s a[4], b[2];
      #pragma unroll
      for (int mi = 0; mi < 4; ++mi)
        a[mi] = *(const v8s*)&As[(wm*64 + mi*16 + r15)*72 + ks*32 + quad*8];
      #pragma unroll
      for (int ni = 0; ni < 2; ++ni)
        b[ni] = *(const v8s*)&Bs[(wn*32 + ni*16 + r15)*72 + ks*32 + quad*8];
      #pragma unroll
      for (int mi = 0; mi < 4; ++mi)
        #pragma unroll
        for (int ni = 0; ni < 2; ++ni)
          acc[mi][ni] = __builtin_amdgcn_mfma_f32_16x16x32_bf16(a[mi], b[ni], acc[mi][ni], 0, 0, 0);
    }
  }
  #pragma unroll
  for (int mi = 0; mi < 4; ++mi)
    #pragma unroll
    for (int rg = 0; rg < 4; ++rg){
      int o = o0 + wm*64 + mi*16 + quad*4 + rg;
      float bia = ldin(Bv, o, f32in);
      #pragma unroll
      for (int ni = 0; ni < 2; ++ni){
        int nidx = wn*32 + ni*16 + r15;
        int mb = nidx >> 4, t = nidx & 15;
        int m = m0 + mg0 + mb;
        int b = m / 576, l = m - b*576;
        size_t addr = ((size_t)(b*512 + o)*16 + t)*576 + l;
        float val = acc[mi][ni][rg] + bia + b2f(x2[addr]);
        if (f32in) ((float*)out)[addr] = val;
        else       ((bf16*)out)[addr] = f2b(val);
      }
    }
}

// ----------------------------------------------------------------
extern "C" void kernel_launch(void* const* d_in, const int* in_sizes, int n_in,
                              void* d_out, int out_size, void* d_ws, size_t ws_size,
                              hipStream_t stream){
  const void* x   = d_in[0];
  const void* nsw = d_in[1];
  const void* nsb = d_in[2];
  const void* qsw = d_in[3];
  const void* qsb = d_in[4];
  const void* psw = d_in[5];
  const void* psb = d_in[6];
  const void* ntw = d_in[7];
  const void* ntb = d_in[8];
  const void* qtw = d_in[9];
  const void* qtb = d_in[10];
  const void* ptw = d_in[11];
  const void* ptb = d_in[12];
  const void* rpk = d_in[13];
  const void* rpv = d_in[14];

  int*  flag = (int*)d_ws;
  bf16* A  = (bf16*)((char*)d_ws + 256);   // 2,359,296: xnT_s / xnT_t chunk
  bf16* A2 = A  + 2359296;                  // 2,359,296: attT_s / attT_t chunk
  bf16* Bq = A2 + 2359296;                  // 7,077,888: qkv chunk
  bf16* Cx = Bq + 7077888;                  // 9,437,184: x2 residual stream

  k_detect<<<1, 64, 0, stream>>>(x, flag);

  // spatial phase: 4 chunks of 8 n
  for (int n0 = 0; n0 < 32; n0 += 8){
    k_gn_s       <<<dim3(32, 8),    256, 0, stream>>>(x, nsw, nsb, A, flag, n0);
    k_qkv_s_mfma <<<dim3(9, 12, 8), 256, 0, stream>>>(A, qsw, qsb, Bq, flag);
    k_attn_s_mfma<<<dim3(9, 64),    256, 0, stream>>>(Bq, A2);
    k_proj_s_mfma<<<dim3(4, 9, 8),  256, 0, stream>>>(A2, psw, psb, x, Cx, flag, n0);
  }
  // temporal phase: 4 chunks of 288 m
  for (int m0 = 0; m0 < 1152; m0 += 288){
    k_gn_t       <<<dim3(288),      256, 0, stream>>>(Cx, ntw, ntb, A, flag, m0);
    k_qkv_t_mfma <<<dim3(12, 72),   256, 0, stream>>>(A, qtw, qtb, Bq, flag);
    k_attn_t     <<<dim3(8, 288),   256, 0, stream>>>(Bq, rpk, rpv, A2, flag);
    k_proj_t_mfma<<<dim3(4, 72),    256, 0, stream>>>(A2, ptw, ptb, Cx, d_out, flag, m0);
  }
}

// Round 7
// 1451.517 us; speedup vs baseline: 3.6131x; 1.2202x over previous
//
#include <hip/hip_runtime.h>
#include <hip/hip_bf16.h>

typedef __hip_bfloat16 bf16;
typedef __attribute__((ext_vector_type(8))) short v8s;
typedef __attribute__((ext_vector_type(4))) float v4f;

__device__ __forceinline__ float b2f(bf16 v){ return __bfloat162float(v); }
__device__ __forceinline__ bf16  f2b(float v){ return __float2bfloat16(v); }

// Inputs may be bf16 OR f32 — runtime-detected flag (1 => f32). Output dtype follows.
__device__ __forceinline__ float ldin(const void* p, int i, bool f32in){
  return f32in ? ((const float*)p)[i] : b2f(((const bf16*)p)[i]);
}

// stage 4 consecutive source elems (f32-or-bf16) into LDS as bf16
__device__ __forceinline__ void stage4(const void* src, size_t off, bool f32in, bf16* dst){
  union { bf16 h[4]; ushort4 u; } tmp;
  if (f32in){
    float4 f = *(const float4*)((const float*)src + off);
    tmp.h[0] = f2b(f.x); tmp.h[1] = f2b(f.y); tmp.h[2] = f2b(f.z); tmp.h[3] = f2b(f.w);
  } else {
    tmp.u = *(const ushort4*)((const ushort*)src + off);
  }
  *(ushort4*)dst = tmp.u;
}
__device__ __forceinline__ void stage4b(const bf16* src, bf16* dst){
  *(ushort4*)dst = *(const ushort4*)src;
}

// Problem: B=2, C=512, T=16, H=W=24, heads=8, ch=64
// spatial: 32 batches [512,576] in 4 chunks of 8 n; temporal: 1152 batches [512,16] in 4 chunks of 288 m
// ws (42.5 MB): flag | A 2,359,296 bf16 (xnT_s / xnT_t) | A2 2,359,296 (attT_s / attT_t)
//   | Bq 7,077,888 (spatial: QT[nl][576][512] + KT[nl][576][512] + V[nl][512][576]; temporal: [m][o][t])
//   | Cx 9,437,184 (x2 residual)

// ---------------------------------------------------------------- detect input dtype
__global__ void k_detect(const void* x, int* flag){
  int tid = threadIdx.x;
  const bf16* p = (const bf16*)x;
  int cnt = 0;
  for (int i = tid; i < 512; i += 64){
    float v = b2f(p[i]);
    if (!(fabsf(v) <= 64.f)) cnt++;
  }
  #pragma unroll
  for (int off = 32; off; off >>= 1) cnt += __shfl_down(cnt, off, 64);
  if (tid == 0) flag[0] = (cnt > 16) ? 1 : 0;
}

// ---------------------------------------------------------------- K1: spatial groupnorm -> xnT [l][c]
__global__ __launch_bounds__(256) void k_gn_s(const void* __restrict__ x,
        const void* __restrict__ gw, const void* __restrict__ gb,
        bf16* __restrict__ xnT, const int* __restrict__ flag, int n0){
  const bool f32in = flag[0] != 0;
  const int g = blockIdx.x;
  const int nl = blockIdx.y;
  const int n = n0 + nl;
  const int b = n >> 4, t = n & 15;
  const int tid = threadIdx.x;
  __shared__ float xs[576*17];     // [l][cg] padded
  __shared__ float red[4][2];
  __shared__ float stats[2];
  float s = 0.f, q = 0.f;
  for (int i = tid; i < 9216; i += 256){
    int cg = i / 576, l = i - cg*576;
    int c = g*16 + cg;
    float v = ldin(x, ((b*512 + c)*16 + t)*576 + l, f32in);
    xs[l*17 + cg] = v; s += v; q += v*v;
  }
  #pragma unroll
  for (int off = 32; off; off >>= 1){ s += __shfl_down(s, off, 64); q += __shfl_down(q, off, 64); }
  int wid = tid >> 6;
  if ((tid & 63) == 0){ red[wid][0] = s; red[wid][1] = q; }
  __syncthreads();
  if (tid == 0){
    float S = red[0][0]+red[1][0]+red[2][0]+red[3][0];
    float Q = red[0][1]+red[1][1]+red[2][1]+red[3][1];
    float mean = S * (1.f/9216.f);
    float var  = Q * (1.f/9216.f) - mean*mean;
    stats[0] = mean; stats[1] = rsqrtf(fmaxf(var, 0.f) + 1e-5f);
  }
  __syncthreads();
  float mean = stats[0], rstd = stats[1];
  for (int i = tid; i < 9216; i += 256){
    int l = i >> 4, cg = i & 15;
    int c = g*16 + cg;
    xnT[(size_t)(nl*576 + l)*512 + c] =
        f2b((xs[l*17 + cg] - mean)*rstd*ldin(gw, c, f32in) + ldin(gb, c, f32in));
  }
}

// ---------------------------------------------------------------- K2: spatial qkv GEMM (MFMA)
// D[l][o] = sum_c XT[l][c] * W[o][c] + bias[o]; block 64l x 128o, BK=64.
// Stores: Q -> QT[l][c], K -> KT[l][c] (c-contiguous), V -> V[c][l].
__global__ __launch_bounds__(256) void k_qkv_s_mfma(const bf16* __restrict__ XT,
        const void* __restrict__ W, const void* __restrict__ Bv,
        bf16* __restrict__ Y, const int* __restrict__ flag){
  const bool f32in = flag[0] != 0;
  const int l0 = blockIdx.x * 64;
  const int o0 = blockIdx.y * 128;
  const int nl = blockIdx.z;
  const int tid = threadIdx.x, lane = tid & 63;
  const int wm = (tid >> 6) & 1, wn = tid >> 7;
  const int r15 = lane & 15, quad = lane >> 4;
  __shared__ bf16 As[64*72];    // XT rows (l)
  __shared__ bf16 Bs[128*72];   // W rows (o)
  v4f acc[2][4];
  #pragma unroll
  for (int i = 0; i < 2; ++i)
    #pragma unroll
    for (int j = 0; j < 4; ++j) acc[i][j] = (v4f){0.f,0.f,0.f,0.f};
  for (int kc = 0; kc < 512; kc += 64){
    __syncthreads();
    #pragma unroll
    for (int r = 0; r < 4; ++r){
      int e4 = (tid + 256*r)*4;
      int row = e4 >> 6, k = e4 & 63;
      stage4b(&XT[(size_t)(nl*576 + l0 + row)*512 + kc + k], &As[row*72 + k]);
    }
    #pragma unroll
    for (int r = 0; r < 8; ++r){
      int e4 = (tid + 256*r)*4;
      int row = e4 >> 6, k = e4 & 63;
      stage4(W, (size_t)(o0+row)*512 + kc + k, f32in, &Bs[row*72 + k]);
    }
    __syncthreads();
    #pragma unroll
    for (int ks = 0; ks < 2; ++ks){
      v8s a[2], b[4];
      #pragma unroll
      for (int mi = 0; mi < 2; ++mi)
        a[mi] = *(const v8s*)&As[(wm*32 + mi*16 + r15)*72 + ks*32 + quad*8];
      #pragma unroll
      for (int ni = 0; ni < 4; ++ni)
        b[ni] = *(const v8s*)&Bs[(wn*64 + ni*16 + r15)*72 + ks*32 + quad*8];
      #pragma unroll
      for (int mi = 0; mi < 2; ++mi)
        #pragma unroll
        for (int ni = 0; ni < 4; ++ni)
          acc[mi][ni] = __builtin_amdgcn_mfma_f32_16x16x32_bf16(a[mi], b[ni], acc[mi][ni], 0, 0, 0);
    }
  }
  const int seg = o0 >> 9;  // 0=Q,1=K,2=V (BN=128 divides 512 -> uniform per block)
  size_t segbase = (seg==0) ? (size_t)nl*294912
                 : (seg==1) ? 2359296u + (size_t)nl*294912
                            : 4718592u + (size_t)nl*294912;
  const int ob = o0 & 511;
  #pragma unroll
  for (int mi = 0; mi < 2; ++mi)
    #pragma unroll
    for (int ni = 0; ni < 4; ++ni){
      int oseg = ob + wn*64 + ni*16 + r15;
      float bia = ldin(Bv, o0 + wn*64 + ni*16 + r15, f32in);
      #pragma unroll
      for (int rg = 0; rg < 4; ++rg){
        int l = l0 + wm*32 + mi*16 + quad*4 + rg;
        float val = acc[mi][ni][rg] + bia;
        size_t dst = (seg==2) ? segbase + (size_t)oseg*576 + l
                              : segbase + (size_t)l*512 + oseg;
        Y[dst] = f2b(val);
      }
    }
}

// ---------------------------------------------------------------- K3: spatial attention (MFMA) -> attT [l][c]
// block: (t-tile of 64, nl*8+head). 4 waves; wave w owns q-rows w*16..w*16+15.
// NOTE: all loops touching acc[] are FULLY unrolled — partial unroll demotes
// the accumulator array to scratch (R6: 317 MB spill writes per dispatch).
__global__ __launch_bounds__(256, 2) void k_attn_s_mfma(const bf16* __restrict__ qkv,
        bf16* __restrict__ attT){
  const int t0 = blockIdx.x;        // 0..8
  const int nh = blockIdx.y;        // 0..63
  const int nl = nh >> 3, head = nh & 7;
  const int tid = threadIdx.x, lane = tid & 63, w = tid >> 6;
  const int r15 = lane & 15, quad = lane >> 4;
  __shared__ bf16 P[64*600];        // stride 600: 16B-aligned rows, ~2-way banks
  const bf16* QT = qkv + (size_t)nl*294912;
  const bf16* KT = qkv + 2359296u + (size_t)nl*294912;
  const bf16* Vp = qkv + 4718592u + (size_t)nl*294912;
  const int c0 = head*64;
  // Q A-fragments (2 ksteps of 32), resident for the whole S phase
  v8s aq0, aq1;
  {
    const bf16* qrow = QT + (size_t)(t0*64 + w*16 + r15)*512 + c0;
    aq0 = *(const v8s*)(qrow + quad*8);
    aq1 = *(const v8s*)(qrow + 32 + quad*8);
  }
  // ---- phase 1: S = (q*scale)·(k*scale)^T, full 576 s in registers
  v4f acc[36];
  #pragma unroll
  for (int st = 0; st < 36; ++st) acc[st] = (v4f){0.f,0.f,0.f,0.f};
  #pragma unroll
  for (int st = 0; st < 36; ++st){
    const bf16* krow = KT + (size_t)(st*16 + r15)*512 + c0;
    v8s b0 = *(const v8s*)(krow + quad*8);
    v8s b1 = *(const v8s*)(krow + 32 + quad*8);
    acc[st] = __builtin_amdgcn_mfma_f32_16x16x32_bf16(aq0, b0, acc[st], 0, 0, 0);
    acc[st] = __builtin_amdgcn_mfma_f32_16x16x32_bf16(aq1, b1, acc[st], 0, 0, 0);
  }
  // ---- softmax over s (rows owned by (quad,rg); cols spread over r15 x 36 tiles)
  float mx[4] = {-1e30f,-1e30f,-1e30f,-1e30f};
  #pragma unroll
  for (int st = 0; st < 36; ++st)
    #pragma unroll
    for (int rg = 0; rg < 4; ++rg){
      float v = acc[st][rg]*0.125f;  // scale^2 = 1/sqrt(64)
      acc[st][rg] = v;
      mx[rg] = fmaxf(mx[rg], v);
    }
  #pragma unroll
  for (int off = 1; off < 16; off <<= 1)
    #pragma unroll
    for (int rg = 0; rg < 4; ++rg) mx[rg] = fmaxf(mx[rg], __shfl_xor(mx[rg], off, 64));
  float sm[4] = {0.f,0.f,0.f,0.f};
  #pragma unroll
  for (int st = 0; st < 36; ++st)
    #pragma unroll
    for (int rg = 0; rg < 4; ++rg){
      float e = __expf(acc[st][rg] - mx[rg]);
      acc[st][rg] = e; sm[rg] += e;
    }
  #pragma unroll
  for (int off = 1; off < 16; off <<= 1)
    #pragma unroll
    for (int rg = 0; rg < 4; ++rg) sm[rg] += __shfl_xor(sm[rg], off, 64);
  float inv[4];
  #pragma unroll
  for (int rg = 0; rg < 4; ++rg) inv[rg] = 1.f / sm[rg];
  // ---- write P rows (this wave's 16 rows only; consumed by same wave below)
  #pragma unroll
  for (int st = 0; st < 36; ++st)
    #pragma unroll
    for (int rg = 0; rg < 4; ++rg)
      P[(w*16 + quad*4 + rg)*600 + st*16 + r15] = f2b(acc[st][rg]*inv[rg]);
  // ---- phase 2: O = P · V^T  (contraction over s, B-frags direct from global V[c][s])
  v4f oc[4];
  #pragma unroll
  for (int ni = 0; ni < 4; ++ni) oc[ni] = (v4f){0.f,0.f,0.f,0.f};
  #pragma unroll 3
  for (int ks = 0; ks < 18; ++ks){
    v8s a = *(const v8s*)&P[(w*16 + r15)*600 + ks*32 + quad*8];
    #pragma unroll
    for (int ni = 0; ni < 4; ++ni){
      v8s b = *(const v8s*)(Vp + (size_t)(c0 + ni*16 + r15)*576 + ks*32 + quad*8);
      oc[ni] = __builtin_amdgcn_mfma_f32_16x16x32_bf16(a, b, oc[ni], 0, 0, 0);
    }
  }
  #pragma unroll
  for (int ni = 0; ni < 4; ++ni)
    #pragma unroll
    for (int rg = 0; rg < 4; ++rg){
      int t = t0*64 + w*16 + quad*4 + rg;
      attT[(size_t)(nl*576 + t)*512 + c0 + ni*16 + r15] = f2b(oc[ni][rg]);
    }
}

// ---------------------------------------------------------------- K4: spatial proj + residual (MFMA)
__global__ __launch_bounds__(256) void k_proj_s_mfma(const bf16* __restrict__ AT,
        const void* __restrict__ W, const void* __restrict__ Bv,
        const void* __restrict__ xin, bf16* __restrict__ x2,
        const int* __restrict__ flag, int n0){
  const bool f32in = flag[0] != 0;
  const int o0 = blockIdx.x * 128;
  const int l0 = blockIdx.y * 64;
  const int nl = blockIdx.z;
  const int n = n0 + nl;
  const int b = n >> 4, t = n & 15;
  const int tid = threadIdx.x, lane = tid & 63;
  const int wm = (tid >> 6) & 1, wn = tid >> 7;
  const int r15 = lane & 15, quad = lane >> 4;
  __shared__ bf16 As[128*72];
  __shared__ bf16 Bs[64*72];
  v4f acc[4][2];
  #pragma unroll
  for (int i = 0; i < 4; ++i)
    #pragma unroll
    for (int j = 0; j < 2; ++j) acc[i][j] = (v4f){0.f,0.f,0.f,0.f};
  for (int kc = 0; kc < 512; kc += 64){
    __syncthreads();
    #pragma unroll
    for (int r = 0; r < 8; ++r){
      int e4 = (tid + 256*r)*4;
      int row = e4 >> 6, k = e4 & 63;
      stage4(W, (size_t)(o0+row)*512 + kc + k, f32in, &As[row*72 + k]);
    }
    #pragma unroll
    for (int r = 0; r < 4; ++r){
      int e4 = (tid + 256*r)*4;
      int row = e4 >> 6, k = e4 & 63;
      stage4b(&AT[(size_t)(nl*576 + l0 + row)*512 + kc + k], &Bs[row*72 + k]);
    }
    __syncthreads();
    #pragma unroll
    for (int ks = 0; ks < 2; ++ks){
      v8s a[4], b[2];
      #pragma unroll
      for (int mi = 0; mi < 4; ++mi)
        a[mi] = *(const v8s*)&As[(wm*64 + mi*16 + r15)*72 + ks*32 + quad*8];
      #pragma unroll
      for (int ni = 0; ni < 2; ++ni)
        b[ni] = *(const v8s*)&Bs[(wn*32 + ni*16 + r15)*72 + ks*32 + quad*8];
      #pragma unroll
      for (int mi = 0; mi < 4; ++mi)
        #pragma unroll
        for (int ni = 0; ni < 2; ++ni)
          acc[mi][ni] = __builtin_amdgcn_mfma_f32_16x16x32_bf16(a[mi], b[ni], acc[mi][ni], 0, 0, 0);
    }
  }
  #pragma unroll
  for (int mi = 0; mi < 4; ++mi)
    #pragma unroll
    for (int rg = 0; rg < 4; ++rg){
      int o = o0 + wm*64 + mi*16 + quad*4 + rg;
      float bia = ldin(Bv, o, f32in);
      #pragma unroll
      for (int ni = 0; ni < 2; ++ni){
        int l = l0 + wn*32 + ni*16 + r15;
        size_t addr = ((size_t)(b*512 + o)*16 + t)*576 + l;
        x2[addr] = f2b(acc[mi][ni][rg] + bia + ldin(xin, addr, f32in));
      }
    }
}

// ---------------------------------------------------------------- K5: temporal groupnorm -> xnT [m][t][c]
__global__ __launch_bounds__(256) void k_gn_t(const bf16* __restrict__ x2,
        const void* __restrict__ gw, const void* __restrict__ gb,
        bf16* __restrict__ xnT, const int* __restrict__ flag, int m0){
  const bool f32in = flag[0] != 0;
  const int ml = blockIdx.x;
  const int m = m0 + ml;
  const int b = m / 576, l = m - b*576;
  const int tid = threadIdx.x;
  __shared__ float xs[8192];        // [t][c]
  __shared__ float mg[32], rg[32];
  for (int i = tid; i < 8192; i += 256){
    int t = i >> 9, c = i & 511;
    xs[i] = b2f(x2[((b*512 + c)*16 + t)*576 + l]);
  }
  __syncthreads();
  {
    int g = tid >> 3, ii = tid & 7;
    float s = 0.f, q = 0.f;
    for (int idx = ii; idx < 256; idx += 8){
      int t = idx >> 4, cg = idx & 15;
      float v = xs[t*512 + g*16 + cg]; s += v; q += v*v;
    }
    #pragma unroll
    for (int off = 1; off < 8; off <<= 1){ s += __shfl_xor(s, off, 64); q += __shfl_xor(q, off, 64); }
    if (ii == 0){
      float mean = s*(1.f/256.f);
      float var  = q*(1.f/256.f) - mean*mean;
      mg[g] = mean; rg[g] = rsqrtf(fmaxf(var, 0.f) + 1e-5f);
    }
  }
  __syncthreads();
  for (int i = tid; i < 8192; i += 256){
    int c = i & 511, g = c >> 4;
    xnT[(size_t)ml*8192 + i] = f2b((xs[i] - mg[g])*rg[g]*ldin(gw, c, f32in) + ldin(gb, c, f32in));
  }
}

// ---------------------------------------------------------------- K6: temporal qkv GEMM (MFMA, 4 m per block)
__global__ __launch_bounds__(256) void k_qkv_t_mfma(const bf16* __restrict__ XT,
        const void* __restrict__ W, const void* __restrict__ Bv,
        bf16* __restrict__ Y, const int* __restrict__ flag){
  const bool f32in = flag[0] != 0;
  const int o0 = blockIdx.x * 128;
  const int mg0 = blockIdx.y * 4;
  const int tid = threadIdx.x, lane = tid & 63;
  const int wm = (tid >> 6) & 1, wn = tid >> 7;
  const int r15 = lane & 15, quad = lane >> 4;
  __shared__ bf16 As[128*72];
  __shared__ bf16 Bs[64*72];
  v4f acc[4][2];
  #pragma unroll
  for (int i = 0; i < 4; ++i)
    #pragma unroll
    for (int j = 0; j < 2; ++j) acc[i][j] = (v4f){0.f,0.f,0.f,0.f};
  for (int kc = 0; kc < 512; kc += 64){
    __syncthreads();
    #pragma unroll
    for (int r = 0; r < 8; ++r){
      int e4 = (tid + 256*r)*4;
      int row = e4 >> 6, k = e4 & 63;
      stage4(W, (size_t)(o0+row)*512 + kc + k, f32in, &As[row*72 + k]);
    }
    #pragma unroll
    for (int r = 0; r < 4; ++r){
      int e4 = (tid + 256*r)*4;
      int row = e4 >> 6, k = e4 & 63;
      stage4b(&XT[(size_t)(mg0 + (row >> 4))*8192 + (row & 15)*512 + kc + k], &Bs[row*72 + k]);
    }
    __syncthreads();
    #pragma unroll
    for (int ks = 0; ks < 2; ++ks){
      v8s a[4], b[2];
      #pragma unroll
      for (int mi = 0; mi < 4; ++mi)
        a[mi] = *(const v8s*)&As[(wm*64 + mi*16 + r15)*72 + ks*32 + quad*8];
      #pragma unroll
      for (int ni = 0; ni < 2; ++ni)
        b[ni] = *(const v8s*)&Bs[(wn*32 + ni*16 + r15)*72 + ks*32 + quad*8];
      #pragma unroll
      for (int mi = 0; mi < 4; ++mi)
        #pragma unroll
        for (int ni = 0; ni < 2; ++ni)
          acc[mi][ni] = __builtin_amdgcn_mfma_f32_16x16x32_bf16(a[mi], b[ni], acc[mi][ni], 0, 0, 0);
    }
  }
  #pragma unroll
  for (int mi = 0; mi < 4; ++mi)
    #pragma unroll
    for (int rg = 0; rg < 4; ++rg){
      int o = o0 + wm*64 + mi*16 + quad*4 + rg;
      float bia = ldin(Bv, o, f32in);
      #pragma unroll
      for (int ni = 0; ni < 2; ++ni){
        int nidx = wn*32 + ni*16 + r15;
        int mb = nidx >> 4, t = nidx & 15;
        Y[((size_t)(mg0 + mb)*1536 + o)*16 + t] = f2b(acc[mi][ni][rg] + bia);
      }
    }
}

// ---------------------------------------------------------------- K7: temporal attention -> attT [m][t][c]
__global__ __launch_bounds__(256) void k_attn_t(const bf16* __restrict__ qkv,
        const void* __restrict__ tbk, const void* __restrict__ tbv,
        bf16* __restrict__ attT, const int* __restrict__ flag){
  const bool f32in = flag[0] != 0;
  const int head = blockIdx.x;
  const int ml = blockIdx.y;
  const int tid = threadIdx.x;
  __shared__ float qs[1024], ks[1024], vs[1024];
  __shared__ float tk[33*65], tv[33*65];
  __shared__ float ps[16*17];
  const int base = (ml*1536 + head*64)*16;
  for (int i = tid; i < 1024; i += 256){
    qs[i] = b2f(qkv[base + i]);
    ks[i] = b2f(qkv[base + 512*16 + i]);
    vs[i] = b2f(qkv[base + 1024*16 + i]);
  }
  for (int i = tid; i < 33*64; i += 256){
    int row = i >> 6, col = i & 63;
    tk[row*65 + col] = ldin(tbk, i, f32in);
    tv[row*65 + col] = ldin(tbv, i, f32in);
  }
  __syncthreads();
  {
    const int t = tid >> 4, s = tid & 15;
    float qk = 0.f, rpe = 0.f;
    #pragma unroll
    for (int c = 0; c < 64; ++c){
      qk  += qs[c*16 + t]*ks[c*16 + s];
      rpe += qs[c*16 + s]*tk[(t - s + 16)*65 + c];
    }
    float logit = 0.125f*qk + 0.35355339059327373f*rpe;
    if (s > t) logit = -1e8f;
    float mx = logit;
    #pragma unroll
    for (int off = 8; off; off >>= 1) mx = fmaxf(mx, __shfl_xor(mx, off, 16));
    float e = __expf(logit - mx);
    float tot = e;
    #pragma unroll
    for (int off = 8; off; off >>= 1) tot += __shfl_xor(tot, off, 16);
    ps[t*17 + s] = e / tot;
  }
  __syncthreads();
  {
    const int c4 = tid >> 4, t = tid & 15;
    #pragma unroll
    for (int u = 0; u < 4; ++u){
      int c = c4 + 16*u;
      float a = 0.f;
      #pragma unroll
      for (int s = 0; s < 16; ++s)
        a += ps[t*17 + s]*(vs[c*16 + s] + tv[(s - t + 16)*65 + c]);
      attT[(size_t)ml*8192 + t*512 + head*64 + c] = f2b(a);
    }
  }
}

// ---------------------------------------------------------------- K8: temporal proj + residual -> out (MFMA)
__global__ __launch_bounds__(256) void k_proj_t_mfma(const bf16* __restrict__ AT,
        const void* __restrict__ W, const void* __restrict__ Bv,
        const bf16* __restrict__ x2, void* __restrict__ out,
        const int* __restrict__ flag, int m0){
  const bool f32in = flag[0] != 0;
  const int o0 = blockIdx.x * 128;
  const int mg0 = blockIdx.y * 4;
  const int tid = threadIdx.x, lane = tid & 63;
  const int wm = (tid >> 6) & 1, wn = tid >> 7;
  const int r15 = lane & 15, quad = lane >> 4;
  __shared__ bf16 As[128*72];
  __shared__ bf16 Bs[64*72];
  v4f acc[4][2];
  #pragma unroll
  for (int i = 0; i < 4; ++i)
    #pragma unroll
    for (int j = 0; j < 2; ++j) acc[i][j] = (v4f){0.f,0.f,0.f,0.f};
  for (int kc = 0; kc < 512; kc += 64){
    __syncthreads();
    #pragma unroll
    for (int r = 0; r < 8; ++r){
      int e4 = (tid + 256*r)*4;
      int row = e4 >> 6, k = e4 & 63;
      stage4(W, (size_t)(o0+row)*512 + kc + k, f32in, &As[row*72 + k]);
    }
    #pragma unroll
    for (int r = 0; r < 4; ++r){
      int e4 = (tid + 256*r)*4;
      int row = e4 >> 6, k = e4 & 63;
      stage4b(&AT[(size_t)(mg0 + (row >> 4))*8192 + (row & 15)*512 + kc + k], &Bs[row*72 + k]);
    }
    __syncthreads();
    #pragma unroll
    for (int ks = 0; ks < 2; ++ks){
      v8s a[4], b[2];
      #pragma unroll
      for (int mi = 0; mi < 4; ++mi)
        a[mi] = *(const v8s*)&As[(wm*64 + mi*16 + r15)*72 + ks*32 + quad*8];
      #pragma unroll
      for (int ni = 0; ni < 2; ++ni)
        b[ni] = *(const v8s*)&Bs[(wn*32 + ni*16 + r15)*72 + ks*32 + quad*8];
      #pragma unroll
      for (int mi = 0; mi < 4; ++mi)
        #pragma unroll
        for (int ni = 0; ni < 2; ++ni)
          acc[mi][ni] = __builtin_amdgcn_mfma_f32_16x16x32_bf16(a[mi], b[ni], acc[mi][ni], 0, 0, 0);
    }
  }
  #pragma unroll
  for (int mi = 0; mi < 4; ++mi)
    #pragma unroll
    for (int rg = 0; rg < 4; ++rg){
      int o = o0 + wm*64 + mi*16 + quad*4 + rg;
      float bia = ldin(Bv, o, f32in);
      #pragma unroll
      for (int ni = 0; ni < 2; ++ni){
        int nidx = wn*32 + ni*16 + r15;
        int mb = nidx >> 4, t = nidx & 15;
        int m = m0 + mg0 + mb;
        int b = m / 576, l = m - b*576;
        size_t addr = ((size_t)(b*512 + o)*16 + t)*576 + l;
        float val = acc[mi][ni][rg] + bia + b2f(x2[addr]);
        if (f32in) ((float*)out)[addr] = val;
        else       ((bf16*)out)[addr] = f2b(val);
      }
    }
}

// ----------------------------------------------------------------
extern "C" void kernel_launch(void* const* d_in, const int* in_sizes, int n_in,
                              void* d_out, int out_size, void* d_ws, size_t ws_size,
                              hipStream_t stream){
  const void* x   = d_in[0];
  const void* nsw = d_in[1];
  const void* nsb = d_in[2];
  const void* qsw = d_in[3];
  const void* qsb = d_in[4];
  const void* psw = d_in[5];
  const void* psb = d_in[6];
  const void* ntw = d_in[7];
  const void* ntb = d_in[8];
  const void* qtw = d_in[9];
  const void* qtb = d_in[10];
  const void* ptw = d_in[11];
  const void* ptb = d_in[12];
  const void* rpk = d_in[13];
  const void* rpv = d_in[14];

  int*  flag = (int*)d_ws;
  bf16* A  = (bf16*)((char*)d_ws + 256);   // 2,359,296: xnT_s / xnT_t chunk
  bf16* A2 = A  + 2359296;                  // 2,359,296: attT_s / attT_t chunk
  bf16* Bq = A2 + 2359296;                  // 7,077,888: qkv chunk
  bf16* Cx = Bq + 7077888;                  // 9,437,184: x2 residual stream

  k_detect<<<1, 64, 0, stream>>>(x, flag);

  // spatial phase: 4 chunks of 8 n
  for (int n0 = 0; n0 < 32; n0 += 8){
    k_gn_s       <<<dim3(32, 8),    256, 0, stream>>>(x, nsw, nsb, A, flag, n0);
    k_qkv_s_mfma <<<dim3(9, 12, 8), 256, 0, stream>>>(A, qsw, qsb, Bq, flag);
    k_attn_s_mfma<<<dim3(9, 64),    256, 0, stream>>>(Bq, A2);
    k_proj_s_mfma<<<dim3(4, 9, 8),  256, 0, stream>>>(A2, psw, psb, x, Cx, flag, n0);
  }
  // temporal phase: 4 chunks of 288 m
  for (int m0 = 0; m0 < 1152; m0 += 288){
    k_gn_t       <<<dim3(288),      256, 0, stream>>>(Cx, ntw, ntb, A, flag, m0);
    k_qkv_t_mfma <<<dim3(12, 72),   256, 0, stream>>>(A, qtw, qtb, Bq, flag);
    k_attn_t     <<<dim3(8, 288),   256, 0, stream>>>(Bq, rpk, rpv, A2, flag);
    k_proj_t_mfma<<<dim3(4, 72),    256, 0, stream>>>(A2, ptw, ptb, Cx, d_out, flag, m0);
  }
}

// Round 8
// 975.897 us; speedup vs baseline: 5.3740x; 1.4874x over previous
//
#include <hip/hip_runtime.h>
#include <hip/hip_bf16.h>

typedef __hip_bfloat16 bf16;
typedef __attribute__((ext_vector_type(8))) short v8s;
typedef __attribute__((ext_vector_type(4))) float v4f;

__device__ __forceinline__ float b2f(bf16 v){ return __bfloat162float(v); }
__device__ __forceinline__ bf16  f2b(float v){ return __float2bfloat16(v); }

// Inputs may be bf16 OR f32 — runtime-detected flag (1 => f32). Output dtype follows.
__device__ __forceinline__ float ldin(const void* p, int i, bool f32in){
  return f32in ? ((const float*)p)[i] : b2f(((const bf16*)p)[i]);
}

// stage 4 consecutive source elems (f32-or-bf16) into LDS as bf16
__device__ __forceinline__ void stage4(const void* src, size_t off, bool f32in, bf16* dst){
  union { bf16 h[4]; ushort4 u; } tmp;
  if (f32in){
    float4 f = *(const float4*)((const float*)src + off);
    tmp.h[0] = f2b(f.x); tmp.h[1] = f2b(f.y); tmp.h[2] = f2b(f.z); tmp.h[3] = f2b(f.w);
  } else {
    tmp.u = *(const ushort4*)((const ushort*)src + off);
  }
  *(ushort4*)dst = tmp.u;
}
__device__ __forceinline__ void stage4b(const bf16* src, bf16* dst){
  *(ushort4*)dst = *(const ushort4*)src;
}

// Problem: B=2, C=512, T=16, H=W=24, heads=8, ch=64
// Pipeline runs in 1 pass (ws >= 113.2 MB) or 4 chunks (fallback).
// ws: flag | A (S elems) | A2 (S) | Bq (3S) | Cx 9,437,184   where S = NCH*294912.

// ---------------------------------------------------------------- detect input dtype
__global__ void k_detect(const void* x, int* flag){
  int tid = threadIdx.x;
  const bf16* p = (const bf16*)x;
  int cnt = 0;
  for (int i = tid; i < 512; i += 64){
    float v = b2f(p[i]);
    if (!(fabsf(v) <= 64.f)) cnt++;
  }
  #pragma unroll
  for (int off = 32; off; off >>= 1) cnt += __shfl_down(cnt, off, 64);
  if (tid == 0) flag[0] = (cnt > 16) ? 1 : 0;
}

// ---------------------------------------------------------------- K1: spatial groupnorm -> xnT [l][c]
__global__ __launch_bounds__(256) void k_gn_s(const void* __restrict__ x,
        const void* __restrict__ gw, const void* __restrict__ gb,
        bf16* __restrict__ xnT, const int* __restrict__ flag, int n0){
  const bool f32in = flag[0] != 0;
  const int g = blockIdx.x;
  const int nl = blockIdx.y;
  const int n = n0 + nl;
  const int b = n >> 4, t = n & 15;
  const int tid = threadIdx.x;
  __shared__ float xs[576*17];     // [l][cg] padded
  __shared__ float red[4][2];
  __shared__ float stats[2];
  float s = 0.f, q = 0.f;
  for (int i = tid; i < 9216; i += 256){
    int cg = i / 576, l = i - cg*576;
    int c = g*16 + cg;
    float v = ldin(x, ((b*512 + c)*16 + t)*576 + l, f32in);
    xs[l*17 + cg] = v; s += v; q += v*v;
  }
  #pragma unroll
  for (int off = 32; off; off >>= 1){ s += __shfl_down(s, off, 64); q += __shfl_down(q, off, 64); }
  int wid = tid >> 6;
  if ((tid & 63) == 0){ red[wid][0] = s; red[wid][1] = q; }
  __syncthreads();
  if (tid == 0){
    float S = red[0][0]+red[1][0]+red[2][0]+red[3][0];
    float Q = red[0][1]+red[1][1]+red[2][1]+red[3][1];
    float mean = S * (1.f/9216.f);
    float var  = Q * (1.f/9216.f) - mean*mean;
    stats[0] = mean; stats[1] = rsqrtf(fmaxf(var, 0.f) + 1e-5f);
  }
  __syncthreads();
  float mean = stats[0], rstd = stats[1];
  for (int i = tid; i < 9216; i += 256){
    int l = i >> 4, cg = i & 15;
    int c = g*16 + cg;
    xnT[(size_t)(nl*576 + l)*512 + c] =
        f2b((xs[l*17 + cg] - mean)*rstd*ldin(gw, c, f32in) + ldin(gb, c, f32in));
  }
}

// ---------------------------------------------------------------- K2: spatial qkv GEMM (MFMA)
// Q -> QT[l][c] at 0, K -> KT[l][c] at kOff, V -> V[c][l] at vOff (elem offsets).
__global__ __launch_bounds__(256) void k_qkv_s_mfma(const bf16* __restrict__ XT,
        const void* __restrict__ W, const void* __restrict__ Bv,
        bf16* __restrict__ Y, const int* __restrict__ flag,
        size_t kOff, size_t vOff){
  const bool f32in = flag[0] != 0;
  const int l0 = blockIdx.x * 64;
  const int o0 = blockIdx.y * 128;
  const int nl = blockIdx.z;
  const int tid = threadIdx.x, lane = tid & 63;
  const int wm = (tid >> 6) & 1, wn = tid >> 7;
  const int r15 = lane & 15, quad = lane >> 4;
  __shared__ bf16 As[64*72];
  __shared__ bf16 Bs[128*72];
  v4f acc[2][4];
  #pragma unroll
  for (int i = 0; i < 2; ++i)
    #pragma unroll
    for (int j = 0; j < 4; ++j) acc[i][j] = (v4f){0.f,0.f,0.f,0.f};
  for (int kc = 0; kc < 512; kc += 64){
    __syncthreads();
    #pragma unroll
    for (int r = 0; r < 4; ++r){
      int e4 = (tid + 256*r)*4;
      int row = e4 >> 6, k = e4 & 63;
      stage4b(&XT[(size_t)(nl*576 + l0 + row)*512 + kc + k], &As[row*72 + k]);
    }
    #pragma unroll
    for (int r = 0; r < 8; ++r){
      int e4 = (tid + 256*r)*4;
      int row = e4 >> 6, k = e4 & 63;
      stage4(W, (size_t)(o0+row)*512 + kc + k, f32in, &Bs[row*72 + k]);
    }
    __syncthreads();
    #pragma unroll
    for (int ks = 0; ks < 2; ++ks){
      v8s a[2], b[4];
      #pragma unroll
      for (int mi = 0; mi < 2; ++mi)
        a[mi] = *(const v8s*)&As[(wm*32 + mi*16 + r15)*72 + ks*32 + quad*8];
      #pragma unroll
      for (int ni = 0; ni < 4; ++ni)
        b[ni] = *(const v8s*)&Bs[(wn*64 + ni*16 + r15)*72 + ks*32 + quad*8];
      #pragma unroll
      for (int mi = 0; mi < 2; ++mi)
        #pragma unroll
        for (int ni = 0; ni < 4; ++ni)
          acc[mi][ni] = __builtin_amdgcn_mfma_f32_16x16x32_bf16(a[mi], b[ni], acc[mi][ni], 0, 0, 0);
    }
  }
  const int seg = o0 >> 9;  // 0=Q,1=K,2=V
  size_t segbase = ((seg==0) ? 0 : (seg==1) ? kOff : vOff) + (size_t)nl*294912;
  const int ob = o0 & 511;
  #pragma unroll
  for (int mi = 0; mi < 2; ++mi)
    #pragma unroll
    for (int ni = 0; ni < 4; ++ni){
      int oseg = ob + wn*64 + ni*16 + r15;
      float bia = ldin(Bv, o0 + wn*64 + ni*16 + r15, f32in);
      #pragma unroll
      for (int rg = 0; rg < 4; ++rg){
        int l = l0 + wm*32 + mi*16 + quad*4 + rg;
        float val = acc[mi][ni][rg] + bia;
        size_t dst = (seg==2) ? segbase + (size_t)oseg*576 + l
                              : segbase + (size_t)l*512 + oseg;
        Y[dst] = f2b(val);
      }
    }
}

// ---------------------------------------------------------------- K3: spatial attention (MFMA) -> attT [l][c]
// 1D grid of 72*nlCount blocks, XCD-swizzled: xcd = bid&7 owns nl ≡ xcd (mod 8),
// so one nl's QKV (1.77 MB) stays in one XCD's L2.
// All acc[] loops FULLY unrolled (partial unroll => scratch spill, R6).
__global__ __launch_bounds__(256, 2) void k_attn_s_mfma(const bf16* __restrict__ qkv,
        bf16* __restrict__ attT, size_t kOff, size_t vOff){
  const int bid = blockIdx.x;
  const int xcd = bid & 7, slot = bid >> 3;
  const int nl = xcd + 8*(slot/72);
  const int idx = slot - 72*(slot/72);
  const int head = idx/9, t0 = idx - 9*head;
  const int tid = threadIdx.x, lane = tid & 63, w = tid >> 6;
  const int r15 = lane & 15, quad = lane >> 4;
  __shared__ bf16 P[64*600];
  const bf16* QT = qkv + (size_t)nl*294912;
  const bf16* KT = qkv + kOff + (size_t)nl*294912;
  const bf16* Vp = qkv + vOff + (size_t)nl*294912;
  const int c0 = head*64;
  v8s aq0, aq1;
  {
    const bf16* qrow = QT + (size_t)(t0*64 + w*16 + r15)*512 + c0;
    aq0 = *(const v8s*)(qrow + quad*8);
    aq1 = *(const v8s*)(qrow + 32 + quad*8);
  }
  // ---- phase 1: S = QK^T over all 576 s, in registers
  v4f acc[36];
  #pragma unroll
  for (int st = 0; st < 36; ++st) acc[st] = (v4f){0.f,0.f,0.f,0.f};
  #pragma unroll
  for (int st = 0; st < 36; ++st){
    const bf16* krow = KT + (size_t)(st*16 + r15)*512 + c0;
    v8s b0 = *(const v8s*)(krow + quad*8);
    v8s b1 = *(const v8s*)(krow + 32 + quad*8);
    acc[st] = __builtin_amdgcn_mfma_f32_16x16x32_bf16(aq0, b0, acc[st], 0, 0, 0);
    acc[st] = __builtin_amdgcn_mfma_f32_16x16x32_bf16(aq1, b1, acc[st], 0, 0, 0);
  }
  // ---- softmax (rows owned by (quad,rg), cols over r15 x st)
  float mx[4] = {-1e30f,-1e30f,-1e30f,-1e30f};
  #pragma unroll
  for (int st = 0; st < 36; ++st)
    #pragma unroll
    for (int rg = 0; rg < 4; ++rg){
      float v = acc[st][rg]*0.125f;
      acc[st][rg] = v;
      mx[rg] = fmaxf(mx[rg], v);
    }
  #pragma unroll
  for (int off = 1; off < 16; off <<= 1)
    #pragma unroll
    for (int rg = 0; rg < 4; ++rg) mx[rg] = fmaxf(mx[rg], __shfl_xor(mx[rg], off, 64));
  float sm[4] = {0.f,0.f,0.f,0.f};
  #pragma unroll
  for (int st = 0; st < 36; ++st)
    #pragma unroll
    for (int rg = 0; rg < 4; ++rg){
      float e = __expf(acc[st][rg] - mx[rg]);
      acc[st][rg] = e; sm[rg] += e;
    }
  #pragma unroll
  for (int off = 1; off < 16; off <<= 1)
    #pragma unroll
    for (int rg = 0; rg < 4; ++rg) sm[rg] += __shfl_xor(sm[rg], off, 64);
  float inv[4];
  #pragma unroll
  for (int rg = 0; rg < 4; ++rg) inv[rg] = 1.f / sm[rg];
  #pragma unroll
  for (int st = 0; st < 36; ++st)
    #pragma unroll
    for (int rg = 0; rg < 4; ++rg)
      P[(w*16 + quad*4 + rg)*600 + st*16 + r15] = f2b(acc[st][rg]*inv[rg]);
  // ---- phase 2: O = P · V^T
  v4f oc[4];
  #pragma unroll
  for (int ni = 0; ni < 4; ++ni) oc[ni] = (v4f){0.f,0.f,0.f,0.f};
  #pragma unroll 3
  for (int ks = 0; ks < 18; ++ks){
    v8s a = *(const v8s*)&P[(w*16 + r15)*600 + ks*32 + quad*8];
    #pragma unroll
    for (int ni = 0; ni < 4; ++ni){
      v8s b = *(const v8s*)(Vp + (size_t)(c0 + ni*16 + r15)*576 + ks*32 + quad*8);
      oc[ni] = __builtin_amdgcn_mfma_f32_16x16x32_bf16(a, b, oc[ni], 0, 0, 0);
    }
  }
  #pragma unroll
  for (int ni = 0; ni < 4; ++ni)
    #pragma unroll
    for (int rg = 0; rg < 4; ++rg){
      int t = t0*64 + w*16 + quad*4 + rg;
      attT[(size_t)(nl*576 + t)*512 + c0 + ni*16 + r15] = f2b(oc[ni][rg]);
    }
}

// ---------------------------------------------------------------- K4: spatial proj + residual (MFMA)
__global__ __launch_bounds__(256) void k_proj_s_mfma(const bf16* __restrict__ AT,
        const void* __restrict__ W, const void* __restrict__ Bv,
        const void* __restrict__ xin, bf16* __restrict__ x2,
        const int* __restrict__ flag, int n0){
  const bool f32in = flag[0] != 0;
  const int o0 = blockIdx.x * 128;
  const int l0 = blockIdx.y * 64;
  const int nl = blockIdx.z;
  const int n = n0 + nl;
  const int b = n >> 4, t = n & 15;
  const int tid = threadIdx.x, lane = tid & 63;
  const int wm = (tid >> 6) & 1, wn = tid >> 7;
  const int r15 = lane & 15, quad = lane >> 4;
  __shared__ bf16 As[128*72];
  __shared__ bf16 Bs[64*72];
  v4f acc[4][2];
  #pragma unroll
  for (int i = 0; i < 4; ++i)
    #pragma unroll
    for (int j = 0; j < 2; ++j) acc[i][j] = (v4f){0.f,0.f,0.f,0.f};
  for (int kc = 0; kc < 512; kc += 64){
    __syncthreads();
    #pragma unroll
    for (int r = 0; r < 8; ++r){
      int e4 = (tid + 256*r)*4;
      int row = e4 >> 6, k = e4 & 63;
      stage4(W, (size_t)(o0+row)*512 + kc + k, f32in, &As[row*72 + k]);
    }
    #pragma unroll
    for (int r = 0; r < 4; ++r){
      int e4 = (tid + 256*r)*4;
      int row = e4 >> 6, k = e4 & 63;
      stage4b(&AT[(size_t)(nl*576 + l0 + row)*512 + kc + k], &Bs[row*72 + k]);
    }
    __syncthreads();
    #pragma unroll
    for (int ks = 0; ks < 2; ++ks){
      v8s a[4], b[2];
      #pragma unroll
      for (int mi = 0; mi < 4; ++mi)
        a[mi] = *(const v8s*)&As[(wm*64 + mi*16 + r15)*72 + ks*32 + quad*8];
      #pragma unroll
      for (int ni = 0; ni < 2; ++ni)
        b[ni] = *(const v8s*)&Bs[(wn*32 + ni*16 + r15)*72 + ks*32 + quad*8];
      #pragma unroll
      for (int mi = 0; mi < 4; ++mi)
        #pragma unroll
        for (int ni = 0; ni < 2; ++ni)
          acc[mi][ni] = __builtin_amdgcn_mfma_f32_16x16x32_bf16(a[mi], b[ni], acc[mi][ni], 0, 0, 0);
    }
  }
  #pragma unroll
  for (int mi = 0; mi < 4; ++mi)
    #pragma unroll
    for (int rg = 0; rg < 4; ++rg){
      int o = o0 + wm*64 + mi*16 + quad*4 + rg;
      float bia = ldin(Bv, o, f32in);
      #pragma unroll
      for (int ni = 0; ni < 2; ++ni){
        int l = l0 + wn*32 + ni*16 + r15;
        size_t addr = ((size_t)(b*512 + o)*16 + t)*576 + l;
        x2[addr] = f2b(acc[mi][ni][rg] + bia + ldin(xin, addr, f32in));
      }
    }
}

// ---------------------------------------------------------------- K5: temporal groupnorm -> xnT [m][t][c]
__global__ __launch_bounds__(256) void k_gn_t(const bf16* __restrict__ x2,
        const void* __restrict__ gw, const void* __restrict__ gb,
        bf16* __restrict__ xnT, const int* __restrict__ flag, int m0){
  const bool f32in = flag[0] != 0;
  const int ml = blockIdx.x;
  const int m = m0 + ml;
  const int b = m / 576, l = m - b*576;
  const int tid = threadIdx.x;
  __shared__ float xs[8192];
  __shared__ float mg[32], rg[32];
  for (int i = tid; i < 8192; i += 256){
    int t = i >> 9, c = i & 511;
    xs[i] = b2f(x2[((b*512 + c)*16 + t)*576 + l]);
  }
  __syncthreads();
  {
    int g = tid >> 3, ii = tid & 7;
    float s = 0.f, q = 0.f;
    for (int idx = ii; idx < 256; idx += 8){
      int t = idx >> 4, cg = idx & 15;
      float v = xs[t*512 + g*16 + cg]; s += v; q += v*v;
    }
    #pragma unroll
    for (int off = 1; off < 8; off <<= 1){ s += __shfl_xor(s, off, 64); q += __shfl_xor(q, off, 64); }
    if (ii == 0){
      float mean = s*(1.f/256.f);
      float var  = q*(1.f/256.f) - mean*mean;
      mg[g] = mean; rg[g] = rsqrtf(fmaxf(var, 0.f) + 1e-5f);
    }
  }
  __syncthreads();
  for (int i = tid; i < 8192; i += 256){
    int c = i & 511, g = c >> 4;
    xnT[(size_t)ml*8192 + i] = f2b((xs[i] - mg[g])*rg[g]*ldin(gw, c, f32in) + ldin(gb, c, f32in));
  }
}

// ---------------------------------------------------------------- K6: temporal qkv GEMM (MFMA, 4 m per block)
__global__ __launch_bounds__(256) void k_qkv_t_mfma(const bf16* __restrict__ XT,
        const void* __restrict__ W, const void* __restrict__ Bv,
        bf16* __restrict__ Y, const int* __restrict__ flag){
  const bool f32in = flag[0] != 0;
  const int o0 = blockIdx.x * 128;
  const int mg0 = blockIdx.y * 4;
  const int tid = threadIdx.x, lane = tid & 63;
  const int wm = (tid >> 6) & 1, wn = tid >> 7;
  const int r15 = lane & 15, quad = lane >> 4;
  __shared__ bf16 As[128*72];
  __shared__ bf16 Bs[64*72];
  v4f acc[4][2];
  #pragma unroll
  for (int i = 0; i < 4; ++i)
    #pragma unroll
    for (int j = 0; j < 2; ++j) acc[i][j] = (v4f){0.f,0.f,0.f,0.f};
  for (int kc = 0; kc < 512; kc += 64){
    __syncthreads();
    #pragma unroll
    for (int r = 0; r < 8; ++r){
      int e4 = (tid + 256*r)*4;
      int row = e4 >> 6, k = e4 & 63;
      stage4(W, (size_t)(o0+row)*512 + kc + k, f32in, &As[row*72 + k]);
    }
    #pragma unroll
    for (int r = 0; r < 4; ++r){
      int e4 = (tid + 256*r)*4;
      int row = e4 >> 6, k = e4 & 63;
      stage4b(&XT[(size_t)(mg0 + (row >> 4))*8192 + (row & 15)*512 + kc + k], &Bs[row*72 + k]);
    }
    __syncthreads();
    #pragma unroll
    for (int ks = 0; ks < 2; ++ks){
      v8s a[4], b[2];
      #pragma unroll
      for (int mi = 0; mi < 4; ++mi)
        a[mi] = *(const v8s*)&As[(wm*64 + mi*16 + r15)*72 + ks*32 + quad*8];
      #pragma unroll
      for (int ni = 0; ni < 2; ++ni)
        b[ni] = *(const v8s*)&Bs[(wn*32 + ni*16 + r15)*72 + ks*32 + quad*8];
      #pragma unroll
      for (int mi = 0; mi < 4; ++mi)
        #pragma unroll
        for (int ni = 0; ni < 2; ++ni)
          acc[mi][ni] = __builtin_amdgcn_mfma_f32_16x16x32_bf16(a[mi], b[ni], acc[mi][ni], 0, 0, 0);
    }
  }
  #pragma unroll
  for (int mi = 0; mi < 4; ++mi)
    #pragma unroll
    for (int rg = 0; rg < 4; ++rg){
      int o = o0 + wm*64 + mi*16 + quad*4 + rg;
      float bia = ldin(Bv, o, f32in);
      #pragma unroll
      for (int ni = 0; ni < 2; ++ni){
        int nidx = wn*32 + ni*16 + r15;
        int mb = nidx >> 4, t = nidx & 15;
        Y[((size_t)(mg0 + mb)*1536 + o)*16 + t] = f2b(acc[mi][ni][rg] + bia);
      }
    }
}

// ---------------------------------------------------------------- K7: temporal attention -> attT [m][t][c]
__global__ __launch_bounds__(256) void k_attn_t(const bf16* __restrict__ qkv,
        const void* __restrict__ tbk, const void* __restrict__ tbv,
        bf16* __restrict__ attT, const int* __restrict__ flag){
  const bool f32in = flag[0] != 0;
  const int head = blockIdx.x;
  const int ml = blockIdx.y;
  const int tid = threadIdx.x;
  __shared__ float qs[1024], ks[1024], vs[1024];
  __shared__ float tk[33*65], tv[33*65];
  __shared__ float ps[16*17];
  const int base = (ml*1536 + head*64)*16;
  for (int i = tid; i < 1024; i += 256){
    qs[i] = b2f(qkv[base + i]);
    ks[i] = b2f(qkv[base + 512*16 + i]);
    vs[i] = b2f(qkv[base + 1024*16 + i]);
  }
  for (int i = tid; i < 33*64; i += 256){
    int row = i >> 6, col = i & 63;
    tk[row*65 + col] = ldin(tbk, i, f32in);
    tv[row*65 + col] = ldin(tbv, i, f32in);
  }
  __syncthreads();
  {
    const int t = tid >> 4, s = tid & 15;
    float qk = 0.f, rpe = 0.f;
    #pragma unroll
    for (int c = 0; c < 64; ++c){
      qk  += qs[c*16 + t]*ks[c*16 + s];
      rpe += qs[c*16 + s]*tk[(t - s + 16)*65 + c];
    }
    float logit = 0.125f*qk + 0.35355339059327373f*rpe;
    if (s > t) logit = -1e8f;
    float mx = logit;
    #pragma unroll
    for (int off = 8; off; off >>= 1) mx = fmaxf(mx, __shfl_xor(mx, off, 16));
    float e = __expf(logit - mx);
    float tot = e;
    #pragma unroll
    for (int off = 8; off; off >>= 1) tot += __shfl_xor(tot, off, 16);
    ps[t*17 + s] = e / tot;
  }
  __syncthreads();
  {
    const int c4 = tid >> 4, t = tid & 15;
    #pragma unroll
    for (int u = 0; u < 4; ++u){
      int c = c4 + 16*u;
      float a = 0.f;
      #pragma unroll
      for (int s = 0; s < 16; ++s)
        a += ps[t*17 + s]*(vs[c*16 + s] + tv[(s - t + 16)*65 + c]);
      attT[(size_t)ml*8192 + t*512 + head*64 + c] = f2b(a);
    }
  }
}

// ---------------------------------------------------------------- K8: temporal proj + residual -> out (MFMA)
__global__ __launch_bounds__(256) void k_proj_t_mfma(const bf16* __restrict__ AT,
        const void* __restrict__ W, const void* __restrict__ Bv,
        const bf16* __restrict__ x2, void* __restrict__ out,
        const int* __restrict__ flag, int m0){
  const bool f32in = flag[0] != 0;
  const int o0 = blockIdx.x * 128;
  const int mg0 = blockIdx.y * 4;
  const int tid = threadIdx.x, lane = tid & 63;
  const int wm = (tid >> 6) & 1, wn = tid >> 7;
  const int r15 = lane & 15, quad = lane >> 4;
  __shared__ bf16 As[128*72];
  __shared__ bf16 Bs[64*72];
  v4f acc[4][2];
  #pragma unroll
  for (int i = 0; i < 4; ++i)
    #pragma unroll
    for (int j = 0; j < 2; ++j) acc[i][j] = (v4f){0.f,0.f,0.f,0.f};
  for (int kc = 0; kc < 512; kc += 64){
    __syncthreads();
    #pragma unroll
    for (int r = 0; r < 8; ++r){
      int e4 = (tid + 256*r)*4;
      int row = e4 >> 6, k = e4 & 63;
      stage4(W, (size_t)(o0+row)*512 + kc + k, f32in, &As[row*72 + k]);
    }
    #pragma unroll
    for (int r = 0; r < 4; ++r){
      int e4 = (tid + 256*r)*4;
      int row = e4 >> 6, k = e4 & 63;
      stage4b(&AT[(size_t)(mg0 + (row >> 4))*8192 + (row & 15)*512 + kc + k], &Bs[row*72 + k]);
    }
    __syncthreads();
    #pragma unroll
    for (int ks = 0; ks < 2; ++ks){
      v8s a[4], b[2];
      #pragma unroll
      for (int mi = 0; mi < 4; ++mi)
        a[mi] = *(const v8s*)&As[(wm*64 + mi*16 + r15)*72 + ks*32 + quad*8];
      #pragma unroll
      for (int ni = 0; ni < 2; ++ni)
        b[ni] = *(const v8s*)&Bs[(wn*32 + ni*16 + r15)*72 + ks*32 + quad*8];
      #pragma unroll
      for (int mi = 0; mi < 4; ++mi)
        #pragma unroll
        for (int ni = 0; ni < 2; ++ni)
          acc[mi][ni] = __builtin_amdgcn_mfma_f32_16x16x32_bf16(a[mi], b[ni], acc[mi][ni], 0, 0, 0);
    }
  }
  #pragma unroll
  for (int mi = 0; mi < 4; ++mi)
    #pragma unroll
    for (int rg = 0; rg < 4; ++rg){
      int o = o0 + wm*64 + mi*16 + quad*4 + rg;
      float bia = ldin(Bv, o, f32in);
      #pragma unroll
      for (int ni = 0; ni < 2; ++ni){
        int nidx = wn*32 + ni*16 + r15;
        int mb = nidx >> 4, t = nidx & 15;
        int m = m0 + mg0 + mb;
        int b = m / 576, l = m - b*576;
        size_t addr = ((size_t)(b*512 + o)*16 + t)*576 + l;
        float val = acc[mi][ni][rg] + bia + b2f(x2[addr]);
        if (f32in) ((float*)out)[addr] = val;
        else       ((bf16*)out)[addr] = f2b(val);
      }
    }
}

// ----------------------------------------------------------------
extern "C" void kernel_launch(void* const* d_in, const int* in_sizes, int n_in,
                              void* d_out, int out_size, void* d_ws, size_t ws_size,
                              hipStream_t stream){
  const void* x   = d_in[0];
  const void* nsw = d_in[1];
  const void* nsb = d_in[2];
  const void* qsw = d_in[3];
  const void* qsb = d_in[4];
  const void* psw = d_in[5];
  const void* psb = d_in[6];
  const void* ntw = d_in[7];
  const void* ntb = d_in[8];
  const void* qtw = d_in[9];
  const void* qtb = d_in[10];
  const void* ptw = d_in[11];
  const void* ptb = d_in[12];
  const void* rpk = d_in[13];
  const void* rpv = d_in[14];

  // Pick chunking from ws_size (constant across calls -> graph-safe).
  // Full pass needs: 256 + (S + S + 3S + 9437184)*2 bytes with S = 32*294912.
  const size_t S_full = (size_t)32*294912;
  const size_t need_full = 256 + (S_full*5 + 9437184)*2;
  const int NCH = (ws_size >= need_full) ? 32 : 8;       // n per spatial pass
  const int MCH = (NCH == 32) ? 1152 : 288;              // m per temporal pass
  const size_t S = (size_t)NCH*294912;                   // elems per A/A2 region

  int*  flag = (int*)d_ws;
  bf16* A  = (bf16*)((char*)d_ws + 256);   // S: xnT_s / xnT_t
  bf16* A2 = A  + S;                        // S: attT_s / attT_t
  bf16* Bq = A2 + S;                        // 3S: qkv
  bf16* Cx = Bq + 3*S;                      // 9,437,184: x2 residual (always full)
  const size_t kOff = S, vOff = 2*S;        // K/V segment offsets inside Bq

  k_detect<<<1, 64, 0, stream>>>(x, flag);

  for (int n0 = 0; n0 < 32; n0 += NCH){
    k_gn_s       <<<dim3(32, NCH),    256, 0, stream>>>(x, nsw, nsb, A, flag, n0);
    k_qkv_s_mfma <<<dim3(9, 12, NCH), 256, 0, stream>>>(A, qsw, qsb, Bq, flag, kOff, vOff);
    k_attn_s_mfma<<<dim3(72*NCH),     256, 0, stream>>>(Bq, A2, kOff, vOff);
    k_proj_s_mfma<<<dim3(4, 9, NCH),  256, 0, stream>>>(A2, psw, psb, x, Cx, flag, n0);
  }
  for (int m0 = 0; m0 < 1152; m0 += MCH){
    k_gn_t       <<<dim3(MCH),        256, 0, stream>>>(Cx, ntw, ntb, A, flag, m0);
    k_qkv_t_mfma <<<dim3(12, MCH/4),  256, 0, stream>>>(A, qtw, qtb, Bq, flag);
    k_attn_t     <<<dim3(8, MCH),     256, 0, stream>>>(Bq, rpk, rpv, A2, flag);
    k_proj_t_mfma<<<dim3(4, MCH/4),   256, 0, stream>>>(A2, ptw, ptb, Cx, d_out, flag, m0);
  }
}

// Round 9
// 885.204 us; speedup vs baseline: 5.9246x; 1.1025x over previous
//
#include <hip/hip_runtime.h>
#include <hip/hip_bf16.h>

typedef __hip_bfloat16 bf16;
typedef __attribute__((ext_vector_type(8))) short v8s;
typedef __attribute__((ext_vector_type(4))) float v4f;

__device__ __forceinline__ float b2f(bf16 v){ return __bfloat162float(v); }
__device__ __forceinline__ bf16  f2b(float v){ return __float2bfloat16(v); }

// Inputs may be bf16 OR f32 — runtime-detected flag (1 => f32). Output dtype follows.
__device__ __forceinline__ float ldin(const void* p, int i, bool f32in){
  return f32in ? ((const float*)p)[i] : b2f(((const bf16*)p)[i]);
}

// stage 4 consecutive source elems (f32-or-bf16) into LDS as bf16
__device__ __forceinline__ void stage4(const void* src, size_t off, bool f32in, bf16* dst){
  union { bf16 h[4]; ushort4 u; } tmp;
  if (f32in){
    float4 f = *(const float4*)((const float*)src + off);
    tmp.h[0] = f2b(f.x); tmp.h[1] = f2b(f.y); tmp.h[2] = f2b(f.z); tmp.h[3] = f2b(f.w);
  } else {
    tmp.u = *(const ushort4*)((const ushort*)src + off);
  }
  *(ushort4*)dst = tmp.u;
}
__device__ __forceinline__ void stage4b(const bf16* src, bf16* dst){
  *(ushort4*)dst = *(const ushort4*)src;
}

// Problem: B=2, C=512, T=16, H=W=24, heads=8, ch=64
// Pipeline runs in 1 pass (ws >= 113.2 MB) or 4 chunks (fallback).
// ws: flag | A (S elems) | A2 (S) | Bq (3S) | Cx 9,437,184   where S = NCH*294912.

// ---------------------------------------------------------------- detect input dtype
__global__ void k_detect(const void* x, int* flag){
  int tid = threadIdx.x;
  const bf16* p = (const bf16*)x;
  int cnt = 0;
  for (int i = tid; i < 512; i += 64){
    float v = b2f(p[i]);
    if (!(fabsf(v) <= 64.f)) cnt++;
  }
  #pragma unroll
  for (int off = 32; off; off >>= 1) cnt += __shfl_down(cnt, off, 64);
  if (tid == 0) flag[0] = (cnt > 16) ? 1 : 0;
}

// ---------------------------------------------------------------- K1: spatial groupnorm -> xnT [l][c]
__global__ __launch_bounds__(256) void k_gn_s(const void* __restrict__ x,
        const void* __restrict__ gw, const void* __restrict__ gb,
        bf16* __restrict__ xnT, const int* __restrict__ flag, int n0){
  const bool f32in = flag[0] != 0;
  const int g = blockIdx.x;
  const int nl = blockIdx.y;
  const int n = n0 + nl;
  const int b = n >> 4, t = n & 15;
  const int tid = threadIdx.x;
  __shared__ float xs[576*17];     // [l][cg] padded
  __shared__ float red[4][2];
  __shared__ float stats[2];
  float s = 0.f, q = 0.f;
  for (int i = tid; i < 9216; i += 256){
    int cg = i / 576, l = i - cg*576;
    int c = g*16 + cg;
    float v = ldin(x, ((b*512 + c)*16 + t)*576 + l, f32in);
    xs[l*17 + cg] = v; s += v; q += v*v;
  }
  #pragma unroll
  for (int off = 32; off; off >>= 1){ s += __shfl_down(s, off, 64); q += __shfl_down(q, off, 64); }
  int wid = tid >> 6;
  if ((tid & 63) == 0){ red[wid][0] = s; red[wid][1] = q; }
  __syncthreads();
  if (tid == 0){
    float S = red[0][0]+red[1][0]+red[2][0]+red[3][0];
    float Q = red[0][1]+red[1][1]+red[2][1]+red[3][1];
    float mean = S * (1.f/9216.f);
    float var  = Q * (1.f/9216.f) - mean*mean;
    stats[0] = mean; stats[1] = rsqrtf(fmaxf(var, 0.f) + 1e-5f);
  }
  __syncthreads();
  float mean = stats[0], rstd = stats[1];
  for (int i = tid; i < 9216; i += 256){
    int l = i >> 4, cg = i & 15;
    int c = g*16 + cg;
    xnT[(size_t)(nl*576 + l)*512 + c] =
        f2b((xs[l*17 + cg] - mean)*rstd*ldin(gw, c, f32in) + ldin(gb, c, f32in));
  }
}

// ---------------------------------------------------------------- K2: spatial qkv GEMM (MFMA)
// Q -> QT[l][c] at 0, K -> KT[l][c] at kOff, V -> V[c][l] at vOff (elem offsets).
__global__ __launch_bounds__(256) void k_qkv_s_mfma(const bf16* __restrict__ XT,
        const void* __restrict__ W, const void* __restrict__ Bv,
        bf16* __restrict__ Y, const int* __restrict__ flag,
        size_t kOff, size_t vOff){
  const bool f32in = flag[0] != 0;
  const int l0 = blockIdx.x * 64;
  const int o0 = blockIdx.y * 128;
  const int nl = blockIdx.z;
  const int tid = threadIdx.x, lane = tid & 63;
  const int wm = (tid >> 6) & 1, wn = tid >> 7;
  const int r15 = lane & 15, quad = lane >> 4;
  __shared__ bf16 As[64*72];
  __shared__ bf16 Bs[128*72];
  v4f acc[2][4];
  #pragma unroll
  for (int i = 0; i < 2; ++i)
    #pragma unroll
    for (int j = 0; j < 4; ++j) acc[i][j] = (v4f){0.f,0.f,0.f,0.f};
  for (int kc = 0; kc < 512; kc += 64){
    __syncthreads();
    #pragma unroll
    for (int r = 0; r < 4; ++r){
      int e4 = (tid + 256*r)*4;
      int row = e4 >> 6, k = e4 & 63;
      stage4b(&XT[(size_t)(nl*576 + l0 + row)*512 + kc + k], &As[row*72 + k]);
    }
    #pragma unroll
    for (int r = 0; r < 8; ++r){
      int e4 = (tid + 256*r)*4;
      int row = e4 >> 6, k = e4 & 63;
      stage4(W, (size_t)(o0+row)*512 + kc + k, f32in, &Bs[row*72 + k]);
    }
    __syncthreads();
    #pragma unroll
    for (int ks = 0; ks < 2; ++ks){
      v8s a[2], b[4];
      #pragma unroll
      for (int mi = 0; mi < 2; ++mi)
        a[mi] = *(const v8s*)&As[(wm*32 + mi*16 + r15)*72 + ks*32 + quad*8];
      #pragma unroll
      for (int ni = 0; ni < 4; ++ni)
        b[ni] = *(const v8s*)&Bs[(wn*64 + ni*16 + r15)*72 + ks*32 + quad*8];
      #pragma unroll
      for (int mi = 0; mi < 2; ++mi)
        #pragma unroll
        for (int ni = 0; ni < 4; ++ni)
          acc[mi][ni] = __builtin_amdgcn_mfma_f32_16x16x32_bf16(a[mi], b[ni], acc[mi][ni], 0, 0, 0);
    }
  }
  const int seg = o0 >> 9;  // 0=Q,1=K,2=V
  size_t segbase = ((seg==0) ? 0 : (seg==1) ? kOff : vOff) + (size_t)nl*294912;
  const int ob = o0 & 511;
  #pragma unroll
  for (int mi = 0; mi < 2; ++mi)
    #pragma unroll
    for (int ni = 0; ni < 4; ++ni){
      int oseg = ob + wn*64 + ni*16 + r15;
      float bia = ldin(Bv, o0 + wn*64 + ni*16 + r15, f32in);
      #pragma unroll
      for (int rg = 0; rg < 4; ++rg){
        int l = l0 + wm*32 + mi*16 + quad*4 + rg;
        float val = acc[mi][ni][rg] + bia;
        size_t dst = (seg==2) ? segbase + (size_t)oseg*576 + l
                              : segbase + (size_t)l*512 + oseg;
        Y[dst] = f2b(val);
      }
    }
}

// ---------------------------------------------------------------- K3: spatial attention (flash MFMA) -> attT [l][c]
// 1D grid XCD-swizzled (xcd=bid&7 owns nl%8). Flash over 9 s-chunks of 64:
// online softmax, K/V staged in LDS cooperatively. acc = 4 S-tiles + 4 O-tiles
// (32 regs vs R8's 144) -> occupancy-bound no more.
__global__ __launch_bounds__(256, 4) void k_attn_s_mfma(const bf16* __restrict__ qkv,
        bf16* __restrict__ attT, size_t kOff, size_t vOff){
  const int bid = blockIdx.x;
  const int xcd = bid & 7, slot = bid >> 3;
  const int nl = xcd + 8*(slot/72);
  const int idx = slot - 72*(slot/72);
  const int head = idx/9, t0 = idx - 9*head;
  const int tid = threadIdx.x, lane = tid & 63, w = tid >> 6;
  const int r15 = lane & 15, quad = lane >> 4;
  __shared__ bf16 Ks[64*72];       // K chunk [s_local][c]
  __shared__ bf16 Vs[64*72];       // V chunk [c_local][s_local]
  __shared__ bf16 Ps[4][16*72];    // per-wave P transpose tile
  const bf16* QT = qkv + (size_t)nl*294912;
  const bf16* KT = qkv + kOff + (size_t)nl*294912;
  const bf16* Vp = qkv + vOff + (size_t)nl*294912;
  const int c0 = head*64;
  v8s aq0, aq1;
  {
    const bf16* qrow = QT + (size_t)(t0*64 + w*16 + r15)*512 + c0;
    aq0 = *(const v8s*)(qrow + quad*8);
    aq1 = *(const v8s*)(qrow + 32 + quad*8);
  }
  v4f oc[4];
  #pragma unroll
  for (int ni = 0; ni < 4; ++ni) oc[ni] = (v4f){0.f,0.f,0.f,0.f};
  float m_run[4] = {-1e30f,-1e30f,-1e30f,-1e30f};
  float l_run[4] = {0.f,0.f,0.f,0.f};
  for (int sc = 0; sc < 9; ++sc){
    __syncthreads();   // previous chunk's LDS reads done before overwrite
    #pragma unroll
    for (int r = 0; r < 4; ++r){
      int e4 = (tid + 256*r)*4;
      int row = e4 >> 6, col = e4 & 63;
      stage4b(&KT[(size_t)(sc*64 + row)*512 + c0 + col], &Ks[row*72 + col]);
      stage4b(&Vp[(size_t)(c0 + row)*576 + sc*64 + col], &Vs[row*72 + col]);
    }
    __syncthreads();
    // S tiles for this chunk (C-layout: row t = quad*4+rg, col s = sj*16+r15)
    v4f sa[4];
    #pragma unroll
    for (int sj = 0; sj < 4; ++sj) sa[sj] = (v4f){0.f,0.f,0.f,0.f};
    #pragma unroll
    for (int sj = 0; sj < 4; ++sj){
      v8s b0 = *(const v8s*)&Ks[(sj*16 + r15)*72 + quad*8];
      v8s b1 = *(const v8s*)&Ks[(sj*16 + r15)*72 + 32 + quad*8];
      sa[sj] = __builtin_amdgcn_mfma_f32_16x16x32_bf16(aq0, b0, sa[sj], 0, 0, 0);
      sa[sj] = __builtin_amdgcn_mfma_f32_16x16x32_bf16(aq1, b1, sa[sj], 0, 0, 0);
    }
    float cmx[4] = {-1e30f,-1e30f,-1e30f,-1e30f};
    #pragma unroll
    for (int sj = 0; sj < 4; ++sj)
      #pragma unroll
      for (int rg = 0; rg < 4; ++rg){
        float v = sa[sj][rg]*0.125f;   // scale^2 = 1/sqrt(64)
        sa[sj][rg] = v;
        cmx[rg] = fmaxf(cmx[rg], v);
      }
    #pragma unroll
    for (int off = 1; off < 16; off <<= 1)
      #pragma unroll
      for (int rg = 0; rg < 4; ++rg) cmx[rg] = fmaxf(cmx[rg], __shfl_xor(cmx[rg], off, 64));
    float alpha[4];
    #pragma unroll
    for (int rg = 0; rg < 4; ++rg){
      float mnew = fmaxf(m_run[rg], cmx[rg]);
      alpha[rg] = __expf(m_run[rg] - mnew);
      m_run[rg] = mnew;
    }
    float psum[4] = {0.f,0.f,0.f,0.f};
    #pragma unroll
    for (int sj = 0; sj < 4; ++sj)
      #pragma unroll
      for (int rg = 0; rg < 4; ++rg){
        float e = __expf(sa[sj][rg] - m_run[rg]);
        sa[sj][rg] = e; psum[rg] += e;
      }
    #pragma unroll
    for (int off = 1; off < 16; off <<= 1)
      #pragma unroll
      for (int rg = 0; rg < 4; ++rg) psum[rg] += __shfl_xor(psum[rg], off, 64);
    #pragma unroll
    for (int rg = 0; rg < 4; ++rg) l_run[rg] = l_run[rg]*alpha[rg] + psum[rg];
    #pragma unroll
    for (int ni = 0; ni < 4; ++ni)
      #pragma unroll
      for (int rg = 0; rg < 4; ++rg) oc[ni][rg] *= alpha[rg];
    // P tile C-layout -> LDS -> A-frag (wave-private region, no barrier needed)
    #pragma unroll
    for (int sj = 0; sj < 4; ++sj)
      #pragma unroll
      for (int rg = 0; rg < 4; ++rg)
        Ps[w][(quad*4 + rg)*72 + sj*16 + r15] = f2b(sa[sj][rg]);
    #pragma unroll
    for (int ks = 0; ks < 2; ++ks){
      v8s a = *(const v8s*)&Ps[w][r15*72 + ks*32 + quad*8];
      #pragma unroll
      for (int ni = 0; ni < 4; ++ni){
        v8s b = *(const v8s*)&Vs[(ni*16 + r15)*72 + ks*32 + quad*8];
        oc[ni] = __builtin_amdgcn_mfma_f32_16x16x32_bf16(a, b, oc[ni], 0, 0, 0);
      }
    }
  }
  float inv[4];
  #pragma unroll
  for (int rg = 0; rg < 4; ++rg) inv[rg] = 1.f / l_run[rg];
  #pragma unroll
  for (int ni = 0; ni < 4; ++ni)
    #pragma unroll
    for (int rg = 0; rg < 4; ++rg){
      int t = t0*64 + w*16 + quad*4 + rg;
      attT[(size_t)(nl*576 + t)*512 + c0 + ni*16 + r15] = f2b(oc[ni][rg]*inv[rg]);
    }
}

// ---------------------------------------------------------------- K4: spatial proj + residual (MFMA)
__global__ __launch_bounds__(256) void k_proj_s_mfma(const bf16* __restrict__ AT,
        const void* __restrict__ W, const void* __restrict__ Bv,
        const void* __restrict__ xin, bf16* __restrict__ x2,
        const int* __restrict__ flag, int n0){
  const bool f32in = flag[0] != 0;
  const int o0 = blockIdx.x * 128;
  const int l0 = blockIdx.y * 64;
  const int nl = blockIdx.z;
  const int n = n0 + nl;
  const int b = n >> 4, t = n & 15;
  const int tid = threadIdx.x, lane = tid & 63;
  const int wm = (tid >> 6) & 1, wn = tid >> 7;
  const int r15 = lane & 15, quad = lane >> 4;
  __shared__ bf16 As[128*72];
  __shared__ bf16 Bs[64*72];
  v4f acc[4][2];
  #pragma unroll
  for (int i = 0; i < 4; ++i)
    #pragma unroll
    for (int j = 0; j < 2; ++j) acc[i][j] = (v4f){0.f,0.f,0.f,0.f};
  for (int kc = 0; kc < 512; kc += 64){
    __syncthreads();
    #pragma unroll
    for (int r = 0; r < 8; ++r){
      int e4 = (tid + 256*r)*4;
      int row = e4 >> 6, k = e4 & 63;
      stage4(W, (size_t)(o0+row)*512 + kc + k, f32in, &As[row*72 + k]);
    }
    #pragma unroll
    for (int r = 0; r < 4; ++r){
      int e4 = (tid + 256*r)*4;
      int row = e4 >> 6, k = e4 & 63;
      stage4b(&AT[(size_t)(nl*576 + l0 + row)*512 + kc + k], &Bs[row*72 + k]);
    }
    __syncthreads();
    #pragma unroll
    for (int ks = 0; ks < 2; ++ks){
      v8s a[4], b[2];
      #pragma unroll
      for (int mi = 0; mi < 4; ++mi)
        a[mi] = *(const v8s*)&As[(wm*64 + mi*16 + r15)*72 + ks*32 + quad*8];
      #pragma unroll
      for (int ni = 0; ni < 2; ++ni)
        b[ni] = *(const v8s*)&Bs[(wn*32 + ni*16 + r15)*72 + ks*32 + quad*8];
      #pragma unroll
      for (int mi = 0; mi < 4; ++mi)
        #pragma unroll
        for (int ni = 0; ni < 2; ++ni)
          acc[mi][ni] = __builtin_amdgcn_mfma_f32_16x16x32_bf16(a[mi], b[ni], acc[mi][ni], 0, 0, 0);
    }
  }
  #pragma unroll
  for (int mi = 0; mi < 4; ++mi)
    #pragma unroll
    for (int rg = 0; rg < 4; ++rg){
      int o = o0 + wm*64 + mi*16 + quad*4 + rg;
      float bia = ldin(Bv, o, f32in);
      #pragma unroll
      for (int ni = 0; ni < 2; ++ni){
        int l = l0 + wn*32 + ni*16 + r15;
        size_t addr = ((size_t)(b*512 + o)*16 + t)*576 + l;
        x2[addr] = f2b(acc[mi][ni][rg] + bia + ldin(xin, addr, f32in));
      }
    }
}

// ---------------------------------------------------------------- K5: temporal groupnorm -> xnT [m][t][c]
__global__ __launch_bounds__(256) void k_gn_t(const bf16* __restrict__ x2,
        const void* __restrict__ gw, const void* __restrict__ gb,
        bf16* __restrict__ xnT, const int* __restrict__ flag, int m0){
  const bool f32in = flag[0] != 0;
  const int ml = blockIdx.x;
  const int m = m0 + ml;
  const int b = m / 576, l = m - b*576;
  const int tid = threadIdx.x;
  __shared__ float xs[8192];
  __shared__ float mg[32], rg[32];
  for (int i = tid; i < 8192; i += 256){
    int t = i >> 9, c = i & 511;
    xs[i] = b2f(x2[((b*512 + c)*16 + t)*576 + l]);
  }
  __syncthreads();
  {
    int g = tid >> 3, ii = tid & 7;
    float s = 0.f, q = 0.f;
    for (int idx = ii; idx < 256; idx += 8){
      int t = idx >> 4, cg = idx & 15;
      float v = xs[t*512 + g*16 + cg]; s += v; q += v*v;
    }
    #pragma unroll
    for (int off = 1; off < 8; off <<= 1){ s += __shfl_xor(s, off, 64); q += __shfl_xor(q, off, 64); }
    if (ii == 0){
      float mean = s*(1.f/256.f);
      float var  = q*(1.f/256.f) - mean*mean;
      mg[g] = mean; rg[g] = rsqrtf(fmaxf(var, 0.f) + 1e-5f);
    }
  }
  __syncthreads();
  for (int i = tid; i < 8192; i += 256){
    int c = i & 511, g = c >> 4;
    xnT[(size_t)ml*8192 + i] = f2b((xs[i] - mg[g])*rg[g]*ldin(gw, c, f32in) + ldin(gb, c, f32in));
  }
}

// ---------------------------------------------------------------- K6: temporal qkv GEMM (MFMA, 4 m per block)
__global__ __launch_bounds__(256) void k_qkv_t_mfma(const bf16* __restrict__ XT,
        const void* __restrict__ W, const void* __restrict__ Bv,
        bf16* __restrict__ Y, const int* __restrict__ flag){
  const bool f32in = flag[0] != 0;
  const int o0 = blockIdx.x * 128;
  const int mg0 = blockIdx.y * 4;
  const int tid = threadIdx.x, lane = tid & 63;
  const int wm = (tid >> 6) & 1, wn = tid >> 7;
  const int r15 = lane & 15, quad = lane >> 4;
  __shared__ bf16 As[128*72];
  __shared__ bf16 Bs[64*72];
  v4f acc[4][2];
  #pragma unroll
  for (int i = 0; i < 4; ++i)
    #pragma unroll
    for (int j = 0; j < 2; ++j) acc[i][j] = (v4f){0.f,0.f,0.f,0.f};
  for (int kc = 0; kc < 512; kc += 64){
    __syncthreads();
    #pragma unroll
    for (int r = 0; r < 8; ++r){
      int e4 = (tid + 256*r)*4;
      int row = e4 >> 6, k = e4 & 63;
      stage4(W, (size_t)(o0+row)*512 + kc + k, f32in, &As[row*72 + k]);
    }
    #pragma unroll
    for (int r = 0; r < 4; ++r){
      int e4 = (tid + 256*r)*4;
      int row = e4 >> 6, k = e4 & 63;
      stage4b(&XT[(size_t)(mg0 + (row >> 4))*8192 + (row & 15)*512 + kc + k], &Bs[row*72 + k]);
    }
    __syncthreads();
    #pragma unroll
    for (int ks = 0; ks < 2; ++ks){
      v8s a[4], b[2];
      #pragma unroll
      for (int mi = 0; mi < 4; ++mi)
        a[mi] = *(const v8s*)&As[(wm*64 + mi*16 + r15)*72 + ks*32 + quad*8];
      #pragma unroll
      for (int ni = 0; ni < 2; ++ni)
        b[ni] = *(const v8s*)&Bs[(wn*32 + ni*16 + r15)*72 + ks*32 + quad*8];
      #pragma unroll
      for (int mi = 0; mi < 4; ++mi)
        #pragma unroll
        for (int ni = 0; ni < 2; ++ni)
          acc[mi][ni] = __builtin_amdgcn_mfma_f32_16x16x32_bf16(a[mi], b[ni], acc[mi][ni], 0, 0, 0);
    }
  }
  #pragma unroll
  for (int mi = 0; mi < 4; ++mi)
    #pragma unroll
    for (int rg = 0; rg < 4; ++rg){
      int o = o0 + wm*64 + mi*16 + quad*4 + rg;
      float bia = ldin(Bv, o, f32in);
      #pragma unroll
      for (int ni = 0; ni < 2; ++ni){
        int nidx = wn*32 + ni*16 + r15;
        int mb = nidx >> 4, t = nidx & 15;
        Y[((size_t)(mg0 + mb)*1536 + o)*16 + t] = f2b(acc[mi][ni][rg] + bia);
      }
    }
}

// ---------------------------------------------------------------- K7: temporal attention -> attT [m][t][c]
__global__ __launch_bounds__(256) void k_attn_t(const bf16* __restrict__ qkv,
        const void* __restrict__ tbk, const void* __restrict__ tbv,
        bf16* __restrict__ attT, const int* __restrict__ flag){
  const bool f32in = flag[0] != 0;
  const int head = blockIdx.x;
  const int ml = blockIdx.y;
  const int tid = threadIdx.x;
  __shared__ float qs[1024], ks[1024], vs[1024];
  __shared__ float tk[33*65], tv[33*65];
  __shared__ float ps[16*17];
  const int base = (ml*1536 + head*64)*16;
  for (int i = tid; i < 1024; i += 256){
    qs[i] = b2f(qkv[base + i]);
    ks[i] = b2f(qkv[base + 512*16 + i]);
    vs[i] = b2f(qkv[base + 1024*16 + i]);
  }
  for (int i = tid; i < 33*64; i += 256){
    int row = i >> 6, col = i & 63;
    tk[row*65 + col] = ldin(tbk, i, f32in);
    tv[row*65 + col] = ldin(tbv, i, f32in);
  }
  __syncthreads();
  {
    const int t = tid >> 4, s = tid & 15;
    float qk = 0.f, rpe = 0.f;
    #pragma unroll
    for (int c = 0; c < 64; ++c){
      qk  += qs[c*16 + t]*ks[c*16 + s];
      rpe += qs[c*16 + s]*tk[(t - s + 16)*65 + c];
    }
    float logit = 0.125f*qk + 0.35355339059327373f*rpe;
    if (s > t) logit = -1e8f;
    float mx = logit;
    #pragma unroll
    for (int off = 8; off; off >>= 1) mx = fmaxf(mx, __shfl_xor(mx, off, 16));
    float e = __expf(logit - mx);
    float tot = e;
    #pragma unroll
    for (int off = 8; off; off >>= 1) tot += __shfl_xor(tot, off, 16);
    ps[t*17 + s] = e / tot;
  }
  __syncthreads();
  {
    const int c4 = tid >> 4, t = tid & 15;
    #pragma unroll
    for (int u = 0; u < 4; ++u){
      int c = c4 + 16*u;
      float a = 0.f;
      #pragma unroll
      for (int s = 0; s < 16; ++s)
        a += ps[t*17 + s]*(vs[c*16 + s] + tv[(s - t + 16)*65 + c]);
      attT[(size_t)ml*8192 + t*512 + head*64 + c] = f2b(a);
    }
  }
}

// ---------------------------------------------------------------- K8: temporal proj + residual -> out (MFMA)
__global__ __launch_bounds__(256) void k_proj_t_mfma(const bf16* __restrict__ AT,
        const void* __restrict__ W, const void* __restrict__ Bv,
        const bf16* __restrict__ x2, void* __restrict__ out,
        const int* __restrict__ flag, int m0){
  const bool f32in = flag[0] != 0;
  const int o0 = blockIdx.x * 128;
  const int mg0 = blockIdx.y * 4;
  const int tid = threadIdx.x, lane = tid & 63;
  const int wm = (tid >> 6) & 1, wn = tid >> 7;
  const int r15 = lane & 15, quad = lane >> 4;
  __shared__ bf16 As[128*72];
  __shared__ bf16 Bs[64*72];
  v4f acc[4][2];
  #pragma unroll
  for (int i = 0; i < 4; ++i)
    #pragma unroll
    for (int j = 0; j < 2; ++j) acc[i][j] = (v4f){0.f,0.f,0.f,0.f};
  for (int kc = 0; kc < 512; kc += 64){
    __syncthreads();
    #pragma unroll
    for (int r = 0; r < 8; ++r){
      int e4 = (tid + 256*r)*4;
      int row = e4 >> 6, k = e4 & 63;
      stage4(W, (size_t)(o0+row)*512 + kc + k, f32in, &As[row*72 + k]);
    }
    #pragma unroll
    for (int r = 0; r < 4; ++r){
      int e4 = (tid + 256*r)*4;
      int row = e4 >> 6, k = e4 & 63;
      stage4b(&AT[(size_t)(mg0 + (row >> 4))*8192 + (row & 15)*512 + kc + k], &Bs[row*72 + k]);
    }
    __syncthreads();
    #pragma unroll
    for (int ks = 0; ks < 2; ++ks){
      v8s a[4], b[2];
      #pragma unroll
      for (int mi = 0; mi < 4; ++mi)
        a[mi] = *(const v8s*)&As[(wm*64 + mi*16 + r15)*72 + ks*32 + quad*8];
      #pragma unroll
      for (int ni = 0; ni < 2; ++ni)
        b[ni] = *(const v8s*)&Bs[(wn*32 + ni*16 + r15)*72 + ks*32 + quad*8];
      #pragma unroll
      for (int mi = 0; mi < 4; ++mi)
        #pragma unroll
        for (int ni = 0; ni < 2; ++ni)
          acc[mi][ni] = __builtin_amdgcn_mfma_f32_16x16x32_bf16(a[mi], b[ni], acc[mi][ni], 0, 0, 0);
    }
  }
  #pragma unroll
  for (int mi = 0; mi < 4; ++mi)
    #pragma unroll
    for (int rg = 0; rg < 4; ++rg){
      int o = o0 + wm*64 + mi*16 + quad*4 + rg;
      float bia = ldin(Bv, o, f32in);
      #pragma unroll
      for (int ni = 0; ni < 2; ++ni){
        int nidx = wn*32 + ni*16 + r15;
        int mb = nidx >> 4, t = nidx & 15;
        int m = m0 + mg0 + mb;
        int b = m / 576, l = m - b*576;
        size_t addr = ((size_t)(b*512 + o)*16 + t)*576 + l;
        float val = acc[mi][ni][rg] + bia + b2f(x2[addr]);
        if (f32in) ((float*)out)[addr] = val;
        else       ((bf16*)out)[addr] = f2b(val);
      }
    }
}

// ----------------------------------------------------------------
extern "C" void kernel_launch(void* const* d_in, const int* in_sizes, int n_in,
                              void* d_out, int out_size, void* d_ws, size_t ws_size,
                              hipStream_t stream){
  const void* x   = d_in[0];
  const void* nsw = d_in[1];
  const void* nsb = d_in[2];
  const void* qsw = d_in[3];
  const void* qsb = d_in[4];
  const void* psw = d_in[5];
  const void* psb = d_in[6];
  const void* ntw = d_in[7];
  const void* ntb = d_in[8];
  const void* qtw = d_in[9];
  const void* qtb = d_in[10];
  const void* ptw = d_in[11];
  const void* ptb = d_in[12];
  const void* rpk = d_in[13];
  const void* rpv = d_in[14];

  // Pick chunking from ws_size (constant across calls -> graph-safe).
  const size_t S_full = (size_t)32*294912;
  const size_t need_full = 256 + (S_full*5 + 9437184)*2;
  const int NCH = (ws_size >= need_full) ? 32 : 8;       // n per spatial pass
  const int MCH = (NCH == 32) ? 1152 : 288;              // m per temporal pass
  const size_t S = (size_t)NCH*294912;                   // elems per A/A2 region

  int*  flag = (int*)d_ws;
  bf16* A  = (bf16*)((char*)d_ws + 256);   // S: xnT_s / xnT_t
  bf16* A2 = A  + S;                        // S: attT_s / attT_t
  bf16* Bq = A2 + S;                        // 3S: qkv
  bf16* Cx = Bq + 3*S;                      // 9,437,184: x2 residual (always full)
  const size_t kOff = S, vOff = 2*S;        // K/V segment offsets inside Bq

  k_detect<<<1, 64, 0, stream>>>(x, flag);

  for (int n0 = 0; n0 < 32; n0 += NCH){
    k_gn_s       <<<dim3(32, NCH),    256, 0, stream>>>(x, nsw, nsb, A, flag, n0);
    k_qkv_s_mfma <<<dim3(9, 12, NCH), 256, 0, stream>>>(A, qsw, qsb, Bq, flag, kOff, vOff);
    k_attn_s_mfma<<<dim3(72*NCH),     256, 0, stream>>>(Bq, A2, kOff, vOff);
    k_proj_s_mfma<<<dim3(4, 9, NCH),  256, 0, stream>>>(A2, psw, psb, x, Cx, flag, n0);
  }
  for (int m0 = 0; m0 < 1152; m0 += MCH){
    k_gn_t       <<<dim3(MCH),        256, 0, stream>>>(Cx, ntw, ntb, A, flag, m0);
    k_qkv_t_mfma <<<dim3(12, MCH/4),  256, 0, stream>>>(A, qtw, qtb, Bq, flag);
    k_attn_t     <<<dim3(8, MCH),     256, 0, stream>>>(Bq, rpk, rpv, A2, flag);
    k_proj_t_mfma<<<dim3(4, MCH/4),   256, 0, stream>>>(A2, ptw, ptb, Cx, d_out, flag, m0);
  }
}

// Round 10
// 710.692 us; speedup vs baseline: 7.3794x; 1.2456x over previous
//
#include <hip/hip_runtime.h>
#include <hip/hip_bf16.h>

typedef __hip_bfloat16 bf16;
typedef __attribute__((ext_vector_type(8))) short v8s;
typedef __attribute__((ext_vector_type(4))) float v4f;

__device__ __forceinline__ float b2f(bf16 v){ return __bfloat162float(v); }
__device__ __forceinline__ bf16  f2b(float v){ return __float2bfloat16(v); }

// Inputs may be bf16 OR f32 — runtime-detected flag (1 => f32). Output dtype follows.
__device__ __forceinline__ float ldin(const void* p, int i, bool f32in){
  return f32in ? ((const float*)p)[i] : b2f(((const bf16*)p)[i]);
}

// stage 4 consecutive source elems (f32-or-bf16) into dst as bf16 (8B write)
__device__ __forceinline__ void stage4(const void* src, size_t off, bool f32in, bf16* dst){
  union { bf16 h[4]; ushort4 u; } tmp;
  if (f32in){
    float4 f = *(const float4*)((const float*)src + off);
    tmp.h[0] = f2b(f.x); tmp.h[1] = f2b(f.y); tmp.h[2] = f2b(f.z); tmp.h[3] = f2b(f.w);
  } else {
    tmp.u = *(const ushort4*)((const ushort*)src + off);
  }
  *(ushort4*)dst = tmp.u;
}
__device__ __forceinline__ void stage4b(const bf16* src, bf16* dst){
  *(ushort4*)dst = *(const ushort4*)src;
}

// Problem: B=2, C=512, T=16, H=W=24, heads=8, ch=64
// Pipeline runs in 1 pass (ws >= 113.2 MB) or 4 chunks (fallback).
// ws: flag | A (S elems) | A2 (S) | Bq (3S) | Cx 9,437,184   where S = NCH*294912.
// A2 doubles as the bf16 weight-copy region before each QKV GEMM (clobbered by attn after).

// ---------------------------------------------------------------- detect input dtype
__global__ void k_detect(const void* x, int* flag){
  int tid = threadIdx.x;
  const bf16* p = (const bf16*)x;
  int cnt = 0;
  for (int i = tid; i < 512; i += 64){
    float v = b2f(p[i]);
    if (!(fabsf(v) <= 64.f)) cnt++;
  }
  #pragma unroll
  for (int off = 32; off; off >>= 1) cnt += __shfl_down(cnt, off, 64);
  if (tid == 0) flag[0] = (cnt > 16) ? 1 : 0;
}

// ---------------------------------------------------------------- weight convert -> bf16 scratch
__global__ __launch_bounds__(256) void k_cvtw(const void* __restrict__ W,
        bf16* __restrict__ out, int n4, const int* __restrict__ flag){
  const bool f32in = flag[0] != 0;
  int i = blockIdx.x*256 + threadIdx.x;
  if (i < n4) stage4(W, (size_t)i*4, f32in, out + (size_t)i*4);
}

// ---------------------------------------------------------------- K1: spatial groupnorm -> xnT [l][c]
__global__ __launch_bounds__(256) void k_gn_s(const void* __restrict__ x,
        const void* __restrict__ gw, const void* __restrict__ gb,
        bf16* __restrict__ xnT, const int* __restrict__ flag, int n0){
  const bool f32in = flag[0] != 0;
  const int g = blockIdx.x;
  const int nl = blockIdx.y;
  const int n = n0 + nl;
  const int b = n >> 4, t = n & 15;
  const int tid = threadIdx.x;
  __shared__ float xs[576*17];     // [l][cg] padded
  __shared__ float red[4][2];
  __shared__ float stats[2];
  float s = 0.f, q = 0.f;
  for (int i = tid; i < 9216; i += 256){
    int cg = i / 576, l = i - cg*576;
    int c = g*16 + cg;
    float v = ldin(x, ((b*512 + c)*16 + t)*576 + l, f32in);
    xs[l*17 + cg] = v; s += v; q += v*v;
  }
  #pragma unroll
  for (int off = 32; off; off >>= 1){ s += __shfl_down(s, off, 64); q += __shfl_down(q, off, 64); }
  int wid = tid >> 6;
  if ((tid & 63) == 0){ red[wid][0] = s; red[wid][1] = q; }
  __syncthreads();
  if (tid == 0){
    float S = red[0][0]+red[1][0]+red[2][0]+red[3][0];
    float Q = red[0][1]+red[1][1]+red[2][1]+red[3][1];
    float mean = S * (1.f/9216.f);
    float var  = Q * (1.f/9216.f) - mean*mean;
    stats[0] = mean; stats[1] = rsqrtf(fmaxf(var, 0.f) + 1e-5f);
  }
  __syncthreads();
  float mean = stats[0], rstd = stats[1];
  for (int i = tid; i < 9216; i += 256){
    int l = i >> 4, cg = i & 15;
    int c = g*16 + cg;
    xnT[(size_t)(nl*576 + l)*512 + c] =
        f2b((xs[l*17 + cg] - mean)*rstd*ldin(gw, c, f32in) + ldin(gb, c, f32in));
  }
}

// ---------------------------------------------------------------- K2: spatial qkv GEMM (MFMA, XCD-swizzled)
// 1D grid = 108*NCH blocks. xcd=bid&7; the 12 o-blocks of one (nl,l0) X-tile are
// consecutive slots on ONE XCD -> X-tile fetched once per XCD-L2, reused 12x.
// W is pre-converted bf16 (Wb). Q -> QT[l][c], K -> KT[l][c], V -> V[c][l].
__global__ __launch_bounds__(256) void k_qkv_s_mfma(const bf16* __restrict__ XT,
        const bf16* __restrict__ Wb, const void* __restrict__ Bv,
        bf16* __restrict__ Y, const int* __restrict__ flag,
        size_t kOff, size_t vOff){
  const bool f32in = flag[0] != 0;
  const int bid = blockIdx.x;
  const int xcd = bid & 7, slot = bid >> 3;
  const int grp_local = slot / 12, oi = slot - grp_local*12;
  const int group = xcd + 8*grp_local;      // 0..9*NCH-1
  const int nl = group / 9;
  const int l0 = (group - nl*9) * 64;
  const int o0 = oi * 128;
  const int tid = threadIdx.x, lane = tid & 63;
  const int wm = (tid >> 6) & 1, wn = tid >> 7;
  const int r15 = lane & 15, quad = lane >> 4;
  __shared__ bf16 As[64*72];
  __shared__ bf16 Bs[128*72];
  v4f acc[2][4];
  #pragma unroll
  for (int i = 0; i < 2; ++i)
    #pragma unroll
    for (int j = 0; j < 4; ++j) acc[i][j] = (v4f){0.f,0.f,0.f,0.f};
  for (int kc = 0; kc < 512; kc += 64){
    __syncthreads();
    #pragma unroll
    for (int r = 0; r < 4; ++r){
      int e4 = (tid + 256*r)*4;
      int row = e4 >> 6, k = e4 & 63;
      stage4b(&XT[(size_t)(nl*576 + l0 + row)*512 + kc + k], &As[row*72 + k]);
    }
    #pragma unroll
    for (int r = 0; r < 8; ++r){
      int e4 = (tid + 256*r)*4;
      int row = e4 >> 6, k = e4 & 63;
      stage4b(&Wb[(size_t)(o0+row)*512 + kc + k], &Bs[row*72 + k]);
    }
    __syncthreads();
    #pragma unroll
    for (int ks = 0; ks < 2; ++ks){
      v8s a[2], b[4];
      #pragma unroll
      for (int mi = 0; mi < 2; ++mi)
        a[mi] = *(const v8s*)&As[(wm*32 + mi*16 + r15)*72 + ks*32 + quad*8];
      #pragma unroll
      for (int ni = 0; ni < 4; ++ni)
        b[ni] = *(const v8s*)&Bs[(wn*64 + ni*16 + r15)*72 + ks*32 + quad*8];
      #pragma unroll
      for (int mi = 0; mi < 2; ++mi)
        #pragma unroll
        for (int ni = 0; ni < 4; ++ni)
          acc[mi][ni] = __builtin_amdgcn_mfma_f32_16x16x32_bf16(a[mi], b[ni], acc[mi][ni], 0, 0, 0);
    }
  }
  const int seg = o0 >> 9;  // 0=Q,1=K,2=V
  size_t segbase = ((seg==0) ? 0 : (seg==1) ? kOff : vOff) + (size_t)nl*294912;
  const int ob = o0 & 511;
  #pragma unroll
  for (int mi = 0; mi < 2; ++mi)
    #pragma unroll
    for (int ni = 0; ni < 4; ++ni){
      int oseg = ob + wn*64 + ni*16 + r15;
      float bia = ldin(Bv, o0 + wn*64 + ni*16 + r15, f32in);
      #pragma unroll
      for (int rg = 0; rg < 4; ++rg){
        int l = l0 + wm*32 + mi*16 + quad*4 + rg;
        float val = acc[mi][ni][rg] + bia;
        size_t dst = (seg==2) ? segbase + (size_t)oseg*576 + l
                              : segbase + (size_t)l*512 + oseg;
        Y[dst] = f2b(val);
      }
    }
}

// ---------------------------------------------------------------- K3: spatial attention (flash MFMA) -> attT [l][c]
__global__ __launch_bounds__(256, 4) void k_attn_s_mfma(const bf16* __restrict__ qkv,
        bf16* __restrict__ attT, size_t kOff, size_t vOff){
  const int bid = blockIdx.x;
  const int xcd = bid & 7, slot = bid >> 3;
  const int nl = xcd + 8*(slot/72);
  const int idx = slot - 72*(slot/72);
  const int head = idx/9, t0 = idx - 9*head;
  const int tid = threadIdx.x, lane = tid & 63, w = tid >> 6;
  const int r15 = lane & 15, quad = lane >> 4;
  __shared__ bf16 Ks[64*72];       // K chunk [s_local][c]
  __shared__ bf16 Vs[64*72];       // V chunk [c_local][s_local]
  __shared__ bf16 Ps[4][16*72];    // per-wave P transpose tile
  const bf16* QT = qkv + (size_t)nl*294912;
  const bf16* KT = qkv + kOff + (size_t)nl*294912;
  const bf16* Vp = qkv + vOff + (size_t)nl*294912;
  const int c0 = head*64;
  v8s aq0, aq1;
  {
    const bf16* qrow = QT + (size_t)(t0*64 + w*16 + r15)*512 + c0;
    aq0 = *(const v8s*)(qrow + quad*8);
    aq1 = *(const v8s*)(qrow + 32 + quad*8);
  }
  v4f oc[4];
  #pragma unroll
  for (int ni = 0; ni < 4; ++ni) oc[ni] = (v4f){0.f,0.f,0.f,0.f};
  float m_run[4] = {-1e30f,-1e30f,-1e30f,-1e30f};
  float l_run[4] = {0.f,0.f,0.f,0.f};
  for (int sc = 0; sc < 9; ++sc){
    __syncthreads();
    #pragma unroll
    for (int r = 0; r < 4; ++r){
      int e4 = (tid + 256*r)*4;
      int row = e4 >> 6, col = e4 & 63;
      stage4b(&KT[(size_t)(sc*64 + row)*512 + c0 + col], &Ks[row*72 + col]);
      stage4b(&Vp[(size_t)(c0 + row)*576 + sc*64 + col], &Vs[row*72 + col]);
    }
    __syncthreads();
    v4f sa[4];
    #pragma unroll
    for (int sj = 0; sj < 4; ++sj) sa[sj] = (v4f){0.f,0.f,0.f,0.f};
    #pragma unroll
    for (int sj = 0; sj < 4; ++sj){
      v8s b0 = *(const v8s*)&Ks[(sj*16 + r15)*72 + quad*8];
      v8s b1 = *(const v8s*)&Ks[(sj*16 + r15)*72 + 32 + quad*8];
      sa[sj] = __builtin_amdgcn_mfma_f32_16x16x32_bf16(aq0, b0, sa[sj], 0, 0, 0);
      sa[sj] = __builtin_amdgcn_mfma_f32_16x16x32_bf16(aq1, b1, sa[sj], 0, 0, 0);
    }
    float cmx[4] = {-1e30f,-1e30f,-1e30f,-1e30f};
    #pragma unroll
    for (int sj = 0; sj < 4; ++sj)
      #pragma unroll
      for (int rg = 0; rg < 4; ++rg){
        float v = sa[sj][rg]*0.125f;
        sa[sj][rg] = v;
        cmx[rg] = fmaxf(cmx[rg], v);
      }
    #pragma unroll
    for (int off = 1; off < 16; off <<= 1)
      #pragma unroll
      for (int rg = 0; rg < 4; ++rg) cmx[rg] = fmaxf(cmx[rg], __shfl_xor(cmx[rg], off, 64));
    float alpha[4];
    #pragma unroll
    for (int rg = 0; rg < 4; ++rg){
      float mnew = fmaxf(m_run[rg], cmx[rg]);
      alpha[rg] = __expf(m_run[rg] - mnew);
      m_run[rg] = mnew;
    }
    float psum[4] = {0.f,0.f,0.f,0.f};
    #pragma unroll
    for (int sj = 0; sj < 4; ++sj)
      #pragma unroll
      for (int rg = 0; rg < 4; ++rg){
        float e = __expf(sa[sj][rg] - m_run[rg]);
        sa[sj][rg] = e; psum[rg] += e;
      }
    #pragma unroll
    for (int off = 1; off < 16; off <<= 1)
      #pragma unroll
      for (int rg = 0; rg < 4; ++rg) psum[rg] += __shfl_xor(psum[rg], off, 64);
    #pragma unroll
    for (int rg = 0; rg < 4; ++rg) l_run[rg] = l_run[rg]*alpha[rg] + psum[rg];
    #pragma unroll
    for (int ni = 0; ni < 4; ++ni)
      #pragma unroll
      for (int rg = 0; rg < 4; ++rg) oc[ni][rg] *= alpha[rg];
    #pragma unroll
    for (int sj = 0; sj < 4; ++sj)
      #pragma unroll
      for (int rg = 0; rg < 4; ++rg)
        Ps[w][(quad*4 + rg)*72 + sj*16 + r15] = f2b(sa[sj][rg]);
    #pragma unroll
    for (int ks = 0; ks < 2; ++ks){
      v8s a = *(const v8s*)&Ps[w][r15*72 + ks*32 + quad*8];
      #pragma unroll
      for (int ni = 0; ni < 4; ++ni){
        v8s b = *(const v8s*)&Vs[(ni*16 + r15)*72 + ks*32 + quad*8];
        oc[ni] = __builtin_amdgcn_mfma_f32_16x16x32_bf16(a, b, oc[ni], 0, 0, 0);
      }
    }
  }
  float inv[4];
  #pragma unroll
  for (int rg = 0; rg < 4; ++rg) inv[rg] = 1.f / l_run[rg];
  #pragma unroll
  for (int ni = 0; ni < 4; ++ni)
    #pragma unroll
    for (int rg = 0; rg < 4; ++rg){
      int t = t0*64 + w*16 + quad*4 + rg;
      attT[(size_t)(nl*576 + t)*512 + c0 + ni*16 + r15] = f2b(oc[ni][rg]*inv[rg]);
    }
}

// ---------------------------------------------------------------- K4: spatial proj + residual (MFMA)
__global__ __launch_bounds__(256) void k_proj_s_mfma(const bf16* __restrict__ AT,
        const void* __restrict__ W, const void* __restrict__ Bv,
        const void* __restrict__ xin, bf16* __restrict__ x2,
        const int* __restrict__ flag, int n0){
  const bool f32in = flag[0] != 0;
  const int o0 = blockIdx.x * 128;
  const int l0 = blockIdx.y * 64;
  const int nl = blockIdx.z;
  const int n = n0 + nl;
  const int b = n >> 4, t = n & 15;
  const int tid = threadIdx.x, lane = tid & 63;
  const int wm = (tid >> 6) & 1, wn = tid >> 7;
  const int r15 = lane & 15, quad = lane >> 4;
  __shared__ bf16 As[128*72];
  __shared__ bf16 Bs[64*72];
  v4f acc[4][2];
  #pragma unroll
  for (int i = 0; i < 4; ++i)
    #pragma unroll
    for (int j = 0; j < 2; ++j) acc[i][j] = (v4f){0.f,0.f,0.f,0.f};
  for (int kc = 0; kc < 512; kc += 64){
    __syncthreads();
    #pragma unroll
    for (int r = 0; r < 8; ++r){
      int e4 = (tid + 256*r)*4;
      int row = e4 >> 6, k = e4 & 63;
      stage4(W, (size_t)(o0+row)*512 + kc + k, f32in, &As[row*72 + k]);
    }
    #pragma unroll
    for (int r = 0; r < 4; ++r){
      int e4 = (tid + 256*r)*4;
      int row = e4 >> 6, k = e4 & 63;
      stage4b(&AT[(size_t)(nl*576 + l0 + row)*512 + kc + k], &Bs[row*72 + k]);
    }
    __syncthreads();
    #pragma unroll
    for (int ks = 0; ks < 2; ++ks){
      v8s a[4], b[2];
      #pragma unroll
      for (int mi = 0; mi < 4; ++mi)
        a[mi] = *(const v8s*)&As[(wm*64 + mi*16 + r15)*72 + ks*32 + quad*8];
      #pragma unroll
      for (int ni = 0; ni < 2; ++ni)
        b[ni] = *(const v8s*)&Bs[(wn*32 + ni*16 + r15)*72 + ks*32 + quad*8];
      #pragma unroll
      for (int mi = 0; mi < 4; ++mi)
        #pragma unroll
        for (int ni = 0; ni < 2; ++ni)
          acc[mi][ni] = __builtin_amdgcn_mfma_f32_16x16x32_bf16(a[mi], b[ni], acc[mi][ni], 0, 0, 0);
    }
  }
  #pragma unroll
  for (int mi = 0; mi < 4; ++mi)
    #pragma unroll
    for (int rg = 0; rg < 4; ++rg){
      int o = o0 + wm*64 + mi*16 + quad*4 + rg;
      float bia = ldin(Bv, o, f32in);
      #pragma unroll
      for (int ni = 0; ni < 2; ++ni){
        int l = l0 + wn*32 + ni*16 + r15;
        size_t addr = ((size_t)(b*512 + o)*16 + t)*576 + l;
        x2[addr] = f2b(acc[mi][ni][rg] + bia + ldin(xin, addr, f32in));
      }
    }
}

// ---------------------------------------------------------------- K5: temporal groupnorm -> xnT [m][t][c]
__global__ __launch_bounds__(256) void k_gn_t(const bf16* __restrict__ x2,
        const void* __restrict__ gw, const void* __restrict__ gb,
        bf16* __restrict__ xnT, const int* __restrict__ flag, int m0){
  const bool f32in = flag[0] != 0;
  const int ml = blockIdx.x;
  const int m = m0 + ml;
  const int b = m / 576, l = m - b*576;
  const int tid = threadIdx.x;
  __shared__ float xs[8192];
  __shared__ float mg[32], rg[32];
  for (int i = tid; i < 8192; i += 256){
    int t = i >> 9, c = i & 511;
    xs[i] = b2f(x2[((b*512 + c)*16 + t)*576 + l]);
  }
  __syncthreads();
  {
    int g = tid >> 3, ii = tid & 7;
    float s = 0.f, q = 0.f;
    for (int idx = ii; idx < 256; idx += 8){
      int t = idx >> 4, cg = idx & 15;
      float v = xs[t*512 + g*16 + cg]; s += v; q += v*v;
    }
    #pragma unroll
    for (int off = 1; off < 8; off <<= 1){ s += __shfl_xor(s, off, 64); q += __shfl_xor(q, off, 64); }
    if (ii == 0){
      float mean = s*(1.f/256.f);
      float var  = q*(1.f/256.f) - mean*mean;
      mg[g] = mean; rg[g] = rsqrtf(fmaxf(var, 0.f) + 1e-5f);
    }
  }
  __syncthreads();
  for (int i = tid; i < 8192; i += 256){
    int c = i & 511, g = c >> 4;
    xnT[(size_t)ml*8192 + i] = f2b((xs[i] - mg[g])*rg[g]*ldin(gw, c, f32in) + ldin(gb, c, f32in));
  }
}

// ---------------------------------------------------------------- K6: temporal qkv GEMM (MFMA, XCD-swizzled, 4 m per block)
__global__ __launch_bounds__(256) void k_qkv_t_mfma(const bf16* __restrict__ XT,
        const bf16* __restrict__ Wb, const void* __restrict__ Bv,
        bf16* __restrict__ Y, const int* __restrict__ flag){
  const bool f32in = flag[0] != 0;
  const int bid = blockIdx.x;
  const int xcd = bid & 7, slot = bid >> 3;
  const int grp_local = slot / 12, oi = slot - grp_local*12;
  const int mg0 = (xcd + 8*grp_local) * 4;
  const int o0 = oi * 128;
  const int tid = threadIdx.x, lane = tid & 63;
  const int wm = (tid >> 6) & 1, wn = tid >> 7;
  const int r15 = lane & 15, quad = lane >> 4;
  __shared__ bf16 As[128*72];
  __shared__ bf16 Bs[64*72];
  v4f acc[4][2];
  #pragma unroll
  for (int i = 0; i < 4; ++i)
    #pragma unroll
    for (int j = 0; j < 2; ++j) acc[i][j] = (v4f){0.f,0.f,0.f,0.f};
  for (int kc = 0; kc < 512; kc += 64){
    __syncthreads();
    #pragma unroll
    for (int r = 0; r < 8; ++r){
      int e4 = (tid + 256*r)*4;
      int row = e4 >> 6, k = e4 & 63;
      stage4b(&Wb[(size_t)(o0+row)*512 + kc + k], &As[row*72 + k]);
    }
    #pragma unroll
    for (int r = 0; r < 4; ++r){
      int e4 = (tid + 256*r)*4;
      int row = e4 >> 6, k = e4 & 63;
      stage4b(&XT[(size_t)(mg0 + (row >> 4))*8192 + (row & 15)*512 + kc + k], &Bs[row*72 + k]);
    }
    __syncthreads();
    #pragma unroll
    for (int ks = 0; ks < 2; ++ks){
      v8s a[4], b[2];
      #pragma unroll
      for (int mi = 0; mi < 4; ++mi)
        a[mi] = *(const v8s*)&As[(wm*64 + mi*16 + r15)*72 + ks*32 + quad*8];
      #pragma unroll
      for (int ni = 0; ni < 2; ++ni)
        b[ni] = *(const v8s*)&Bs[(wn*32 + ni*16 + r15)*72 + ks*32 + quad*8];
      #pragma unroll
      for (int mi = 0; mi < 4; ++mi)
        #pragma unroll
        for (int ni = 0; ni < 2; ++ni)
          acc[mi][ni] = __builtin_amdgcn_mfma_f32_16x16x32_bf16(a[mi], b[ni], acc[mi][ni], 0, 0, 0);
    }
  }
  #pragma unroll
  for (int mi = 0; mi < 4; ++mi)
    #pragma unroll
    for (int rg = 0; rg < 4; ++rg){
      int o = o0 + wm*64 + mi*16 + quad*4 + rg;
      float bia = ldin(Bv, o, f32in);
      #pragma unroll
      for (int ni = 0; ni < 2; ++ni){
        int nidx = wn*32 + ni*16 + r15;
        int mb = nidx >> 4, t = nidx & 15;
        Y[((size_t)(mg0 + mb)*1536 + o)*16 + t] = f2b(acc[mi][ni][rg] + bia);
      }
    }
}

// ---------------------------------------------------------------- K7: temporal attention -> attT [m][t][c]
__global__ __launch_bounds__(256) void k_attn_t(const bf16* __restrict__ qkv,
        const void* __restrict__ tbk, const void* __restrict__ tbv,
        bf16* __restrict__ attT, const int* __restrict__ flag){
  const bool f32in = flag[0] != 0;
  const int head = blockIdx.x;
  const int ml = blockIdx.y;
  const int tid = threadIdx.x;
  __shared__ float qs[1024], ks[1024], vs[1024];
  __shared__ float tk[33*65], tv[33*65];
  __shared__ float ps[16*17];
  const int base = (ml*1536 + head*64)*16;
  for (int i = tid; i < 1024; i += 256){
    qs[i] = b2f(qkv[base + i]);
    ks[i] = b2f(qkv[base + 512*16 + i]);
    vs[i] = b2f(qkv[base + 1024*16 + i]);
  }
  for (int i = tid; i < 33*64; i += 256){
    int row = i >> 6, col = i & 63;
    tk[row*65 + col] = ldin(tbk, i, f32in);
    tv[row*65 + col] = ldin(tbv, i, f32in);
  }
  __syncthreads();
  {
    const int t = tid >> 4, s = tid & 15;
    float qk = 0.f, rpe = 0.f;
    #pragma unroll
    for (int c = 0; c < 64; ++c){
      qk  += qs[c*16 + t]*ks[c*16 + s];
      rpe += qs[c*16 + s]*tk[(t - s + 16)*65 + c];
    }
    float logit = 0.125f*qk + 0.35355339059327373f*rpe;
    if (s > t) logit = -1e8f;
    float mx = logit;
    #pragma unroll
    for (int off = 8; off; off >>= 1) mx = fmaxf(mx, __shfl_xor(mx, off, 16));
    float e = __expf(logit - mx);
    float tot = e;
    #pragma unroll
    for (int off = 8; off; off >>= 1) tot += __shfl_xor(tot, off, 16);
    ps[t*17 + s] = e / tot;
  }
  __syncthreads();
  {
    const int c4 = tid >> 4, t = tid & 15;
    #pragma unroll
    for (int u = 0; u < 4; ++u){
      int c = c4 + 16*u;
      float a = 0.f;
      #pragma unroll
      for (int s = 0; s < 16; ++s)
        a += ps[t*17 + s]*(vs[c*16 + s] + tv[(s - t + 16)*65 + c]);
      attT[(size_t)ml*8192 + t*512 + head*64 + c] = f2b(a);
    }
  }
}

// ---------------------------------------------------------------- K8: temporal proj + residual -> out (MFMA)
__global__ __launch_bounds__(256) void k_proj_t_mfma(const bf16* __restrict__ AT,
        const void* __restrict__ W, const void* __restrict__ Bv,
        const bf16* __restrict__ x2, void* __restrict__ out,
        const int* __restrict__ flag, int m0){
  const bool f32in = flag[0] != 0;
  const int o0 = blockIdx.x * 128;
  const int mg0 = blockIdx.y * 4;
  const int tid = threadIdx.x, lane = tid & 63;
  const int wm = (tid >> 6) & 1, wn = tid >> 7;
  const int r15 = lane & 15, quad = lane >> 4;
  __shared__ bf16 As[128*72];
  __shared__ bf16 Bs[64*72];
  v4f acc[4][2];
  #pragma unroll
  for (int i = 0; i < 4; ++i)
    #pragma unroll
    for (int j = 0; j < 2; ++j) acc[i][j] = (v4f){0.f,0.f,0.f,0.f};
  for (int kc = 0; kc < 512; kc += 64){
    __syncthreads();
    #pragma unroll
    for (int r = 0; r < 8; ++r){
      int e4 = (tid + 256*r)*4;
      int row = e4 >> 6, k = e4 & 63;
      stage4(W, (size_t)(o0+row)*512 + kc + k, f32in, &As[row*72 + k]);
    }
    #pragma unroll
    for (int r = 0; r < 4; ++r){
      int e4 = (tid + 256*r)*4;
      int row = e4 >> 6, k = e4 & 63;
      stage4b(&AT[(size_t)(mg0 + (row >> 4))*8192 + (row & 15)*512 + kc + k], &Bs[row*72 + k]);
    }
    __syncthreads();
    #pragma unroll
    for (int ks = 0; ks < 2; ++ks){
      v8s a[4], b[2];
      #pragma unroll
      for (int mi = 0; mi < 4; ++mi)
        a[mi] = *(const v8s*)&As[(wm*64 + mi*16 + r15)*72 + ks*32 + quad*8];
      #pragma unroll
      for (int ni = 0; ni < 2; ++ni)
        b[ni] = *(const v8s*)&Bs[(wn*32 + ni*16 + r15)*72 + ks*32 + quad*8];
      #pragma unroll
      for (int mi = 0; mi < 4; ++mi)
        #pragma unroll
        for (int ni = 0; ni < 2; ++ni)
          acc[mi][ni] = __builtin_amdgcn_mfma_f32_16x16x32_bf16(a[mi], b[ni], acc[mi][ni], 0, 0, 0);
    }
  }
  #pragma unroll
  for (int mi = 0; mi < 4; ++mi)
    #pragma unroll
    for (int rg = 0; rg < 4; ++rg){
      int o = o0 + wm*64 + mi*16 + quad*4 + rg;
      float bia = ldin(Bv, o, f32in);
      #pragma unroll
      for (int ni = 0; ni < 2; ++ni){
        int nidx = wn*32 + ni*16 + r15;
        int mb = nidx >> 4, t = nidx & 15;
        int m = m0 + mg0 + mb;
        int b = m / 576, l = m - b*576;
        size_t addr = ((size_t)(b*512 + o)*16 + t)*576 + l;
        float val = acc[mi][ni][rg] + bia + b2f(x2[addr]);
        if (f32in) ((float*)out)[addr] = val;
        else       ((bf16*)out)[addr] = f2b(val);
      }
    }
}

// ----------------------------------------------------------------
extern "C" void kernel_launch(void* const* d_in, const int* in_sizes, int n_in,
                              void* d_out, int out_size, void* d_ws, size_t ws_size,
                              hipStream_t stream){
  const void* x   = d_in[0];
  const void* nsw = d_in[1];
  const void* nsb = d_in[2];
  const void* qsw = d_in[3];
  const void* qsb = d_in[4];
  const void* psw = d_in[5];
  const void* psb = d_in[6];
  const void* ntw = d_in[7];
  const void* ntb = d_in[8];
  const void* qtw = d_in[9];
  const void* qtb = d_in[10];
  const void* ptw = d_in[11];
  const void* ptb = d_in[12];
  const void* rpk = d_in[13];
  const void* rpv = d_in[14];

  // Pick chunking from ws_size (constant across calls -> graph-safe).
  const size_t S_full = (size_t)32*294912;
  const size_t need_full = 256 + (S_full*5 + 9437184)*2;
  const int NCH = (ws_size >= need_full) ? 32 : 8;       // n per spatial pass
  const int MCH = (NCH == 32) ? 1152 : 288;              // m per temporal pass
  const size_t S = (size_t)NCH*294912;                   // elems per A/A2 region

  int*  flag = (int*)d_ws;
  bf16* A  = (bf16*)((char*)d_ws + 256);   // S: xnT_s / xnT_t
  bf16* A2 = A  + S;                        // S: attT_s / attT_t (+ transient bf16 W copy)
  bf16* Bq = A2 + S;                        // 3S: qkv
  bf16* Cx = Bq + 3*S;                      // 9,437,184: x2 residual (always full)
  const size_t kOff = S, vOff = 2*S;        // K/V segment offsets inside Bq
  bf16* Wcv = A2;                           // 786,432 elems, clobbered by attn afterwards

  k_detect<<<1, 64, 0, stream>>>(x, flag);

  for (int n0 = 0; n0 < 32; n0 += NCH){
    k_gn_s       <<<dim3(32, NCH),   256, 0, stream>>>(x, nsw, nsb, A, flag, n0);
    k_cvtw       <<<dim3(768),       256, 0, stream>>>(qsw, Wcv, 196608, flag);
    k_qkv_s_mfma <<<dim3(108*NCH),   256, 0, stream>>>(A, Wcv, qsb, Bq, flag, kOff, vOff);
    k_attn_s_mfma<<<dim3(72*NCH),    256, 0, stream>>>(Bq, A2, kOff, vOff);
    k_proj_s_mfma<<<dim3(4, 9, NCH), 256, 0, stream>>>(A2, psw, psb, x, Cx, flag, n0);
  }
  for (int m0 = 0; m0 < 1152; m0 += MCH){
    k_gn_t       <<<dim3(MCH),       256, 0, stream>>>(Cx, ntw, ntb, A, flag, m0);
    k_cvtw       <<<dim3(768),       256, 0, stream>>>(qtw, Wcv, 196608, flag);
    k_qkv_t_mfma <<<dim3(3*MCH),     256, 0, stream>>>(A, Wcv, qtb, Bq, flag);
    k_attn_t     <<<dim3(8, MCH),    256, 0, stream>>>(Bq, rpk, rpv, A2, flag);
    k_proj_t_mfma<<<dim3(4, MCH/4),  256, 0, stream>>>(A2, ptw, ptb, Cx, d_out, flag, m0);
  }
}

// Round 11
// 622.213 us; speedup vs baseline: 8.4287x; 1.1422x over previous
//
#include <hip/hip_runtime.h>
#include <hip/hip_bf16.h>

typedef __hip_bfloat16 bf16;
typedef __attribute__((ext_vector_type(8))) short v8s;
typedef __attribute__((ext_vector_type(4))) float v4f;

__device__ __forceinline__ float b2f(bf16 v){ return __bfloat162float(v); }
__device__ __forceinline__ bf16  f2b(float v){ return __float2bfloat16(v); }

// Inputs may be bf16 OR f32 — runtime-detected flag (1 => f32). Output dtype follows.
__device__ __forceinline__ float ldin(const void* p, int i, bool f32in){
  return f32in ? ((const float*)p)[i] : b2f(((const bf16*)p)[i]);
}

// stage 4 consecutive source elems (f32-or-bf16) into dst as bf16 (8B write)
__device__ __forceinline__ void stage4(const void* src, size_t off, bool f32in, bf16* dst){
  union { bf16 h[4]; ushort4 u; } tmp;
  if (f32in){
    float4 f = *(const float4*)((const float*)src + off);
    tmp.h[0] = f2b(f.x); tmp.h[1] = f2b(f.y); tmp.h[2] = f2b(f.z); tmp.h[3] = f2b(f.w);
  } else {
    tmp.u = *(const ushort4*)((const ushort*)src + off);
  }
  *(ushort4*)dst = tmp.u;
}
__device__ __forceinline__ void stage4b(const bf16* src, bf16* dst){
  *(ushort4*)dst = *(const ushort4*)src;
}

// Problem: B=2, C=512, T=16, H=W=24, heads=8, ch=64
// Pipeline runs in 1 pass (ws >= 113.2 MB) or 4 chunks (fallback).
// ws: flag | A (S elems) | A2 (S) | Bq (3S) | Cx 9,437,184   where S = NCH*294912.
// A2 doubles as bf16 W-copy before QKV GEMMs; Bq start doubles as bf16 W-copy
// for proj_t (qkv_t dead after attn_t).

// ---------------------------------------------------------------- detect input dtype
__global__ void k_detect(const void* x, int* flag){
  int tid = threadIdx.x;
  const bf16* p = (const bf16*)x;
  int cnt = 0;
  for (int i = tid; i < 512; i += 64){
    float v = b2f(p[i]);
    if (!(fabsf(v) <= 64.f)) cnt++;
  }
  #pragma unroll
  for (int off = 32; off; off >>= 1) cnt += __shfl_down(cnt, off, 64);
  if (tid == 0) flag[0] = (cnt > 16) ? 1 : 0;
}

// ---------------------------------------------------------------- weight convert -> bf16 scratch
__global__ __launch_bounds__(256) void k_cvtw(const void* __restrict__ W,
        bf16* __restrict__ out, int n4, const int* __restrict__ flag){
  const bool f32in = flag[0] != 0;
  int i = blockIdx.x*256 + threadIdx.x;
  if (i < n4) stage4(W, (size_t)i*4, f32in, out + (size_t)i*4);
}

// ---------------------------------------------------------------- K1: spatial groupnorm -> xnT [l][c]
__global__ __launch_bounds__(256) void k_gn_s(const void* __restrict__ x,
        const void* __restrict__ gw, const void* __restrict__ gb,
        bf16* __restrict__ xnT, const int* __restrict__ flag, int n0){
  const bool f32in = flag[0] != 0;
  const int g = blockIdx.x;
  const int nl = blockIdx.y;
  const int n = n0 + nl;
  const int b = n >> 4, t = n & 15;
  const int tid = threadIdx.x;
  __shared__ float xs[576*17];     // [l][cg] padded
  __shared__ float red[4][2];
  __shared__ float stats[2];
  float s = 0.f, q = 0.f;
  for (int i = tid; i < 9216; i += 256){
    int cg = i / 576, l = i - cg*576;
    int c = g*16 + cg;
    float v = ldin(x, ((b*512 + c)*16 + t)*576 + l, f32in);
    xs[l*17 + cg] = v; s += v; q += v*v;
  }
  #pragma unroll
  for (int off = 32; off; off >>= 1){ s += __shfl_down(s, off, 64); q += __shfl_down(q, off, 64); }
  int wid = tid >> 6;
  if ((tid & 63) == 0){ red[wid][0] = s; red[wid][1] = q; }
  __syncthreads();
  if (tid == 0){
    float S = red[0][0]+red[1][0]+red[2][0]+red[3][0];
    float Q = red[0][1]+red[1][1]+red[2][1]+red[3][1];
    float mean = S * (1.f/9216.f);
    float var  = Q * (1.f/9216.f) - mean*mean;
    stats[0] = mean; stats[1] = rsqrtf(fmaxf(var, 0.f) + 1e-5f);
  }
  __syncthreads();
  float mean = stats[0], rstd = stats[1];
  for (int i = tid; i < 9216; i += 256){
    int l = i >> 4, cg = i & 15;
    int c = g*16 + cg;
    xnT[(size_t)(nl*576 + l)*512 + c] =
        f2b((xs[l*17 + cg] - mean)*rstd*ldin(gw, c, f32in) + ldin(gb, c, f32in));
  }
}

// ---------------------------------------------------------------- K2: spatial qkv GEMM (MFMA, XCD-swizzled)
__global__ __launch_bounds__(256) void k_qkv_s_mfma(const bf16* __restrict__ XT,
        const bf16* __restrict__ Wb, const void* __restrict__ Bv,
        bf16* __restrict__ Y, const int* __restrict__ flag,
        size_t kOff, size_t vOff){
  const bool f32in = flag[0] != 0;
  const int bid = blockIdx.x;
  const int xcd = bid & 7, slot = bid >> 3;
  const int grp_local = slot / 12, oi = slot - grp_local*12;
  const int group = xcd + 8*grp_local;      // 0..9*NCH-1
  const int nl = group / 9;
  const int l0 = (group - nl*9) * 64;
  const int o0 = oi * 128;
  const int tid = threadIdx.x, lane = tid & 63;
  const int wm = (tid >> 6) & 1, wn = tid >> 7;
  const int r15 = lane & 15, quad = lane >> 4;
  __shared__ bf16 As[64*72];
  __shared__ bf16 Bs[128*72];
  v4f acc[2][4];
  #pragma unroll
  for (int i = 0; i < 2; ++i)
    #pragma unroll
    for (int j = 0; j < 4; ++j) acc[i][j] = (v4f){0.f,0.f,0.f,0.f};
  for (int kc = 0; kc < 512; kc += 64){
    __syncthreads();
    #pragma unroll
    for (int r = 0; r < 4; ++r){
      int e4 = (tid + 256*r)*4;
      int row = e4 >> 6, k = e4 & 63;
      stage4b(&XT[(size_t)(nl*576 + l0 + row)*512 + kc + k], &As[row*72 + k]);
    }
    #pragma unroll
    for (int r = 0; r < 8; ++r){
      int e4 = (tid + 256*r)*4;
      int row = e4 >> 6, k = e4 & 63;
      stage4b(&Wb[(size_t)(o0+row)*512 + kc + k], &Bs[row*72 + k]);
    }
    __syncthreads();
    #pragma unroll
    for (int ks = 0; ks < 2; ++ks){
      v8s a[2], b[4];
      #pragma unroll
      for (int mi = 0; mi < 2; ++mi)
        a[mi] = *(const v8s*)&As[(wm*32 + mi*16 + r15)*72 + ks*32 + quad*8];
      #pragma unroll
      for (int ni = 0; ni < 4; ++ni)
        b[ni] = *(const v8s*)&Bs[(wn*64 + ni*16 + r15)*72 + ks*32 + quad*8];
      #pragma unroll
      for (int mi = 0; mi < 2; ++mi)
        #pragma unroll
        for (int ni = 0; ni < 4; ++ni)
          acc[mi][ni] = __builtin_amdgcn_mfma_f32_16x16x32_bf16(a[mi], b[ni], acc[mi][ni], 0, 0, 0);
    }
  }
  const int seg = o0 >> 9;  // 0=Q,1=K,2=V
  size_t segbase = ((seg==0) ? 0 : (seg==1) ? kOff : vOff) + (size_t)nl*294912;
  const int ob = o0 & 511;
  #pragma unroll
  for (int mi = 0; mi < 2; ++mi)
    #pragma unroll
    for (int ni = 0; ni < 4; ++ni){
      int oseg = ob + wn*64 + ni*16 + r15;
      float bia = ldin(Bv, o0 + wn*64 + ni*16 + r15, f32in);
      #pragma unroll
      for (int rg = 0; rg < 4; ++rg){
        int l = l0 + wm*32 + mi*16 + quad*4 + rg;
        float val = acc[mi][ni][rg] + bia;
        size_t dst = (seg==2) ? segbase + (size_t)oseg*576 + l
                              : segbase + (size_t)l*512 + oseg;
        Y[dst] = f2b(val);
      }
    }
}

// ---------------------------------------------------------------- K3: spatial attention (flash MFMA) -> attT [l][c]
__global__ __launch_bounds__(256, 4) void k_attn_s_mfma(const bf16* __restrict__ qkv,
        bf16* __restrict__ attT, size_t kOff, size_t vOff){
  const int bid = blockIdx.x;
  const int xcd = bid & 7, slot = bid >> 3;
  const int nl = xcd + 8*(slot/72);
  const int idx = slot - 72*(slot/72);
  const int head = idx/9, t0 = idx - 9*head;
  const int tid = threadIdx.x, lane = tid & 63, w = tid >> 6;
  const int r15 = lane & 15, quad = lane >> 4;
  __shared__ bf16 Ks[64*72];
  __shared__ bf16 Vs[64*72];
  __shared__ bf16 Ps[4][16*72];
  const bf16* QT = qkv + (size_t)nl*294912;
  const bf16* KT = qkv + kOff + (size_t)nl*294912;
  const bf16* Vp = qkv + vOff + (size_t)nl*294912;
  const int c0 = head*64;
  v8s aq0, aq1;
  {
    const bf16* qrow = QT + (size_t)(t0*64 + w*16 + r15)*512 + c0;
    aq0 = *(const v8s*)(qrow + quad*8);
    aq1 = *(const v8s*)(qrow + 32 + quad*8);
  }
  v4f oc[4];
  #pragma unroll
  for (int ni = 0; ni < 4; ++ni) oc[ni] = (v4f){0.f,0.f,0.f,0.f};
  float m_run[4] = {-1e30f,-1e30f,-1e30f,-1e30f};
  float l_run[4] = {0.f,0.f,0.f,0.f};
  for (int sc = 0; sc < 9; ++sc){
    __syncthreads();
    #pragma unroll
    for (int r = 0; r < 4; ++r){
      int e4 = (tid + 256*r)*4;
      int row = e4 >> 6, col = e4 & 63;
      stage4b(&KT[(size_t)(sc*64 + row)*512 + c0 + col], &Ks[row*72 + col]);
      stage4b(&Vp[(size_t)(c0 + row)*576 + sc*64 + col], &Vs[row*72 + col]);
    }
    __syncthreads();
    v4f sa[4];
    #pragma unroll
    for (int sj = 0; sj < 4; ++sj) sa[sj] = (v4f){0.f,0.f,0.f,0.f};
    #pragma unroll
    for (int sj = 0; sj < 4; ++sj){
      v8s b0 = *(const v8s*)&Ks[(sj*16 + r15)*72 + quad*8];
      v8s b1 = *(const v8s*)&Ks[(sj*16 + r15)*72 + 32 + quad*8];
      sa[sj] = __builtin_amdgcn_mfma_f32_16x16x32_bf16(aq0, b0, sa[sj], 0, 0, 0);
      sa[sj] = __builtin_amdgcn_mfma_f32_16x16x32_bf16(aq1, b1, sa[sj], 0, 0, 0);
    }
    float cmx[4] = {-1e30f,-1e30f,-1e30f,-1e30f};
    #pragma unroll
    for (int sj = 0; sj < 4; ++sj)
      #pragma unroll
      for (int rg = 0; rg < 4; ++rg){
        float v = sa[sj][rg]*0.125f;
        sa[sj][rg] = v;
        cmx[rg] = fmaxf(cmx[rg], v);
      }
    #pragma unroll
    for (int off = 1; off < 16; off <<= 1)
      #pragma unroll
      for (int rg = 0; rg < 4; ++rg) cmx[rg] = fmaxf(cmx[rg], __shfl_xor(cmx[rg], off, 64));
    float alpha[4];
    #pragma unroll
    for (int rg = 0; rg < 4; ++rg){
      float mnew = fmaxf(m_run[rg], cmx[rg]);
      alpha[rg] = __expf(m_run[rg] - mnew);
      m_run[rg] = mnew;
    }
    float psum[4] = {0.f,0.f,0.f,0.f};
    #pragma unroll
    for (int sj = 0; sj < 4; ++sj)
      #pragma unroll
      for (int rg = 0; rg < 4; ++rg){
        float e = __expf(sa[sj][rg] - m_run[rg]);
        sa[sj][rg] = e; psum[rg] += e;
      }
    #pragma unroll
    for (int off = 1; off < 16; off <<= 1)
      #pragma unroll
      for (int rg = 0; rg < 4; ++rg) psum[rg] += __shfl_xor(psum[rg], off, 64);
    #pragma unroll
    for (int rg = 0; rg < 4; ++rg) l_run[rg] = l_run[rg]*alpha[rg] + psum[rg];
    #pragma unroll
    for (int ni = 0; ni < 4; ++ni)
      #pragma unroll
      for (int rg = 0; rg < 4; ++rg) oc[ni][rg] *= alpha[rg];
    #pragma unroll
    for (int sj = 0; sj < 4; ++sj)
      #pragma unroll
      for (int rg = 0; rg < 4; ++rg)
        Ps[w][(quad*4 + rg)*72 + sj*16 + r15] = f2b(sa[sj][rg]);
    #pragma unroll
    for (int ks = 0; ks < 2; ++ks){
      v8s a = *(const v8s*)&Ps[w][r15*72 + ks*32 + quad*8];
      #pragma unroll
      for (int ni = 0; ni < 4; ++ni){
        v8s b = *(const v8s*)&Vs[(ni*16 + r15)*72 + ks*32 + quad*8];
        oc[ni] = __builtin_amdgcn_mfma_f32_16x16x32_bf16(a, b, oc[ni], 0, 0, 0);
      }
    }
  }
  float inv[4];
  #pragma unroll
  for (int rg = 0; rg < 4; ++rg) inv[rg] = 1.f / l_run[rg];
  #pragma unroll
  for (int ni = 0; ni < 4; ++ni)
    #pragma unroll
    for (int rg = 0; rg < 4; ++rg){
      int t = t0*64 + w*16 + quad*4 + rg;
      attT[(size_t)(nl*576 + t)*512 + c0 + ni*16 + r15] = f2b(oc[ni][rg]*inv[rg]);
    }
}

// ---------------------------------------------------------------- K4: spatial proj + residual (MFMA)
__global__ __launch_bounds__(256) void k_proj_s_mfma(const bf16* __restrict__ AT,
        const void* __restrict__ W, const void* __restrict__ Bv,
        const void* __restrict__ xin, bf16* __restrict__ x2,
        const int* __restrict__ flag, int n0){
  const bool f32in = flag[0] != 0;
  const int o0 = blockIdx.x * 128;
  const int l0 = blockIdx.y * 64;
  const int nl = blockIdx.z;
  const int n = n0 + nl;
  const int b = n >> 4, t = n & 15;
  const int tid = threadIdx.x, lane = tid & 63;
  const int wm = (tid >> 6) & 1, wn = tid >> 7;
  const int r15 = lane & 15, quad = lane >> 4;
  __shared__ bf16 As[128*72];
  __shared__ bf16 Bs[64*72];
  v4f acc[4][2];
  #pragma unroll
  for (int i = 0; i < 4; ++i)
    #pragma unroll
    for (int j = 0; j < 2; ++j) acc[i][j] = (v4f){0.f,0.f,0.f,0.f};
  for (int kc = 0; kc < 512; kc += 64){
    __syncthreads();
    #pragma unroll
    for (int r = 0; r < 8; ++r){
      int e4 = (tid + 256*r)*4;
      int row = e4 >> 6, k = e4 & 63;
      stage4(W, (size_t)(o0+row)*512 + kc + k, f32in, &As[row*72 + k]);
    }
    #pragma unroll
    for (int r = 0; r < 4; ++r){
      int e4 = (tid + 256*r)*4;
      int row = e4 >> 6, k = e4 & 63;
      stage4b(&AT[(size_t)(nl*576 + l0 + row)*512 + kc + k], &Bs[row*72 + k]);
    }
    __syncthreads();
    #pragma unroll
    for (int ks = 0; ks < 2; ++ks){
      v8s a[4], b[2];
      #pragma unroll
      for (int mi = 0; mi < 4; ++mi)
        a[mi] = *(const v8s*)&As[(wm*64 + mi*16 + r15)*72 + ks*32 + quad*8];
      #pragma unroll
      for (int ni = 0; ni < 2; ++ni)
        b[ni] = *(const v8s*)&Bs[(wn*32 + ni*16 + r15)*72 + ks*32 + quad*8];
      #pragma unroll
      for (int mi = 0; mi < 4; ++mi)
        #pragma unroll
        for (int ni = 0; ni < 2; ++ni)
          acc[mi][ni] = __builtin_amdgcn_mfma_f32_16x16x32_bf16(a[mi], b[ni], acc[mi][ni], 0, 0, 0);
    }
  }
  #pragma unroll
  for (int mi = 0; mi < 4; ++mi)
    #pragma unroll
    for (int rg = 0; rg < 4; ++rg){
      int o = o0 + wm*64 + mi*16 + quad*4 + rg;
      float bia = ldin(Bv, o, f32in);
      #pragma unroll
      for (int ni = 0; ni < 2; ++ni){
        int l = l0 + wn*32 + ni*16 + r15;
        size_t addr = ((size_t)(b*512 + o)*16 + t)*576 + l;
        x2[addr] = f2b(acc[mi][ni][rg] + bia + ldin(xin, addr, f32in));
      }
    }
}

// ---------------------------------------------------------------- K5: temporal groupnorm -> xnT [m][t][c]
__global__ __launch_bounds__(256) void k_gn_t(const bf16* __restrict__ x2,
        const void* __restrict__ gw, const void* __restrict__ gb,
        bf16* __restrict__ xnT, const int* __restrict__ flag, int m0){
  const bool f32in = flag[0] != 0;
  const int ml = blockIdx.x;
  const int m = m0 + ml;
  const int b = m / 576, l = m - b*576;
  const int tid = threadIdx.x;
  __shared__ float xs[8192];
  __shared__ float mg[32], rg[32];
  for (int i = tid; i < 8192; i += 256){
    int t = i >> 9, c = i & 511;
    xs[i] = b2f(x2[((b*512 + c)*16 + t)*576 + l]);
  }
  __syncthreads();
  {
    int g = tid >> 3, ii = tid & 7;
    float s = 0.f, q = 0.f;
    for (int idx = ii; idx < 256; idx += 8){
      int t = idx >> 4, cg = idx & 15;
      float v = xs[t*512 + g*16 + cg]; s += v; q += v*v;
    }
    #pragma unroll
    for (int off = 1; off < 8; off <<= 1){ s += __shfl_xor(s, off, 64); q += __shfl_xor(q, off, 64); }
    if (ii == 0){
      float mean = s*(1.f/256.f);
      float var  = q*(1.f/256.f) - mean*mean;
      mg[g] = mean; rg[g] = rsqrtf(fmaxf(var, 0.f) + 1e-5f);
    }
  }
  __syncthreads();
  for (int i = tid; i < 8192; i += 256){
    int c = i & 511, g = c >> 4;
    xnT[(size_t)ml*8192 + i] = f2b((xs[i] - mg[g])*rg[g]*ldin(gw, c, f32in) + ldin(gb, c, f32in));
  }
}

// ---------------------------------------------------------------- K6: temporal qkv GEMM (MFMA, XCD-swizzled, 4 m per block)
__global__ __launch_bounds__(256) void k_qkv_t_mfma(const bf16* __restrict__ XT,
        const bf16* __restrict__ Wb, const void* __restrict__ Bv,
        bf16* __restrict__ Y, const int* __restrict__ flag){
  const bool f32in = flag[0] != 0;
  const int bid = blockIdx.x;
  const int xcd = bid & 7, slot = bid >> 3;
  const int grp_local = slot / 12, oi = slot - grp_local*12;
  const int mg0 = (xcd + 8*grp_local) * 4;
  const int o0 = oi * 128;
  const int tid = threadIdx.x, lane = tid & 63;
  const int wm = (tid >> 6) & 1, wn = tid >> 7;
  const int r15 = lane & 15, quad = lane >> 4;
  __shared__ bf16 As[128*72];
  __shared__ bf16 Bs[64*72];
  v4f acc[4][2];
  #pragma unroll
  for (int i = 0; i < 4; ++i)
    #pragma unroll
    for (int j = 0; j < 2; ++j) acc[i][j] = (v4f){0.f,0.f,0.f,0.f};
  for (int kc = 0; kc < 512; kc += 64){
    __syncthreads();
    #pragma unroll
    for (int r = 0; r < 8; ++r){
      int e4 = (tid + 256*r)*4;
      int row = e4 >> 6, k = e4 & 63;
      stage4b(&Wb[(size_t)(o0+row)*512 + kc + k], &As[row*72 + k]);
    }
    #pragma unroll
    for (int r = 0; r < 4; ++r){
      int e4 = (tid + 256*r)*4;
      int row = e4 >> 6, k = e4 & 63;
      stage4b(&XT[(size_t)(mg0 + (row >> 4))*8192 + (row & 15)*512 + kc + k], &Bs[row*72 + k]);
    }
    __syncthreads();
    #pragma unroll
    for (int ks = 0; ks < 2; ++ks){
      v8s a[4], b[2];
      #pragma unroll
      for (int mi = 0; mi < 4; ++mi)
        a[mi] = *(const v8s*)&As[(wm*64 + mi*16 + r15)*72 + ks*32 + quad*8];
      #pragma unroll
      for (int ni = 0; ni < 2; ++ni)
        b[ni] = *(const v8s*)&Bs[(wn*32 + ni*16 + r15)*72 + ks*32 + quad*8];
      #pragma unroll
      for (int mi = 0; mi < 4; ++mi)
        #pragma unroll
        for (int ni = 0; ni < 2; ++ni)
          acc[mi][ni] = __builtin_amdgcn_mfma_f32_16x16x32_bf16(a[mi], b[ni], acc[mi][ni], 0, 0, 0);
    }
  }
  #pragma unroll
  for (int mi = 0; mi < 4; ++mi)
    #pragma unroll
    for (int rg = 0; rg < 4; ++rg){
      int o = o0 + wm*64 + mi*16 + quad*4 + rg;
      float bia = ldin(Bv, o, f32in);
      #pragma unroll
      for (int ni = 0; ni < 2; ++ni){
        int nidx = wn*32 + ni*16 + r15;
        int mb = nidx >> 4, t = nidx & 15;
        Y[((size_t)(mg0 + mb)*1536 + o)*16 + t] = f2b(acc[mi][ni][rg] + bia);
      }
    }
}

// ---------------------------------------------------------------- K7: temporal attention -> attT [m][t][c]
__global__ __launch_bounds__(256) void k_attn_t(const bf16* __restrict__ qkv,
        const void* __restrict__ tbk, const void* __restrict__ tbv,
        bf16* __restrict__ attT, const int* __restrict__ flag){
  const bool f32in = flag[0] != 0;
  const int head = blockIdx.x;
  const int ml = blockIdx.y;
  const int tid = threadIdx.x;
  __shared__ float qs[1024], ks[1024], vs[1024];
  __shared__ float tk[33*65], tv[33*65];
  __shared__ float ps[16*17];
  const int base = (ml*1536 + head*64)*16;
  for (int i = tid; i < 1024; i += 256){
    qs[i] = b2f(qkv[base + i]);
    ks[i] = b2f(qkv[base + 512*16 + i]);
    vs[i] = b2f(qkv[base + 1024*16 + i]);
  }
  for (int i = tid; i < 33*64; i += 256){
    int row = i >> 6, col = i & 63;
    tk[row*65 + col] = ldin(tbk, i, f32in);
    tv[row*65 + col] = ldin(tbv, i, f32in);
  }
  __syncthreads();
  {
    const int t = tid >> 4, s = tid & 15;
    float qk = 0.f, rpe = 0.f;
    #pragma unroll
    for (int c = 0; c < 64; ++c){
      qk  += qs[c*16 + t]*ks[c*16 + s];
      rpe += qs[c*16 + s]*tk[(t - s + 16)*65 + c];
    }
    float logit = 0.125f*qk + 0.35355339059327373f*rpe;
    if (s > t) logit = -1e8f;
    float mx = logit;
    #pragma unroll
    for (int off = 8; off; off >>= 1) mx = fmaxf(mx, __shfl_xor(mx, off, 16));
    float e = __expf(logit - mx);
    float tot = e;
    #pragma unroll
    for (int off = 8; off; off >>= 1) tot += __shfl_xor(tot, off, 16);
    ps[t*17 + s] = e / tot;
  }
  __syncthreads();
  {
    const int c4 = tid >> 4, t = tid & 15;
    #pragma unroll
    for (int u = 0; u < 4; ++u){
      int c = c4 + 16*u;
      float a = 0.f;
      #pragma unroll
      for (int s = 0; s < 16; ++s)
        a += ps[t*17 + s]*(vs[c*16 + s] + tv[(s - t + 16)*65 + c]);
      attT[(size_t)ml*8192 + t*512 + head*64 + c] = f2b(a);
    }
  }
}

// ---------------------------------------------------------------- K8: temporal proj + residual -> out (MFMA, coalesced)
// N-tile = (2 t, 32 m) with m fastest: 16 consecutive lanes -> 16 consecutive l
// -> coalesced out-store and x2-load (R10: t-fast mapping gave 2x write amp,
// 977 GB/s scatter-bound, 140 us). Grid (4 o, 8 t-pair, MCH/32 m-groups).
__global__ __launch_bounds__(256) void k_proj_t_mfma(const bf16* __restrict__ AT,
        const bf16* __restrict__ Wb, const void* __restrict__ Bv,
        const bf16* __restrict__ x2, void* __restrict__ out,
        const int* __restrict__ flag, int m0){
  const bool f32in = flag[0] != 0;
  const int o0 = blockIdx.x * 128;
  const int tp = blockIdx.y;            // t-pair: covers t = 2*tp, 2*tp+1
  const int mg0 = blockIdx.z * 32;      // chunk-local m base (32 | 576)
  const int tid = threadIdx.x, lane = tid & 63;
  const int wm = (tid >> 6) & 1, wn = tid >> 7;
  const int r15 = lane & 15, quad = lane >> 4;
  __shared__ bf16 As[128*72];
  __shared__ bf16 Bs[64*72];
  v4f acc[4][2];
  #pragma unroll
  for (int i = 0; i < 4; ++i)
    #pragma unroll
    for (int j = 0; j < 2; ++j) acc[i][j] = (v4f){0.f,0.f,0.f,0.f};
  for (int kc = 0; kc < 512; kc += 64){
    __syncthreads();
    #pragma unroll
    for (int r = 0; r < 8; ++r){
      int e4 = (tid + 256*r)*4;
      int row = e4 >> 6, k = e4 & 63;
      stage4b(&Wb[(size_t)(o0+row)*512 + kc + k], &As[row*72 + k]);
    }
    #pragma unroll
    for (int r = 0; r < 4; ++r){
      int e4 = (tid + 256*r)*4;
      int row = e4 >> 6, k = e4 & 63;   // row = nidx: ts = row>>5, mm = row&31
      stage4b(&AT[(size_t)(mg0 + (row & 31))*8192 + (tp*2 + (row >> 5))*512 + kc + k],
              &Bs[row*72 + k]);
    }
    __syncthreads();
    #pragma unroll
    for (int ks = 0; ks < 2; ++ks){
      v8s a[4], b[2];
      #pragma unroll
      for (int mi = 0; mi < 4; ++mi)
        a[mi] = *(const v8s*)&As[(wm*64 + mi*16 + r15)*72 + ks*32 + quad*8];
      #pragma unroll
      for (int ni = 0; ni < 2; ++ni)
        b[ni] = *(const v8s*)&Bs[(wn*32 + ni*16 + r15)*72 + ks*32 + quad*8];
      #pragma unroll
      for (int mi = 0; mi < 4; ++mi)
        #pragma unroll
        for (int ni = 0; ni < 2; ++ni)
          acc[mi][ni] = __builtin_amdgcn_mfma_f32_16x16x32_bf16(a[mi], b[ni], acc[mi][ni], 0, 0, 0);
    }
  }
  const int tt = tp*2 + wn;             // nidx>>5 == wn
  #pragma unroll
  for (int mi = 0; mi < 4; ++mi)
    #pragma unroll
    for (int rg = 0; rg < 4; ++rg){
      int o = o0 + wm*64 + mi*16 + quad*4 + rg;
      float bia = ldin(Bv, o, f32in);
      #pragma unroll
      for (int ni = 0; ni < 2; ++ni){
        int m = m0 + mg0 + ni*16 + r15; // consecutive lanes -> consecutive m/l
        int b = m / 576, l = m - b*576;
        size_t addr = ((size_t)(b*512 + o)*16 + tt)*576 + l;
        float val = acc[mi][ni][rg] + bia + b2f(x2[addr]);
        if (f32in) ((float*)out)[addr] = val;
        else       ((bf16*)out)[addr] = f2b(val);
      }
    }
}

// ----------------------------------------------------------------
extern "C" void kernel_launch(void* const* d_in, const int* in_sizes, int n_in,
                              void* d_out, int out_size, void* d_ws, size_t ws_size,
                              hipStream_t stream){
  const void* x   = d_in[0];
  const void* nsw = d_in[1];
  const void* nsb = d_in[2];
  const void* qsw = d_in[3];
  const void* qsb = d_in[4];
  const void* psw = d_in[5];
  const void* psb = d_in[6];
  const void* ntw = d_in[7];
  const void* ntb = d_in[8];
  const void* qtw = d_in[9];
  const void* qtb = d_in[10];
  const void* ptw = d_in[11];
  const void* ptb = d_in[12];
  const void* rpk = d_in[13];
  const void* rpv = d_in[14];

  // Pick chunking from ws_size (constant across calls -> graph-safe).
  const size_t S_full = (size_t)32*294912;
  const size_t need_full = 256 + (S_full*5 + 9437184)*2;
  const int NCH = (ws_size >= need_full) ? 32 : 8;       // n per spatial pass
  const int MCH = (NCH == 32) ? 1152 : 288;              // m per temporal pass
  const size_t S = (size_t)NCH*294912;                   // elems per A/A2 region

  int*  flag = (int*)d_ws;
  bf16* A  = (bf16*)((char*)d_ws + 256);   // S: xnT_s / xnT_t
  bf16* A2 = A  + S;                        // S: attT_s / attT_t (+ transient bf16 W copy)
  bf16* Bq = A2 + S;                        // 3S: qkv (+ transient proj_t W copy)
  bf16* Cx = Bq + 3*S;                      // 9,437,184: x2 residual (always full)
  const size_t kOff = S, vOff = 2*S;        // K/V segment offsets inside Bq
  bf16* Wcv  = A2;                          // qkv W copy (clobbered by attn outputs)
  bf16* Wcv2 = Bq;                          // proj_t W copy (qkv_t dead after attn_t)

  k_detect<<<1, 64, 0, stream>>>(x, flag);

  for (int n0 = 0; n0 < 32; n0 += NCH){
    k_gn_s       <<<dim3(32, NCH),   256, 0, stream>>>(x, nsw, nsb, A, flag, n0);
    k_cvtw       <<<dim3(768),       256, 0, stream>>>(qsw, Wcv, 196608, flag);
    k_qkv_s_mfma <<<dim3(108*NCH),   256, 0, stream>>>(A, Wcv, qsb, Bq, flag, kOff, vOff);
    k_attn_s_mfma<<<dim3(72*NCH),    256, 0, stream>>>(Bq, A2, kOff, vOff);
    k_proj_s_mfma<<<dim3(4, 9, NCH), 256, 0, stream>>>(A2, psw, psb, x, Cx, flag, n0);
  }
  for (int m0 = 0; m0 < 1152; m0 += MCH){
    k_gn_t       <<<dim3(MCH),       256, 0, stream>>>(Cx, ntw, ntb, A, flag, m0);
    k_cvtw       <<<dim3(768),       256, 0, stream>>>(qtw, Wcv, 196608, flag);
    k_qkv_t_mfma <<<dim3(3*MCH),     256, 0, stream>>>(A, Wcv, qtb, Bq, flag);
    k_attn_t     <<<dim3(8, MCH),    256, 0, stream>>>(Bq, rpk, rpv, A2, flag);
    k_cvtw       <<<dim3(256),       256, 0, stream>>>(ptw, Wcv2, 65536, flag);
    k_proj_t_mfma<<<dim3(4, 8, MCH/32), 256, 0, stream>>>(A2, Wcv2, ptb, Cx, d_out, flag, m0);
  }
}

// Round 12
// 595.114 us; speedup vs baseline: 8.8125x; 1.0455x over previous
//
#include <hip/hip_runtime.h>
#include <hip/hip_bf16.h>

typedef __hip_bfloat16 bf16;
typedef __attribute__((ext_vector_type(8))) short v8s;
typedef __attribute__((ext_vector_type(4))) float v4f;

__device__ __forceinline__ float b2f(bf16 v){ return __bfloat162float(v); }
__device__ __forceinline__ bf16  f2b(float v){ return __float2bfloat16(v); }

// Inputs may be bf16 OR f32 — runtime-detected flag (1 => f32). Output dtype follows.
__device__ __forceinline__ float ldin(const void* p, int i, bool f32in){
  return f32in ? ((const float*)p)[i] : b2f(((const bf16*)p)[i]);
}

// stage 4 consecutive source elems (f32-or-bf16) into dst as bf16 (8B write)
__device__ __forceinline__ void stage4(const void* src, size_t off, bool f32in, bf16* dst){
  union { bf16 h[4]; ushort4 u; } tmp;
  if (f32in){
    float4 f = *(const float4*)((const float*)src + off);
    tmp.h[0] = f2b(f.x); tmp.h[1] = f2b(f.y); tmp.h[2] = f2b(f.z); tmp.h[3] = f2b(f.w);
  } else {
    tmp.u = *(const ushort4*)((const ushort*)src + off);
  }
  *(ushort4*)dst = tmp.u;
}
__device__ __forceinline__ void stage4b(const bf16* src, bf16* dst){
  *(ushort4*)dst = *(const ushort4*)src;
}

// Problem: B=2, C=512, T=16, H=W=24, heads=8, ch=64
// ws: flag | A (S) | A2 (S) | Bq (3S) | Cx 9,437,184 | [Cx2 9,437,184 if room]
// Cx2 = x2 in [m][t][c] layout so gn_t reads coalesced (R11: gn_t gather was
// 2B loads at 18KB stride).

// ---------------------------------------------------------------- detect input dtype
__global__ void k_detect(const void* x, int* flag){
  int tid = threadIdx.x;
  const bf16* p = (const bf16*)x;
  int cnt = 0;
  for (int i = tid; i < 512; i += 64){
    float v = b2f(p[i]);
    if (!(fabsf(v) <= 64.f)) cnt++;
  }
  #pragma unroll
  for (int off = 32; off; off >>= 1) cnt += __shfl_down(cnt, off, 64);
  if (tid == 0) flag[0] = (cnt > 16) ? 1 : 0;
}

// ---------------------------------------------------------------- weight convert -> bf16 scratch
__global__ __launch_bounds__(256) void k_cvtw(const void* __restrict__ W,
        bf16* __restrict__ out, int n4, const int* __restrict__ flag){
  const bool f32in = flag[0] != 0;
  int i = blockIdx.x*256 + threadIdx.x;
  if (i < n4) stage4(W, (size_t)i*4, f32in, out + (size_t)i*4);
}

// ---------------------------------------------------------------- K1: spatial groupnorm -> xnT [l][c]
__global__ __launch_bounds__(256) void k_gn_s(const void* __restrict__ x,
        const void* __restrict__ gw, const void* __restrict__ gb,
        bf16* __restrict__ xnT, const int* __restrict__ flag, int n0){
  const bool f32in = flag[0] != 0;
  const int g = blockIdx.x;
  const int nl = blockIdx.y;
  const int n = n0 + nl;
  const int b = n >> 4, t = n & 15;
  const int tid = threadIdx.x;
  __shared__ float xs[576*17];     // [l][cg] padded
  __shared__ float red[4][2];
  __shared__ float stats[2];
  float s = 0.f, q = 0.f;
  for (int i = tid; i < 9216; i += 256){
    int cg = i / 576, l = i - cg*576;
    int c = g*16 + cg;
    float v = ldin(x, ((b*512 + c)*16 + t)*576 + l, f32in);
    xs[l*17 + cg] = v; s += v; q += v*v;
  }
  #pragma unroll
  for (int off = 32; off; off >>= 1){ s += __shfl_down(s, off, 64); q += __shfl_down(q, off, 64); }
  int wid = tid >> 6;
  if ((tid & 63) == 0){ red[wid][0] = s; red[wid][1] = q; }
  __syncthreads();
  if (tid == 0){
    float S = red[0][0]+red[1][0]+red[2][0]+red[3][0];
    float Q = red[0][1]+red[1][1]+red[2][1]+red[3][1];
    float mean = S * (1.f/9216.f);
    float var  = Q * (1.f/9216.f) - mean*mean;
    stats[0] = mean; stats[1] = rsqrtf(fmaxf(var, 0.f) + 1e-5f);
  }
  __syncthreads();
  float mean = stats[0], rstd = stats[1];
  for (int i = tid; i < 9216; i += 256){
    int l = i >> 4, cg = i & 15;
    int c = g*16 + cg;
    xnT[(size_t)(nl*576 + l)*512 + c] =
        f2b((xs[l*17 + cg] - mean)*rstd*ldin(gw, c, f32in) + ldin(gb, c, f32in));
  }
}

// ---------------------------------------------------------------- K2: spatial qkv GEMM (MFMA, XCD-swizzled)
__global__ __launch_bounds__(256) void k_qkv_s_mfma(const bf16* __restrict__ XT,
        const bf16* __restrict__ Wb, const void* __restrict__ Bv,
        bf16* __restrict__ Y, const int* __restrict__ flag,
        size_t kOff, size_t vOff){
  const bool f32in = flag[0] != 0;
  const int bid = blockIdx.x;
  const int xcd = bid & 7, slot = bid >> 3;
  const int grp_local = slot / 12, oi = slot - grp_local*12;
  const int group = xcd + 8*grp_local;      // 0..9*NCH-1
  const int nl = group / 9;
  const int l0 = (group - nl*9) * 64;
  const int o0 = oi * 128;
  const int tid = threadIdx.x, lane = tid & 63;
  const int wm = (tid >> 6) & 1, wn = tid >> 7;
  const int r15 = lane & 15, quad = lane >> 4;
  __shared__ bf16 As[64*72];
  __shared__ bf16 Bs[128*72];
  v4f acc[2][4];
  #pragma unroll
  for (int i = 0; i < 2; ++i)
    #pragma unroll
    for (int j = 0; j < 4; ++j) acc[i][j] = (v4f){0.f,0.f,0.f,0.f};
  for (int kc = 0; kc < 512; kc += 64){
    __syncthreads();
    #pragma unroll
    for (int r = 0; r < 4; ++r){
      int e4 = (tid + 256*r)*4;
      int row = e4 >> 6, k = e4 & 63;
      stage4b(&XT[(size_t)(nl*576 + l0 + row)*512 + kc + k], &As[row*72 + k]);
    }
    #pragma unroll
    for (int r = 0; r < 8; ++r){
      int e4 = (tid + 256*r)*4;
      int row = e4 >> 6, k = e4 & 63;
      stage4b(&Wb[(size_t)(o0+row)*512 + kc + k], &Bs[row*72 + k]);
    }
    __syncthreads();
    #pragma unroll
    for (int ks = 0; ks < 2; ++ks){
      v8s a[2], b[4];
      #pragma unroll
      for (int mi = 0; mi < 2; ++mi)
        a[mi] = *(const v8s*)&As[(wm*32 + mi*16 + r15)*72 + ks*32 + quad*8];
      #pragma unroll
      for (int ni = 0; ni < 4; ++ni)
        b[ni] = *(const v8s*)&Bs[(wn*64 + ni*16 + r15)*72 + ks*32 + quad*8];
      #pragma unroll
      for (int mi = 0; mi < 2; ++mi)
        #pragma unroll
        for (int ni = 0; ni < 4; ++ni)
          acc[mi][ni] = __builtin_amdgcn_mfma_f32_16x16x32_bf16(a[mi], b[ni], acc[mi][ni], 0, 0, 0);
    }
  }
  const int seg = o0 >> 9;  // 0=Q,1=K,2=V
  size_t segbase = ((seg==0) ? 0 : (seg==1) ? kOff : vOff) + (size_t)nl*294912;
  const int ob = o0 & 511;
  #pragma unroll
  for (int mi = 0; mi < 2; ++mi)
    #pragma unroll
    for (int ni = 0; ni < 4; ++ni){
      int oseg = ob + wn*64 + ni*16 + r15;
      float bia = ldin(Bv, o0 + wn*64 + ni*16 + r15, f32in);
      #pragma unroll
      for (int rg = 0; rg < 4; ++rg){
        int l = l0 + wm*32 + mi*16 + quad*4 + rg;
        float val = acc[mi][ni][rg] + bia;
        size_t dst = (seg==2) ? segbase + (size_t)oseg*576 + l
                              : segbase + (size_t)l*512 + oseg;
        Y[dst] = f2b(val);
      }
    }
}

// ---------------------------------------------------------------- K3: spatial attention (flash MFMA) -> attT [l][c]
__global__ __launch_bounds__(256, 4) void k_attn_s_mfma(const bf16* __restrict__ qkv,
        bf16* __restrict__ attT, size_t kOff, size_t vOff){
  const int bid = blockIdx.x;
  const int xcd = bid & 7, slot = bid >> 3;
  const int nl = xcd + 8*(slot/72);
  const int idx = slot - 72*(slot/72);
  const int head = idx/9, t0 = idx - 9*head;
  const int tid = threadIdx.x, lane = tid & 63, w = tid >> 6;
  const int r15 = lane & 15, quad = lane >> 4;
  __shared__ bf16 Ks[64*72];
  __shared__ bf16 Vs[64*72];
  __shared__ bf16 Ps[4][16*72];
  const bf16* QT = qkv + (size_t)nl*294912;
  const bf16* KT = qkv + kOff + (size_t)nl*294912;
  const bf16* Vp = qkv + vOff + (size_t)nl*294912;
  const int c0 = head*64;
  v8s aq0, aq1;
  {
    const bf16* qrow = QT + (size_t)(t0*64 + w*16 + r15)*512 + c0;
    aq0 = *(const v8s*)(qrow + quad*8);
    aq1 = *(const v8s*)(qrow + 32 + quad*8);
  }
  v4f oc[4];
  #pragma unroll
  for (int ni = 0; ni < 4; ++ni) oc[ni] = (v4f){0.f,0.f,0.f,0.f};
  float m_run[4] = {-1e30f,-1e30f,-1e30f,-1e30f};
  float l_run[4] = {0.f,0.f,0.f,0.f};
  for (int sc = 0; sc < 9; ++sc){
    __syncthreads();
    #pragma unroll
    for (int r = 0; r < 4; ++r){
      int e4 = (tid + 256*r)*4;
      int row = e4 >> 6, col = e4 & 63;
      stage4b(&KT[(size_t)(sc*64 + row)*512 + c0 + col], &Ks[row*72 + col]);
      stage4b(&Vp[(size_t)(c0 + row)*576 + sc*64 + col], &Vs[row*72 + col]);
    }
    __syncthreads();
    v4f sa[4];
    #pragma unroll
    for (int sj = 0; sj < 4; ++sj) sa[sj] = (v4f){0.f,0.f,0.f,0.f};
    #pragma unroll
    for (int sj = 0; sj < 4; ++sj){
      v8s b0 = *(const v8s*)&Ks[(sj*16 + r15)*72 + quad*8];
      v8s b1 = *(const v8s*)&Ks[(sj*16 + r15)*72 + 32 + quad*8];
      sa[sj] = __builtin_amdgcn_mfma_f32_16x16x32_bf16(aq0, b0, sa[sj], 0, 0, 0);
      sa[sj] = __builtin_amdgcn_mfma_f32_16x16x32_bf16(aq1, b1, sa[sj], 0, 0, 0);
    }
    float cmx[4] = {-1e30f,-1e30f,-1e30f,-1e30f};
    #pragma unroll
    for (int sj = 0; sj < 4; ++sj)
      #pragma unroll
      for (int rg = 0; rg < 4; ++rg){
        float v = sa[sj][rg]*0.125f;
        sa[sj][rg] = v;
        cmx[rg] = fmaxf(cmx[rg], v);
      }
    #pragma unroll
    for (int off = 1; off < 16; off <<= 1)
      #pragma unroll
      for (int rg = 0; rg < 4; ++rg) cmx[rg] = fmaxf(cmx[rg], __shfl_xor(cmx[rg], off, 64));
    float alpha[4];
    #pragma unroll
    for (int rg = 0; rg < 4; ++rg){
      float mnew = fmaxf(m_run[rg], cmx[rg]);
      alpha[rg] = __expf(m_run[rg] - mnew);
      m_run[rg] = mnew;
    }
    float psum[4] = {0.f,0.f,0.f,0.f};
    #pragma unroll
    for (int sj = 0; sj < 4; ++sj)
      #pragma unroll
      for (int rg = 0; rg < 4; ++rg){
        float e = __expf(sa[sj][rg] - m_run[rg]);
        sa[sj][rg] = e; psum[rg] += e;
      }
    #pragma unroll
    for (int off = 1; off < 16; off <<= 1)
      #pragma unroll
      for (int rg = 0; rg < 4; ++rg) psum[rg] += __shfl_xor(psum[rg], off, 64);
    #pragma unroll
    for (int rg = 0; rg < 4; ++rg) l_run[rg] = l_run[rg]*alpha[rg] + psum[rg];
    #pragma unroll
    for (int ni = 0; ni < 4; ++ni)
      #pragma unroll
      for (int rg = 0; rg < 4; ++rg) oc[ni][rg] *= alpha[rg];
    #pragma unroll
    for (int sj = 0; sj < 4; ++sj)
      #pragma unroll
      for (int rg = 0; rg < 4; ++rg)
        Ps[w][(quad*4 + rg)*72 + sj*16 + r15] = f2b(sa[sj][rg]);
    #pragma unroll
    for (int ks = 0; ks < 2; ++ks){
      v8s a = *(const v8s*)&Ps[w][r15*72 + ks*32 + quad*8];
      #pragma unroll
      for (int ni = 0; ni < 4; ++ni){
        v8s b = *(const v8s*)&Vs[(ni*16 + r15)*72 + ks*32 + quad*8];
        oc[ni] = __builtin_amdgcn_mfma_f32_16x16x32_bf16(a, b, oc[ni], 0, 0, 0);
      }
    }
  }
  float inv[4];
  #pragma unroll
  for (int rg = 0; rg < 4; ++rg) inv[rg] = 1.f / l_run[rg];
  #pragma unroll
  for (int ni = 0; ni < 4; ++ni)
    #pragma unroll
    for (int rg = 0; rg < 4; ++rg){
      int t = t0*64 + w*16 + quad*4 + rg;
      attT[(size_t)(nl*576 + t)*512 + c0 + ni*16 + r15] = f2b(oc[ni][rg]*inv[rg]);
    }
}

// ---------------------------------------------------------------- K4: spatial proj + residual (MFMA)
// Optionally dual-writes x2T [m][t][c] so gn_t reads coalesced (doT gate).
__global__ __launch_bounds__(256) void k_proj_s_mfma(const bf16* __restrict__ AT,
        const void* __restrict__ W, const void* __restrict__ Bv,
        const void* __restrict__ xin, bf16* __restrict__ x2,
        bf16* __restrict__ x2T, int doT,
        const int* __restrict__ flag, int n0){
  const bool f32in = flag[0] != 0;
  const int o0 = blockIdx.x * 128;
  const int l0 = blockIdx.y * 64;
  const int nl = blockIdx.z;
  const int n = n0 + nl;
  const int b = n >> 4, t = n & 15;
  const int tid = threadIdx.x, lane = tid & 63;
  const int wm = (tid >> 6) & 1, wn = tid >> 7;
  const int r15 = lane & 15, quad = lane >> 4;
  __shared__ bf16 As[128*72];
  __shared__ bf16 Bs[64*72];
  v4f acc[4][2];
  #pragma unroll
  for (int i = 0; i < 4; ++i)
    #pragma unroll
    for (int j = 0; j < 2; ++j) acc[i][j] = (v4f){0.f,0.f,0.f,0.f};
  for (int kc = 0; kc < 512; kc += 64){
    __syncthreads();
    #pragma unroll
    for (int r = 0; r < 8; ++r){
      int e4 = (tid + 256*r)*4;
      int row = e4 >> 6, k = e4 & 63;
      stage4(W, (size_t)(o0+row)*512 + kc + k, f32in, &As[row*72 + k]);
    }
    #pragma unroll
    for (int r = 0; r < 4; ++r){
      int e4 = (tid + 256*r)*4;
      int row = e4 >> 6, k = e4 & 63;
      stage4b(&AT[(size_t)(nl*576 + l0 + row)*512 + kc + k], &Bs[row*72 + k]);
    }
    __syncthreads();
    #pragma unroll
    for (int ks = 0; ks < 2; ++ks){
      v8s a[4], b[2];
      #pragma unroll
      for (int mi = 0; mi < 4; ++mi)
        a[mi] = *(const v8s*)&As[(wm*64 + mi*16 + r15)*72 + ks*32 + quad*8];
      #pragma unroll
      for (int ni = 0; ni < 2; ++ni)
        b[ni] = *(const v8s*)&Bs[(wn*32 + ni*16 + r15)*72 + ks*32 + quad*8];
      #pragma unroll
      for (int mi = 0; mi < 4; ++mi)
        #pragma unroll
        for (int ni = 0; ni < 2; ++ni)
          acc[mi][ni] = __builtin_amdgcn_mfma_f32_16x16x32_bf16(a[mi], b[ni], acc[mi][ni], 0, 0, 0);
    }
  }
  #pragma unroll
  for (int mi = 0; mi < 4; ++mi)
    #pragma unroll
    for (int rg = 0; rg < 4; ++rg){
      int o = o0 + wm*64 + mi*16 + quad*4 + rg;
      float bia = ldin(Bv, o, f32in);
      #pragma unroll
      for (int ni = 0; ni < 2; ++ni){
        int l = l0 + wn*32 + ni*16 + r15;
        size_t addr = ((size_t)(b*512 + o)*16 + t)*576 + l;
        bf16 v = f2b(acc[mi][ni][rg] + bia + ldin(xin, addr, f32in));
        x2[addr] = v;
        if (doT) x2T[(size_t)(b*576 + l)*8192 + t*512 + o] = v;
      }
    }
}

// ---------------------------------------------------------------- K5a: temporal groupnorm (scattered x2) -> xnT [m][t][c]
__global__ __launch_bounds__(256) void k_gn_t(const bf16* __restrict__ x2,
        const void* __restrict__ gw, const void* __restrict__ gb,
        bf16* __restrict__ xnT, const int* __restrict__ flag, int m0){
  const bool f32in = flag[0] != 0;
  const int ml = blockIdx.x;
  const int m = m0 + ml;
  const int b = m / 576, l = m - b*576;
  const int tid = threadIdx.x;
  __shared__ float xs[8192];
  __shared__ float mg[32], rg[32];
  for (int i = tid; i < 8192; i += 256){
    int t = i >> 9, c = i & 511;
    xs[i] = b2f(x2[((b*512 + c)*16 + t)*576 + l]);
  }
  __syncthreads();
  {
    int g = tid >> 3, ii = tid & 7;
    float s = 0.f, q = 0.f;
    for (int idx = ii; idx < 256; idx += 8){
      int t = idx >> 4, cg = idx & 15;
      float v = xs[t*512 + g*16 + cg]; s += v; q += v*v;
    }
    #pragma unroll
    for (int off = 1; off < 8; off <<= 1){ s += __shfl_xor(s, off, 64); q += __shfl_xor(q, off, 64); }
    if (ii == 0){
      float mean = s*(1.f/256.f);
      float var  = q*(1.f/256.f) - mean*mean;
      mg[g] = mean; rg[g] = rsqrtf(fmaxf(var, 0.f) + 1e-5f);
    }
  }
  __syncthreads();
  for (int i = tid; i < 8192; i += 256){
    int c = i & 511, g = c >> 4;
    xnT[(size_t)ml*8192 + i] = f2b((xs[i] - mg[g])*rg[g]*ldin(gw, c, f32in) + ldin(gb, c, f32in));
  }
}

// ---------------------------------------------------------------- K5b: temporal groupnorm (coalesced x2T)
__global__ __launch_bounds__(256) void k_gn_t2(const bf16* __restrict__ x2T,
        const void* __restrict__ gw, const void* __restrict__ gb,
        bf16* __restrict__ xnT, const int* __restrict__ flag, int m0){
  const bool f32in = flag[0] != 0;
  const int ml = blockIdx.x;
  const int m = m0 + ml;
  const int tid = threadIdx.x;
  __shared__ float xs[8192];
  __shared__ float mg[32], rg[32];
  for (int i = tid; i < 8192; i += 256)
    xs[i] = b2f(x2T[(size_t)m*8192 + i]);     // [t][c] order, fully coalesced
  __syncthreads();
  {
    int g = tid >> 3, ii = tid & 7;
    float s = 0.f, q = 0.f;
    for (int idx = ii; idx < 256; idx += 8){
      int t = idx >> 4, cg = idx & 15;
      float v = xs[t*512 + g*16 + cg]; s += v; q += v*v;
    }
    #pragma unroll
    for (int off = 1; off < 8; off <<= 1){ s += __shfl_xor(s, off, 64); q += __shfl_xor(q, off, 64); }
    if (ii == 0){
      float mean = s*(1.f/256.f);
      float var  = q*(1.f/256.f) - mean*mean;
      mg[g] = mean; rg[g] = rsqrtf(fmaxf(var, 0.f) + 1e-5f);
    }
  }
  __syncthreads();
  for (int i = tid; i < 8192; i += 256){
    int c = i & 511, g = c >> 4;
    xnT[(size_t)ml*8192 + i] = f2b((xs[i] - mg[g])*rg[g]*ldin(gw, c, f32in) + ldin(gb, c, f32in));
  }
}

// ---------------------------------------------------------------- K6: temporal qkv GEMM (MFMA, XCD-swizzled, 4 m per block)
__global__ __launch_bounds__(256) void k_qkv_t_mfma(const bf16* __restrict__ XT,
        const bf16* __restrict__ Wb, const void* __restrict__ Bv,
        bf16* __restrict__ Y, const int* __restrict__ flag){
  const bool f32in = flag[0] != 0;
  const int bid = blockIdx.x;
  const int xcd = bid & 7, slot = bid >> 3;
  const int grp_local = slot / 12, oi = slot - grp_local*12;
  const int mg0 = (xcd + 8*grp_local) * 4;
  const int o0 = oi * 128;
  const int tid = threadIdx.x, lane = tid & 63;
  const int wm = (tid >> 6) & 1, wn = tid >> 7;
  const int r15 = lane & 15, quad = lane >> 4;
  __shared__ bf16 As[128*72];
  __shared__ bf16 Bs[64*72];
  v4f acc[4][2];
  #pragma unroll
  for (int i = 0; i < 4; ++i)
    #pragma unroll
    for (int j = 0; j < 2; ++j) acc[i][j] = (v4f){0.f,0.f,0.f,0.f};
  for (int kc = 0; kc < 512; kc += 64){
    __syncthreads();
    #pragma unroll
    for (int r = 0; r < 8; ++r){
      int e4 = (tid + 256*r)*4;
      int row = e4 >> 6, k = e4 & 63;
      stage4b(&Wb[(size_t)(o0+row)*512 + kc + k], &As[row*72 + k]);
    }
    #pragma unroll
    for (int r = 0; r < 4; ++r){
      int e4 = (tid + 256*r)*4;
      int row = e4 >> 6, k = e4 & 63;
      stage4b(&XT[(size_t)(mg0 + (row >> 4))*8192 + (row & 15)*512 + kc + k], &Bs[row*72 + k]);
    }
    __syncthreads();
    #pragma unroll
    for (int ks = 0; ks < 2; ++ks){
      v8s a[4], b[2];
      #pragma unroll
      for (int mi = 0; mi < 4; ++mi)
        a[mi] = *(const v8s*)&As[(wm*64 + mi*16 + r15)*72 + ks*32 + quad*8];
      #pragma unroll
      for (int ni = 0; ni < 2; ++ni)
        b[ni] = *(const v8s*)&Bs[(wn*32 + ni*16 + r15)*72 + ks*32 + quad*8];
      #pragma unroll
      for (int mi = 0; mi < 4; ++mi)
        #pragma unroll
        for (int ni = 0; ni < 2; ++ni)
          acc[mi][ni] = __builtin_amdgcn_mfma_f32_16x16x32_bf16(a[mi], b[ni], acc[mi][ni], 0, 0, 0);
    }
  }
  #pragma unroll
  for (int mi = 0; mi < 4; ++mi)
    #pragma unroll
    for (int rg = 0; rg < 4; ++rg){
      int o = o0 + wm*64 + mi*16 + quad*4 + rg;
      float bia = ldin(Bv, o, f32in);
      #pragma unroll
      for (int ni = 0; ni < 2; ++ni){
        int nidx = wn*32 + ni*16 + r15;
        int mb = nidx >> 4, t = nidx & 15;
        Y[((size_t)(mg0 + mb)*1536 + o)*16 + t] = f2b(acc[mi][ni][rg] + bia);
      }
    }
}

// ---------------------------------------------------------------- K7: temporal attention -> attT [m][t][c]
// float4-vectorized: q/k/v transposed to [t][c] in LDS (R11: 384 scalar
// ds_read/thread made this LDS-instruction-bound at 96 us).
__global__ __launch_bounds__(256) void k_attn_t(const bf16* __restrict__ qkv,
        const void* __restrict__ tbk, const void* __restrict__ tbv,
        bf16* __restrict__ attT, const int* __restrict__ flag){
  const bool f32in = flag[0] != 0;
  const int head = blockIdx.x;
  const int ml = blockIdx.y;
  const int tid = threadIdx.x;
  __shared__ float qsT[16*68], ksT[16*68], vsT[16*68];  // [t][c], stride 68 (16B-aligned rows)
  __shared__ float tks[33*68], tvs[33*68];              // [d][c]
  __shared__ float ps[16*17];
  const int base = (ml*1536 + head*64)*16;
  for (int i = tid; i < 1024; i += 256){
    int c = i >> 4, t = i & 15;
    qsT[t*68 + c] = b2f(qkv[base + i]);
    ksT[t*68 + c] = b2f(qkv[base + 8192 + i]);
    vsT[t*68 + c] = b2f(qkv[base + 16384 + i]);
  }
  for (int i = tid; i < 33*64; i += 256){
    int d = i >> 6, c = i & 63;
    tks[d*68 + c] = ldin(tbk, i, f32in);
    tvs[d*68 + c] = ldin(tbv, i, f32in);
  }
  __syncthreads();
  {
    const int t = tid >> 4, s = tid & 15;
    const float4* qt = (const float4*)&qsT[t*68];
    const float4* kr = (const float4*)&ksT[s*68];
    const float4* q2 = (const float4*)&qsT[s*68];
    const float4* tr = (const float4*)&tks[(t - s + 16)*68];
    float qk = 0.f, rp = 0.f;
    #pragma unroll
    for (int c4 = 0; c4 < 16; ++c4){
      float4 a = qt[c4], b = kr[c4];
      qk += a.x*b.x + a.y*b.y + a.z*b.z + a.w*b.w;
      float4 a2 = q2[c4], tb = tr[c4];
      rp += a2.x*tb.x + a2.y*tb.y + a2.z*tb.z + a2.w*tb.w;
    }
    float logit = 0.125f*qk + 0.35355339059327373f*rp;
    if (s > t) logit = -1e8f;
    float mx = logit;
    #pragma unroll
    for (int off = 8; off; off >>= 1) mx = fmaxf(mx, __shfl_xor(mx, off, 16));
    float e = __expf(logit - mx);
    float tot = e;
    #pragma unroll
    for (int off = 8; off; off >>= 1) tot += __shfl_xor(tot, off, 16);
    ps[t*17 + s] = e / tot;
  }
  __syncthreads();
  {
    const int c4 = tid & 15, t = tid >> 4;
    float4 acc = {0.f,0.f,0.f,0.f};
    #pragma unroll
    for (int s = 0; s < 16; ++s){
      float p = ps[t*17 + s];
      float4 v4 = *(const float4*)&vsT[s*68 + c4*4];
      float4 t4 = *(const float4*)&tvs[(s - t + 16)*68 + c4*4];
      acc.x += p*(v4.x + t4.x); acc.y += p*(v4.y + t4.y);
      acc.z += p*(v4.z + t4.z); acc.w += p*(v4.w + t4.w);
    }
    union { bf16 h[4]; ushort4 u; } o;
    o.h[0] = f2b(acc.x); o.h[1] = f2b(acc.y); o.h[2] = f2b(acc.z); o.h[3] = f2b(acc.w);
    *(ushort4*)&attT[(size_t)ml*8192 + t*512 + head*64 + c4*4] = o.u;
  }
}

// ---------------------------------------------------------------- K8: temporal proj + residual -> out (MFMA, coalesced)
__global__ __launch_bounds__(256) void k_proj_t_mfma(const bf16* __restrict__ AT,
        const bf16* __restrict__ Wb, const void* __restrict__ Bv,
        const bf16* __restrict__ x2, void* __restrict__ out,
        const int* __restrict__ flag, int m0){
  const bool f32in = flag[0] != 0;
  const int o0 = blockIdx.x * 128;
  const int tp = blockIdx.y;            // t-pair
  const int mg0 = blockIdx.z * 32;      // m base (32 | 576)
  const int tid = threadIdx.x, lane = tid & 63;
  const int wm = (tid >> 6) & 1, wn = tid >> 7;
  const int r15 = lane & 15, quad = lane >> 4;
  __shared__ bf16 As[128*72];
  __shared__ bf16 Bs[64*72];
  v4f acc[4][2];
  #pragma unroll
  for (int i = 0; i < 4; ++i)
    #pragma unroll
    for (int j = 0; j < 2; ++j) acc[i][j] = (v4f){0.f,0.f,0.f,0.f};
  for (int kc = 0; kc < 512; kc += 64){
    __syncthreads();
    #pragma unroll
    for (int r = 0; r < 8; ++r){
      int e4 = (tid + 256*r)*4;
      int row = e4 >> 6, k = e4 & 63;
      stage4b(&Wb[(size_t)(o0+row)*512 + kc + k], &As[row*72 + k]);
    }
    #pragma unroll
    for (int r = 0; r < 4; ++r){
      int e4 = (tid + 256*r)*4;
      int row = e4 >> 6, k = e4 & 63;
      stage4b(&AT[(size_t)(mg0 + (row & 31))*8192 + (tp*2 + (row >> 5))*512 + kc + k],
              &Bs[row*72 + k]);
    }
    __syncthreads();
    #pragma unroll
    for (int ks = 0; ks < 2; ++ks){
      v8s a[4], b[2];
      #pragma unroll
      for (int mi = 0; mi < 4; ++mi)
        a[mi] = *(const v8s*)&As[(wm*64 + mi*16 + r15)*72 + ks*32 + quad*8];
      #pragma unroll
      for (int ni = 0; ni < 2; ++ni)
        b[ni] = *(const v8s*)&Bs[(wn*32 + ni*16 + r15)*72 + ks*32 + quad*8];
      #pragma unroll
      for (int mi = 0; mi < 4; ++mi)
        #pragma unroll
        for (int ni = 0; ni < 2; ++ni)
          acc[mi][ni] = __builtin_amdgcn_mfma_f32_16x16x32_bf16(a[mi], b[ni], acc[mi][ni], 0, 0, 0);
    }
  }
  const int tt = tp*2 + wn;
  #pragma unroll
  for (int mi = 0; mi < 4; ++mi)
    #pragma unroll
    for (int rg = 0; rg < 4; ++rg){
      int o = o0 + wm*64 + mi*16 + quad*4 + rg;
      float bia = ldin(Bv, o, f32in);
      #pragma unroll
      for (int ni = 0; ni < 2; ++ni){
        int m = m0 + mg0 + ni*16 + r15;
        int b = m / 576, l = m - b*576;
        size_t addr = ((size_t)(b*512 + o)*16 + tt)*576 + l;
        float val = acc[mi][ni][rg] + bia + b2f(x2[addr]);
        if (f32in) ((float*)out)[addr] = val;
        else       ((bf16*)out)[addr] = f2b(val);
      }
    }
}

// ----------------------------------------------------------------
extern "C" void kernel_launch(void* const* d_in, const int* in_sizes, int n_in,
                              void* d_out, int out_size, void* d_ws, size_t ws_size,
                              hipStream_t stream){
  const void* x   = d_in[0];
  const void* nsw = d_in[1];
  const void* nsb = d_in[2];
  const void* qsw = d_in[3];
  const void* qsb = d_in[4];
  const void* psw = d_in[5];
  const void* psb = d_in[6];
  const void* ntw = d_in[7];
  const void* ntb = d_in[8];
  const void* qtw = d_in[9];
  const void* qtb = d_in[10];
  const void* ptw = d_in[11];
  const void* ptb = d_in[12];
  const void* rpk = d_in[13];
  const void* rpv = d_in[14];

  // Chunking and x2T gate from ws_size (constant across calls -> graph-safe).
  const size_t S_full = (size_t)32*294912;
  const size_t need_full = 256 + (S_full*5 + 9437184)*2;
  const size_t need_T    = 256 + (S_full*5 + (size_t)2*9437184)*2;  // +18.9 MB for x2T
  const int NCH = (ws_size >= need_full) ? 32 : 8;
  const int MCH = (NCH == 32) ? 1152 : 288;
  const size_t S = (size_t)NCH*294912;
  const int useT = (NCH == 32 && ws_size >= need_T) ? 1 : 0;

  int*  flag = (int*)d_ws;
  bf16* A  = (bf16*)((char*)d_ws + 256);   // S: xnT_s / xnT_t
  bf16* A2 = A  + S;                        // S: attT_s / attT_t (+ transient W copy)
  bf16* Bq = A2 + S;                        // 3S: qkv (+ transient proj_t W copy)
  bf16* Cx = Bq + 3*S;                      // 9,437,184: x2 residual
  bf16* Cx2 = Cx + 9437184;                 // 9,437,184: x2T [m][t][c] (if useT)
  const size_t kOff = S, vOff = 2*S;
  bf16* Wcv  = A2;
  bf16* Wcv2 = Bq;

  k_detect<<<1, 64, 0, stream>>>(x, flag);

  for (int n0 = 0; n0 < 32; n0 += NCH){
    k_gn_s       <<<dim3(32, NCH),   256, 0, stream>>>(x, nsw, nsb, A, flag, n0);
    k_cvtw       <<<dim3(768),       256, 0, stream>>>(qsw, Wcv, 196608, flag);
    k_qkv_s_mfma <<<dim3(108*NCH),   256, 0, stream>>>(A, Wcv, qsb, Bq, flag, kOff, vOff);
    k_attn_s_mfma<<<dim3(72*NCH),    256, 0, stream>>>(Bq, A2, kOff, vOff);
    k_proj_s_mfma<<<dim3(4, 9, NCH), 256, 0, stream>>>(A2, psw, psb, x, Cx, Cx2, useT, flag, n0);
  }
  for (int m0 = 0; m0 < 1152; m0 += MCH){
    if (useT) k_gn_t2<<<dim3(MCH),   256, 0, stream>>>(Cx2, ntw, ntb, A, flag, m0);
    else      k_gn_t <<<dim3(MCH),   256, 0, stream>>>(Cx,  ntw, ntb, A, flag, m0);
    k_cvtw       <<<dim3(768),       256, 0, stream>>>(qtw, Wcv, 196608, flag);
    k_qkv_t_mfma <<<dim3(3*MCH),     256, 0, stream>>>(A, Wcv, qtb, Bq, flag);
    k_attn_t     <<<dim3(8, MCH),    256, 0, stream>>>(Bq, rpk, rpv, A2, flag);
    k_cvtw       <<<dim3(256),       256, 0, stream>>>(ptw, Wcv2, 65536, flag);
    k_proj_t_mfma<<<dim3(4, 8, MCH/32), 256, 0, stream>>>(A2, Wcv2, ptb, Cx, d_out, flag, m0);
  }
}